// Round 1
// baseline (2438.033 us; speedup 1.0000x reference)
//
#include <hip/hip_runtime.h>
#include <math.h>

#define GE 8  // edges/nodes per wave

__device__ __forceinline__ float bcast(float v, int k) {
  return __int_as_float(__builtin_amdgcn_readlane(__float_as_int(v), k));
}

// order-independent atomic float max (standard signed/unsigned trick; no NaNs here)
__device__ __forceinline__ void atomicMaxF(float* addr, float val) {
  if (val >= 0.0f) {
    atomicMax((int*)addr, __float_as_int(val));
  } else {
    atomicMin((unsigned int*)addr, (unsigned int)__float_as_int(val));
  }
}

// ---------------- goal = vc[argmax(labels[:,1])] ----------------
__global__ __launch_bounds__(256) void k_goal(const float* __restrict__ v,
                                              const float* __restrict__ labels,
                                              int N, float* __restrict__ goal) {
  __shared__ float bv[256];
  __shared__ int bi[256];
  float best = -INFINITY;
  int besti = 0;
  for (int i = threadIdx.x; i < N; i += 256) {
    float val = labels[2 * i + 1];
    if (val > best) { best = val; besti = i; }
  }
  bv[threadIdx.x] = best; bi[threadIdx.x] = besti;
  __syncthreads();
  for (int s = 128; s > 0; s >>= 1) {
    if (threadIdx.x < s) {
      float ov = bv[threadIdx.x + s]; int oi = bi[threadIdx.x + s];
      if (ov > bv[threadIdx.x] || (ov == bv[threadIdx.x] && oi < bi[threadIdx.x])) {
        bv[threadIdx.x] = ov; bi[threadIdx.x] = oi;
      }
    }
    __syncthreads();
  }
  if (threadIdx.x < 9) {
    int g = bi[0];
    float gv = (threadIdx.x < 7) ? v[7 * g + threadIdx.x] : labels[2 * g + threadIdx.x - 7];
    goal[threadIdx.x] = gv;
  }
}

// ---------------- x0 = MLP2([vc, goal, d, d*d]) , 36 -> 64 -> 64 ----------------
__global__ __launch_bounds__(256) void k_hx(const float* __restrict__ v,
                                            const float* __restrict__ labels,
                                            const float* __restrict__ goal,
                                            const float* __restrict__ w1, const float* __restrict__ b1,
                                            const float* __restrict__ w2, const float* __restrict__ b2,
                                            float* __restrict__ xout, int N) {
  int lane = threadIdx.x & 63;
  int wid = (blockIdx.x * blockDim.x + threadIdx.x) >> 6;
  int base = wid * GE;
  int c = lane % 9;
  float f[GE];
#pragma unroll
  for (int e = 0; e < GE; ++e) {
    int i = base + e; if (i >= N) i = N - 1;
    float fv = 0.f;
    if (lane < 36) {
      float vcv = (c < 7) ? v[7 * i + c] : labels[2 * i + (c - 7)];
      float gl = goal[c];
      float d = vcv - gl;
      fv = (lane < 9) ? vcv : (lane < 18) ? gl : (lane < 27) ? d : d * d;
    }
    f[e] = fv;
  }
  float acc[GE];
  float bb = b1[lane];
#pragma unroll
  for (int e = 0; e < GE; ++e) acc[e] = bb;
  for (int k = 0; k < 36; ++k) {
    float w = w1[k * 64 + lane];
#pragma unroll
    for (int e = 0; e < GE; ++e) acc[e] = fmaf(bcast(f[e], k), w, acc[e]);
  }
  float h[GE];
#pragma unroll
  for (int e = 0; e < GE; ++e) h[e] = fmaxf(acc[e], 0.f);
  float b2v = b2[lane];
#pragma unroll
  for (int e = 0; e < GE; ++e) acc[e] = b2v;
#pragma unroll 4
  for (int k = 0; k < 64; ++k) {
    float w = w2[k * 64 + lane];
#pragma unroll
    for (int e = 0; e < GE; ++e) acc[e] = fmaf(bcast(h[e], k), w, acc[e]);
  }
#pragma unroll
  for (int e = 0; e < GE; ++e) {
    int i = base + e;
    if (i < N) xout[(size_t)i * 64 + lane] = acc[e];
  }
}

// ---------------- y0 = MLP2([vcj - vci, vcj, vci]), 27 -> 64 -> 64  (i=src, j=dst) ------
__global__ __launch_bounds__(256) void k_hy(const float* __restrict__ v,
                                            const float* __restrict__ labels,
                                            const int* __restrict__ src, const int* __restrict__ dst,
                                            const float* __restrict__ w1, const float* __restrict__ b1,
                                            const float* __restrict__ w2, const float* __restrict__ b2,
                                            float* __restrict__ y, int E) {
  int lane = threadIdx.x & 63;
  int wid = (blockIdx.x * blockDim.x + threadIdx.x) >> 6;
  int base = wid * GE;
  int c = lane % 9;
  float f[GE];
#pragma unroll
  for (int e = 0; e < GE; ++e) {
    int eidx = base + e; if (eidx >= E) eidx = E - 1;
    float fv = 0.f;
    if (lane < 27) {
      int si = src[eidx], di = dst[eidx];
      float vci = (c < 7) ? v[7 * si + c] : labels[2 * si + (c - 7)];
      float vcj = (c < 7) ? v[7 * di + c] : labels[2 * di + (c - 7)];
      fv = (lane < 9) ? (vcj - vci) : (lane < 18) ? vcj : vci;
    }
    f[e] = fv;
  }
  float acc[GE];
  float bb = b1[lane];
#pragma unroll
  for (int e = 0; e < GE; ++e) acc[e] = bb;
  for (int k = 0; k < 27; ++k) {
    float w = w1[k * 64 + lane];
#pragma unroll
    for (int e = 0; e < GE; ++e) acc[e] = fmaf(bcast(f[e], k), w, acc[e]);
  }
  float h[GE];
#pragma unroll
  for (int e = 0; e < GE; ++e) h[e] = fmaxf(acc[e], 0.f);
  float b2v = b2[lane];
#pragma unroll
  for (int e = 0; e < GE; ++e) acc[e] = b2v;
#pragma unroll 4
  for (int k = 0; k < 64; ++k) {
    float w = w2[k * 64 + lane];
#pragma unroll
    for (int e = 0; e < GE; ++e) acc[e] = fmaf(bcast(h[e], k), w, acc[e]);
  }
#pragma unroll
  for (int e = 0; e < GE; ++e) {
    int eidx = base + e;
    if (eidx < E) y[(size_t)eidx * 64 + lane] = acc[e];
  }
}

// ---------------- m = MLP2([x[src]-x[dst], x[src], x[dst], y]) ; scatter-max to xnew[dst] ----
__global__ __launch_bounds__(256) void k_fx(const float* __restrict__ x,
                                            const float* __restrict__ y,
                                            const int* __restrict__ src, const int* __restrict__ dst,
                                            const float* __restrict__ w1, const float* __restrict__ b1,
                                            const float* __restrict__ w2, const float* __restrict__ b2,
                                            float* __restrict__ xnew, int E) {
  __shared__ float w1s[256 * 64];  // 64 KB
  {
    const float4* g = (const float4*)w1;
    float4* s = (float4*)w1s;
    for (int i = threadIdx.x; i < 256 * 64 / 4; i += blockDim.x) s[i] = g[i];
  }
  __syncthreads();
  int lane = threadIdx.x & 63;
  int wid = blockIdx.x * (blockDim.x >> 6) + (threadIdx.x >> 6);
  int base = wid * GE;
  float fA[GE][4];
  int dsts[GE];
#pragma unroll
  for (int e = 0; e < GE; ++e) {
    int eidx = base + e; if (eidx >= E) eidx = E - 1;
    int si = src[eidx], di = dst[eidx];
    dsts[e] = di;
    float xs = x[(size_t)si * 64 + lane];
    float xd = x[(size_t)di * 64 + lane];
    float yv = y[(size_t)eidx * 64 + lane];
    fA[e][0] = xs - xd; fA[e][1] = xs; fA[e][2] = xd; fA[e][3] = yv;
  }
  float acc[GE];
  float bb = b1[lane];
#pragma unroll
  for (int e = 0; e < GE; ++e) acc[e] = bb;
#pragma unroll
  for (int q = 0; q < 4; ++q) {
#pragma unroll 4
    for (int k2 = 0; k2 < 64; ++k2) {
      float w = w1s[(q * 64 + k2) * 64 + lane];
#pragma unroll
      for (int e = 0; e < GE; ++e) acc[e] = fmaf(bcast(fA[e][q], k2), w, acc[e]);
    }
  }
  float h[GE];
#pragma unroll
  for (int e = 0; e < GE; ++e) h[e] = fmaxf(acc[e], 0.f);
  float b2v = b2[lane];
#pragma unroll
  for (int e = 0; e < GE; ++e) acc[e] = b2v;
#pragma unroll 4
  for (int k = 0; k < 64; ++k) {
    float w = w2[k * 64 + lane];
#pragma unroll
    for (int e = 0; e < GE; ++e) acc[e] = fmaf(bcast(h[e], k), w, acc[e]);
  }
#pragma unroll
  for (int e = 0; e < GE; ++e) {
    int eidx = base + e;
    if (eidx < E) atomicMaxF(&xnew[(size_t)dsts[e] * 64 + lane], acc[e]);
  }
}

// ---------------- y = max(y, MLP2([x[dst]-x[src], x[dst], x[src]])), 192 -> 64 -> 64 ----
__global__ __launch_bounds__(256) void k_fy(const float* __restrict__ x,
                                            float* __restrict__ y,
                                            const int* __restrict__ src, const int* __restrict__ dst,
                                            const float* __restrict__ w1, const float* __restrict__ b1,
                                            const float* __restrict__ w2, const float* __restrict__ b2,
                                            int E) {
  __shared__ float w1s[192 * 64];  // 48 KB
  {
    const float4* g = (const float4*)w1;
    float4* s = (float4*)w1s;
    for (int i = threadIdx.x; i < 192 * 64 / 4; i += blockDim.x) s[i] = g[i];
  }
  __syncthreads();
  int lane = threadIdx.x & 63;
  int wid = blockIdx.x * (blockDim.x >> 6) + (threadIdx.x >> 6);
  int base = wid * GE;
  float fA[GE][3];
#pragma unroll
  for (int e = 0; e < GE; ++e) {
    int eidx = base + e; if (eidx >= E) eidx = E - 1;
    int si = src[eidx], di = dst[eidx];
    float xs = x[(size_t)si * 64 + lane];
    float xd = x[(size_t)di * 64 + lane];
    fA[e][0] = xd - xs; fA[e][1] = xd; fA[e][2] = xs;
  }
  float acc[GE];
  float bb = b1[lane];
#pragma unroll
  for (int e = 0; e < GE; ++e) acc[e] = bb;
#pragma unroll
  for (int q = 0; q < 3; ++q) {
#pragma unroll 4
    for (int k2 = 0; k2 < 64; ++k2) {
      float w = w1s[(q * 64 + k2) * 64 + lane];
#pragma unroll
      for (int e = 0; e < GE; ++e) acc[e] = fmaf(bcast(fA[e][q], k2), w, acc[e]);
    }
  }
  float h[GE];
#pragma unroll
  for (int e = 0; e < GE; ++e) h[e] = fmaxf(acc[e], 0.f);
  float b2v = b2[lane];
#pragma unroll
  for (int e = 0; e < GE; ++e) acc[e] = b2v;
#pragma unroll 4
  for (int k = 0; k < 64; ++k) {
    float w = w2[k * 64 + lane];
#pragma unroll
    for (int e = 0; e < GE; ++e) acc[e] = fmaf(bcast(h[e], k), w, acc[e]);
  }
#pragma unroll
  for (int e = 0; e < GE; ++e) {
    int eidx = base + e;
    if (eidx < E) {
      float* yp = &y[(size_t)eidx * 64 + lane];
      *yp = fmaxf(*yp, acc[e]);
    }
  }
}

// ---------------- out = feta(x): 64 -> 64 -> 64 -> 1 ----------------
__global__ __launch_bounds__(256) void k_feta(const float* __restrict__ x,
                                              const float* __restrict__ w1, const float* __restrict__ b1,
                                              const float* __restrict__ w2, const float* __restrict__ b2,
                                              const float* __restrict__ w3,
                                              float* __restrict__ out, int N) {
  int lane = threadIdx.x & 63;
  int wid = (blockIdx.x * blockDim.x + threadIdx.x) >> 6;
  int base = wid * GE;
  float xr[GE];
#pragma unroll
  for (int e = 0; e < GE; ++e) {
    int i = base + e; if (i >= N) i = N - 1;
    xr[e] = x[(size_t)i * 64 + lane];
  }
  float acc[GE];
  float bb = b1[lane];
#pragma unroll
  for (int e = 0; e < GE; ++e) acc[e] = bb;
#pragma unroll 4
  for (int k = 0; k < 64; ++k) {
    float w = w1[k * 64 + lane];
#pragma unroll
    for (int e = 0; e < GE; ++e) acc[e] = fmaf(bcast(xr[e], k), w, acc[e]);
  }
  float h1[GE];
#pragma unroll
  for (int e = 0; e < GE; ++e) h1[e] = fmaxf(acc[e], 0.f);
  float b2v = b2[lane];
#pragma unroll
  for (int e = 0; e < GE; ++e) acc[e] = b2v;
#pragma unroll 4
  for (int k = 0; k < 64; ++k) {
    float w = w2[k * 64 + lane];
#pragma unroll
    for (int e = 0; e < GE; ++e) acc[e] = fmaf(bcast(h1[e], k), w, acc[e]);
  }
  float w3l = w3[lane];
#pragma unroll
  for (int e = 0; e < GE; ++e) {
    float r = fmaxf(acc[e], 0.f) * w3l;
    for (int off = 32; off > 0; off >>= 1) r += __shfl_xor(r, off, 64);
    int i = base + e;
    if (lane == 0 && i < N) out[i] = r;
  }
}

__global__ __launch_bounds__(256) void k_copy(const float4* __restrict__ s,
                                              float4* __restrict__ d, int n4) {
  int i = blockIdx.x * blockDim.x + threadIdx.x;
  if (i < n4) d[i] = s[i];
}

extern "C" void kernel_launch(void* const* d_in, const int* in_sizes, int n_in,
                              void* d_out, int out_size, void* d_ws, size_t ws_size,
                              hipStream_t stream) {
  const float* v      = (const float*)d_in[0];
  const float* labels = (const float*)d_in[1];
  const int*   ei     = (const int*)d_in[2];
  // d_in[3] = loop (always 3 for this problem; fixed sequence keeps graph capture valid)
  const float* hx_w1 = (const float*)d_in[4];
  const float* hx_b1 = (const float*)d_in[5];
  const float* hx_w2 = (const float*)d_in[6];
  const float* hx_b2 = (const float*)d_in[7];
  const float* hy_w1 = (const float*)d_in[8];
  const float* hy_b1 = (const float*)d_in[9];
  const float* hy_w2 = (const float*)d_in[10];
  const float* hy_b2 = (const float*)d_in[11];
  const float* fx_w1 = (const float*)d_in[12];
  const float* fx_b1 = (const float*)d_in[13];
  const float* fx_w2 = (const float*)d_in[14];
  const float* fx_b2 = (const float*)d_in[15];
  const float* fy_w1 = (const float*)d_in[16];
  const float* fy_b1 = (const float*)d_in[17];
  const float* fy_w2 = (const float*)d_in[18];
  const float* fy_b2 = (const float*)d_in[19];
  const float* feta_w1 = (const float*)d_in[20];
  const float* feta_b1 = (const float*)d_in[21];
  const float* feta_w2 = (const float*)d_in[22];
  const float* feta_b2 = (const float*)d_in[23];
  const float* feta_w3 = (const float*)d_in[24];

  int N = in_sizes[0] / 7;
  int E = in_sizes[2] / 2;
  const int* src = ei;
  const int* dst = ei + E;

  float* ws = (float*)d_ws;
  float* goal = ws;                     // 16 floats
  float* xa = ws + 16;                  // N*64
  float* xb = xa + (size_t)N * 64;      // N*64
  float* y  = xb + (size_t)N * 64;      // E*64

  k_goal<<<1, 256, 0, stream>>>(v, labels, N, goal);
  k_hx<<<(N + 31) / 32, 256, 0, stream>>>(v, labels, goal, hx_w1, hx_b1, hx_w2, hx_b2, xa, N);
  k_hy<<<(E + 31) / 32, 256, 0, stream>>>(v, labels, src, dst, hy_w1, hy_b1, hy_w2, hy_b2, y, E);

  float* xc = xa;
  float* xo = xb;
  for (int t = 0; t < 3; ++t) {
    k_copy<<<(N * 16 + 255) / 256, 256, 0, stream>>>((const float4*)xc, (float4*)xo, N * 16);
    k_fx<<<(E + 31) / 32, 256, 0, stream>>>(xc, y, src, dst, fx_w1, fx_b1, fx_w2, fx_b2, xo, E);
    float* tmp = xc; xc = xo; xo = tmp;
    k_fy<<<(E + 31) / 32, 256, 0, stream>>>(xc, y, src, dst, fy_w1, fy_b1, fy_w2, fy_b2, E);
  }
  k_feta<<<(N + 31) / 32, 256, 0, stream>>>(xc, feta_w1, feta_b1, feta_w2, feta_b2, feta_w3,
                                            (float*)d_out, N);
}

// Round 2
// 801.961 us; speedup vs baseline: 3.0401x; 3.0401x over previous
//
#include <hip/hip_runtime.h>
#include <math.h>

typedef unsigned short u16;
typedef unsigned int u32;
typedef __attribute__((ext_vector_type(8))) short bf16x8;
typedef __attribute__((ext_vector_type(4))) float f32x4;

union U8s { bf16x8 v; u32 u[4]; u16 s[8]; };

#define GE 8  // edges/nodes per wave for the VALU kernels

__device__ __forceinline__ float bcast(float v, int k) {
  return __int_as_float(__builtin_amdgcn_readlane(__float_as_int(v), k));
}

__device__ __forceinline__ void atomicMaxF(float* addr, float val) {
  if (val >= 0.0f) {
    atomicMax((int*)addr, __float_as_int(val));
  } else {
    atomicMin((unsigned int*)addr, (unsigned int)__float_as_int(val));
  }
}

// pack top-16-bits of two floats into one u32: low short = trunc-bf16(f0), high = trunc-bf16(f1)
__device__ __forceinline__ u32 pack_hi2(float f0, float f1) {
  return __builtin_amdgcn_perm(__float_as_uint(f1), __float_as_uint(f0), 0x07060302u);
}

__device__ __forceinline__ float upf(u16 s) { return __uint_as_float(((u32)s) << 16); }

// split 8 fp32 -> bf16 hi frag + bf16 lo frag (truncation split: residual <= 2^-16 rel)
__device__ __forceinline__ void dec8(const float* f, U8s& h, U8s& l) {
#pragma unroll
  for (int i = 0; i < 4; ++i) {
    float a = f[2 * i], b = f[2 * i + 1];
    float ra = a - __uint_as_float(__float_as_uint(a) & 0xffff0000u);
    float rb = b - __uint_as_float(__float_as_uint(b) & 0xffff0000u);
    h.u[i] = pack_hi2(a, b);
    l.u[i] = pack_hi2(ra, rb);
  }
}

// ---------------- goal: argmax over labels[:,1] (packed u64 atomic; first-max tie) ------
__global__ __launch_bounds__(256) void k_goal1(const float* __restrict__ labels, int N,
                                               unsigned long long* __restrict__ key) {
  int i = blockIdx.x * 256 + threadIdx.x;
  if (i < N) {
    float val = labels[2 * i + 1];  // labels are {0,1}: uint-orderable
    unsigned long long k = ((unsigned long long)__float_as_uint(val) << 32) | (u32)(~i);
    atomicMax(key, k);
  }
}

__global__ void k_goal2(const float* __restrict__ v, const float* __restrict__ labels,
                        const unsigned long long* __restrict__ key, float* __restrict__ goal) {
  int g = (int)(~(u32)(*key));
  int c = threadIdx.x;
  if (c < 9) goal[c] = (c < 7) ? v[7 * (size_t)g + c] : labels[2 * (size_t)g + (c - 7)];
}

// ---------------- weight prep: fold concat-linearity + bf16 hi/lo split, frag-major ------
// fx L1: Wcat[192][64] = [W0+W1 ; W2-W0 ; W3]  (applies to [xs, xd, y])
// fy L1: Wcat[128][64] = [W0+W1 ; W2-W0]       (applies to [xd, xs])
// frag-major: idx = ((c*4+t)*64 + lane)*8 + j, value = Wcat[c*32 + (lane>>4)*8 + j][t*16 + (lane&15)]
__global__ __launch_bounds__(256) void k_prep(const float* __restrict__ fxw1, const float* __restrict__ fxw2,
                                              const float* __restrict__ fyw1, const float* __restrict__ fyw2,
                                              u16* __restrict__ wp) {
  u16* fxB1h = wp;          u16* fxB1l = wp + 12288;
  u16* fxB2h = wp + 24576;  u16* fxB2l = wp + 28672;
  u16* fyB1h = wp + 32768;  u16* fyB1l = wp + 40960;
  u16* fyB2h = wp + 49152;  u16* fyB2l = wp + 53248;
  int tid = blockIdx.x * 256 + threadIdx.x;
  int which, id;
  u16 *oh, *ol;
  if (tid < 1536)      { which = 0; id = tid;        oh = fxB1h; ol = fxB1l; }
  else if (tid < 2048) { which = 1; id = tid - 1536; oh = fxB2h; ol = fxB2l; }
  else if (tid < 3072) { which = 2; id = tid - 2048; oh = fyB1h; ol = fyB1l; }
  else if (tid < 3584) { which = 3; id = tid - 3072; oh = fyB2h; ol = fyB2l; }
  else return;
  int lane = id & 63;
  int q = lane >> 4, col = lane & 15;
  int c = id >> 8, t = (id >> 6) & 3;
#pragma unroll
  for (int j = 0; j < 8; ++j) {
    int k = c * 32 + q * 8 + j;
    int n = t * 16 + col;
    float w;
    if (which == 0) {
      w = (k < 64)  ? fxw1[k * 64 + n] + fxw1[(k + 64) * 64 + n]
        : (k < 128) ? fxw1[(k + 64) * 64 + n] - fxw1[(k - 64) * 64 + n]
                    : fxw1[(k + 64) * 64 + n];
    } else if (which == 1) {
      w = fxw2[k * 64 + n];
    } else if (which == 2) {
      w = (k < 64) ? fyw1[k * 64 + n] + fyw1[(k + 64) * 64 + n]
                   : fyw1[(k + 64) * 64 + n] - fyw1[(k - 64) * 64 + n];
    } else {
      w = fyw2[k * 64 + n];
    }
    // RNE hi, RNE lo
    u32 u = __float_as_uint(w);
    u32 hr = (u + 0x7fffu + ((u >> 16) & 1u)) >> 16;
    float rres = w - __uint_as_float(hr << 16);
    u32 u2 = __float_as_uint(rres);
    u32 lr = (u2 + 0x7fffu + ((u2 >> 16) & 1u)) >> 16;
    oh[id * 8 + j] = (u16)hr;
    ol[id * 8 + j] = (u16)lr;
  }
}

// ---------------- x0 = MLP2([vc, goal, d, d*d]) , 36 -> 64 -> 64 (VALU; small) ----------
__global__ __launch_bounds__(256) void k_hx(const float* __restrict__ v,
                                            const float* __restrict__ labels,
                                            const float* __restrict__ goal,
                                            const float* __restrict__ w1, const float* __restrict__ b1,
                                            const float* __restrict__ w2, const float* __restrict__ b2,
                                            float* __restrict__ xout, int N) {
  int lane = threadIdx.x & 63;
  int wid = (blockIdx.x * blockDim.x + threadIdx.x) >> 6;
  int base = wid * GE;
  int c = lane % 9;
  float f[GE];
#pragma unroll
  for (int e = 0; e < GE; ++e) {
    int i = base + e; if (i >= N) i = N - 1;
    float fv = 0.f;
    if (lane < 36) {
      float vcv = (c < 7) ? v[7 * i + c] : labels[2 * i + (c - 7)];
      float gl = goal[c];
      float d = vcv - gl;
      fv = (lane < 9) ? vcv : (lane < 18) ? gl : (lane < 27) ? d : d * d;
    }
    f[e] = fv;
  }
  float acc[GE];
  float bb = b1[lane];
#pragma unroll
  for (int e = 0; e < GE; ++e) acc[e] = bb;
  for (int k = 0; k < 36; ++k) {
    float w = w1[k * 64 + lane];
#pragma unroll
    for (int e = 0; e < GE; ++e) acc[e] = fmaf(bcast(f[e], k), w, acc[e]);
  }
  float h[GE];
#pragma unroll
  for (int e = 0; e < GE; ++e) h[e] = fmaxf(acc[e], 0.f);
  float b2v = b2[lane];
#pragma unroll
  for (int e = 0; e < GE; ++e) acc[e] = b2v;
#pragma unroll 4
  for (int k = 0; k < 64; ++k) {
    float w = w2[k * 64 + lane];
#pragma unroll
    for (int e = 0; e < GE; ++e) acc[e] = fmaf(bcast(h[e], k), w, acc[e]);
  }
#pragma unroll
  for (int e = 0; e < GE; ++e) {
    int i = base + e;
    if (i < N) xout[(size_t)i * 64 + lane] = acc[e];
  }
}

// ---------------- y0 = MLP2([vcj - vci, vcj, vci]); writes bf16 hi/lo ----------
__global__ __launch_bounds__(256) void k_hy(const float* __restrict__ v,
                                            const float* __restrict__ labels,
                                            const int* __restrict__ src, const int* __restrict__ dst,
                                            const float* __restrict__ w1, const float* __restrict__ b1,
                                            const float* __restrict__ w2, const float* __restrict__ b2,
                                            u16* __restrict__ yh, u16* __restrict__ yl, int E) {
  int lane = threadIdx.x & 63;
  int wid = (blockIdx.x * blockDim.x + threadIdx.x) >> 6;
  int base = wid * GE;
  int c = lane % 9;
  float f[GE];
#pragma unroll
  for (int e = 0; e < GE; ++e) {
    int eidx = base + e; if (eidx >= E) eidx = E - 1;
    float fv = 0.f;
    if (lane < 27) {
      int si = src[eidx], di = dst[eidx];
      float vci = (c < 7) ? v[7 * si + c] : labels[2 * si + (c - 7)];
      float vcj = (c < 7) ? v[7 * di + c] : labels[2 * di + (c - 7)];
      fv = (lane < 9) ? (vcj - vci) : (lane < 18) ? vcj : vci;
    }
    f[e] = fv;
  }
  float acc[GE];
  float bb = b1[lane];
#pragma unroll
  for (int e = 0; e < GE; ++e) acc[e] = bb;
  for (int k = 0; k < 27; ++k) {
    float w = w1[k * 64 + lane];
#pragma unroll
    for (int e = 0; e < GE; ++e) acc[e] = fmaf(bcast(f[e], k), w, acc[e]);
  }
  float h[GE];
#pragma unroll
  for (int e = 0; e < GE; ++e) h[e] = fmaxf(acc[e], 0.f);
  float b2v = b2[lane];
#pragma unroll
  for (int e = 0; e < GE; ++e) acc[e] = b2v;
#pragma unroll 4
  for (int k = 0; k < 64; ++k) {
    float w = w2[k * 64 + lane];
#pragma unroll
    for (int e = 0; e < GE; ++e) acc[e] = fmaf(bcast(h[e], k), w, acc[e]);
  }
#pragma unroll
  for (int e = 0; e < GE; ++e) {
    int eidx = base + e;
    if (eidx < E) {
      float fq = acc[e];
      u32 u = __float_as_uint(fq);
      yh[(size_t)eidx * 64 + lane] = (u16)(u >> 16);
      float r = fq - __uint_as_float(u & 0xffff0000u);
      yl[(size_t)eidx * 64 + lane] = (u16)(__float_as_uint(r) >> 16);
    }
  }
}

// ---------------- fx: MFMA, 16 edges/wave. feats=[xs,xd,y] (folded W), K=192 ----------
__global__ __launch_bounds__(256) void k_fx(
    const float* __restrict__ x, const u16* __restrict__ yh, const u16* __restrict__ yl,
    const int* __restrict__ src, const int* __restrict__ dst,
    const u16* __restrict__ B1h, const u16* __restrict__ B1l, const float* __restrict__ b1,
    const u16* __restrict__ B2h, const u16* __restrict__ B2l, const float* __restrict__ b2,
    float* __restrict__ xnew, int E) {
  __shared__ float hbuf[4][16 * 68];
  const int lane = threadIdx.x & 63;
  const int wv = threadIdx.x >> 6;
  const int m = lane & 15, q = lane >> 4;
  const int base = blockIdx.x * 64 + wv * 16;
  int em = base + m; if (em >= E) em = E - 1;
  const int si = src[em], di = dst[em];

  const float* ps = x + (size_t)si * 64 + q * 8;
  const float* pd = x + (size_t)di * 64 + q * 8;
  float fs[16], fd[16];
  *(float4*)(fs + 0)  = *(const float4*)(ps);
  *(float4*)(fs + 4)  = *(const float4*)(ps + 4);
  *(float4*)(fs + 8)  = *(const float4*)(ps + 32);
  *(float4*)(fs + 12) = *(const float4*)(ps + 36);
  *(float4*)(fd + 0)  = *(const float4*)(pd);
  *(float4*)(fd + 4)  = *(const float4*)(pd + 4);
  *(float4*)(fd + 8)  = *(const float4*)(pd + 32);
  *(float4*)(fd + 12) = *(const float4*)(pd + 36);

  U8s Ah[6], Al[6];
  dec8(fs + 0, Ah[0], Al[0]);
  dec8(fs + 8, Ah[1], Al[1]);
  dec8(fd + 0, Ah[2], Al[2]);
  dec8(fd + 8, Ah[3], Al[3]);
  const u16* pyh = yh + (size_t)em * 64 + q * 8;
  const u16* pyl = yl + (size_t)em * 64 + q * 8;
  Ah[4].v = *(const bf16x8*)(pyh);      Ah[5].v = *(const bf16x8*)(pyh + 32);
  Al[4].v = *(const bf16x8*)(pyl);      Al[5].v = *(const bf16x8*)(pyl + 32);

  f32x4 acc[4];
#pragma unroll
  for (int t = 0; t < 4; ++t) { float bv = b1[t * 16 + m]; acc[t] = (f32x4){bv, bv, bv, bv}; }

#pragma unroll
  for (int c = 0; c < 6; ++c) {
#pragma unroll
    for (int t = 0; t < 4; ++t) {
      bf16x8 bh = *(const bf16x8*)(B1h + ((size_t)(c * 4 + t) * 64 + lane) * 8);
      bf16x8 bl = *(const bf16x8*)(B1l + ((size_t)(c * 4 + t) * 64 + lane) * 8);
      acc[t] = __builtin_amdgcn_mfma_f32_16x16x32_bf16(Ah[c].v, bh, acc[t], 0, 0, 0);
      acc[t] = __builtin_amdgcn_mfma_f32_16x16x32_bf16(Al[c].v, bh, acc[t], 0, 0, 0);
      acc[t] = __builtin_amdgcn_mfma_f32_16x16x32_bf16(Ah[c].v, bl, acc[t], 0, 0, 0);
    }
  }

  // ReLU + transpose C-layout -> A-layout via LDS (wave-private tile, pad 68 kills conflicts)
  float* hb = hbuf[wv];
#pragma unroll
  for (int t = 0; t < 4; ++t)
#pragma unroll
    for (int r = 0; r < 4; ++r)
      hb[(q * 4 + r) * 68 + t * 16 + m] = fmaxf(acc[t][r], 0.f);
  __syncthreads();

  float fh[16];
  const float* hr = hb + m * 68 + q * 8;
  *(float4*)(fh + 0)  = *(const float4*)(hr);
  *(float4*)(fh + 4)  = *(const float4*)(hr + 4);
  *(float4*)(fh + 8)  = *(const float4*)(hr + 32);
  *(float4*)(fh + 12) = *(const float4*)(hr + 36);
  U8s A2h[2], A2l[2];
  dec8(fh + 0, A2h[0], A2l[0]);
  dec8(fh + 8, A2h[1], A2l[1]);

  f32x4 acc2[4];
#pragma unroll
  for (int t = 0; t < 4; ++t) { float bv = b2[t * 16 + m]; acc2[t] = (f32x4){bv, bv, bv, bv}; }
#pragma unroll
  for (int c = 0; c < 2; ++c) {
#pragma unroll
    for (int t = 0; t < 4; ++t) {
      bf16x8 bh = *(const bf16x8*)(B2h + ((size_t)(c * 4 + t) * 64 + lane) * 8);
      bf16x8 bl = *(const bf16x8*)(B2l + ((size_t)(c * 4 + t) * 64 + lane) * 8);
      acc2[t] = __builtin_amdgcn_mfma_f32_16x16x32_bf16(A2h[c].v, bh, acc2[t], 0, 0, 0);
      acc2[t] = __builtin_amdgcn_mfma_f32_16x16x32_bf16(A2l[c].v, bh, acc2[t], 0, 0, 0);
      acc2[t] = __builtin_amdgcn_mfma_f32_16x16x32_bf16(A2h[c].v, bl, acc2[t], 0, 0, 0);
    }
  }

  int dj[4]; bool lv[4];
#pragma unroll
  for (int r = 0; r < 4; ++r) {
    int e2 = base + q * 4 + r;
    lv[r] = e2 < E;
    if (e2 >= E) e2 = E - 1;
    dj[r] = dst[e2];
  }
#pragma unroll
  for (int t = 0; t < 4; ++t)
#pragma unroll
    for (int r = 0; r < 4; ++r)
      if (lv[r]) atomicMaxF(&xnew[(size_t)dj[r] * 64 + t * 16 + m], acc2[t][r]);
}

// ---------------- fy: MFMA, feats=[xd,xs] (folded W), K=128; y = max(y, out) ----------
__global__ __launch_bounds__(256) void k_fy(
    const float* __restrict__ x, u16* __restrict__ yh, u16* __restrict__ yl,
    const int* __restrict__ src, const int* __restrict__ dst,
    const u16* __restrict__ B1h, const u16* __restrict__ B1l, const float* __restrict__ b1,
    const u16* __restrict__ B2h, const u16* __restrict__ B2l, const float* __restrict__ b2,
    int E) {
  __shared__ float hbuf[4][16 * 68];
  const int lane = threadIdx.x & 63;
  const int wv = threadIdx.x >> 6;
  const int m = lane & 15, q = lane >> 4;
  const int base = blockIdx.x * 64 + wv * 16;
  int em = base + m; if (em >= E) em = E - 1;
  const int si = src[em], di = dst[em];

  const float* ps = x + (size_t)si * 64 + q * 8;
  const float* pd = x + (size_t)di * 64 + q * 8;
  float fs[16], fd[16];
  *(float4*)(fd + 0)  = *(const float4*)(pd);
  *(float4*)(fd + 4)  = *(const float4*)(pd + 4);
  *(float4*)(fd + 8)  = *(const float4*)(pd + 32);
  *(float4*)(fd + 12) = *(const float4*)(pd + 36);
  *(float4*)(fs + 0)  = *(const float4*)(ps);
  *(float4*)(fs + 4)  = *(const float4*)(ps + 4);
  *(float4*)(fs + 8)  = *(const float4*)(ps + 32);
  *(float4*)(fs + 12) = *(const float4*)(ps + 36);

  U8s Ah[4], Al[4];
  dec8(fd + 0, Ah[0], Al[0]);   // chunks 0,1: xd (W0+W1)
  dec8(fd + 8, Ah[1], Al[1]);
  dec8(fs + 0, Ah[2], Al[2]);   // chunks 2,3: xs (W2-W0)
  dec8(fs + 8, Ah[3], Al[3]);

  f32x4 acc[4];
#pragma unroll
  for (int t = 0; t < 4; ++t) { float bv = b1[t * 16 + m]; acc[t] = (f32x4){bv, bv, bv, bv}; }
#pragma unroll
  for (int c = 0; c < 4; ++c) {
#pragma unroll
    for (int t = 0; t < 4; ++t) {
      bf16x8 bh = *(const bf16x8*)(B1h + ((size_t)(c * 4 + t) * 64 + lane) * 8);
      bf16x8 bl = *(const bf16x8*)(B1l + ((size_t)(c * 4 + t) * 64 + lane) * 8);
      acc[t] = __builtin_amdgcn_mfma_f32_16x16x32_bf16(Ah[c].v, bh, acc[t], 0, 0, 0);
      acc[t] = __builtin_amdgcn_mfma_f32_16x16x32_bf16(Al[c].v, bh, acc[t], 0, 0, 0);
      acc[t] = __builtin_amdgcn_mfma_f32_16x16x32_bf16(Ah[c].v, bl, acc[t], 0, 0, 0);
    }
  }

  float* hb = hbuf[wv];
#pragma unroll
  for (int t = 0; t < 4; ++t)
#pragma unroll
    for (int r = 0; r < 4; ++r)
      hb[(q * 4 + r) * 68 + t * 16 + m] = fmaxf(acc[t][r], 0.f);
  __syncthreads();

  float fh[16];
  const float* hr = hb + m * 68 + q * 8;
  *(float4*)(fh + 0)  = *(const float4*)(hr);
  *(float4*)(fh + 4)  = *(const float4*)(hr + 4);
  *(float4*)(fh + 8)  = *(const float4*)(hr + 32);
  *(float4*)(fh + 12) = *(const float4*)(hr + 36);
  U8s A2h[2], A2l[2];
  dec8(fh + 0, A2h[0], A2l[0]);
  dec8(fh + 8, A2h[1], A2l[1]);
  __syncthreads();  // done reading h before overwriting hbuf with the output tile

  f32x4 acc2[4];
#pragma unroll
  for (int t = 0; t < 4; ++t) { float bv = b2[t * 16 + m]; acc2[t] = (f32x4){bv, bv, bv, bv}; }
#pragma unroll
  for (int c = 0; c < 2; ++c) {
#pragma unroll
    for (int t = 0; t < 4; ++t) {
      bf16x8 bh = *(const bf16x8*)(B2h + ((size_t)(c * 4 + t) * 64 + lane) * 8);
      bf16x8 bl = *(const bf16x8*)(B2l + ((size_t)(c * 4 + t) * 64 + lane) * 8);
      acc2[t] = __builtin_amdgcn_mfma_f32_16x16x32_bf16(A2h[c].v, bh, acc2[t], 0, 0, 0);
      acc2[t] = __builtin_amdgcn_mfma_f32_16x16x32_bf16(A2l[c].v, bh, acc2[t], 0, 0, 0);
      acc2[t] = __builtin_amdgcn_mfma_f32_16x16x32_bf16(A2h[c].v, bl, acc2[t], 0, 0, 0);
    }
  }

  // transpose output to row-major, then y = max(y_old, out), re-split to hi/lo
#pragma unroll
  for (int t = 0; t < 4; ++t)
#pragma unroll
    for (int r = 0; r < 4; ++r)
      hb[(q * 4 + r) * 68 + t * 16 + m] = acc2[t][r];
  __syncthreads();

  int row = base + m;
  bool live = row < E;          // guard: clamped waves must not write (avoid hi/lo torn reads)
  if (row >= E) row = E - 1;
  if (live) {
    float ov[16];
    const float* orow = hb + m * 68 + q * 16;
    *(float4*)(ov + 0)  = *(const float4*)(orow);
    *(float4*)(ov + 4)  = *(const float4*)(orow + 4);
    *(float4*)(ov + 8)  = *(const float4*)(orow + 8);
    *(float4*)(ov + 12) = *(const float4*)(orow + 12);
    size_t yo = (size_t)row * 64 + q * 16;
    U8s Hh0, Hh1, Hl0, Hl1;
    Hh0.v = *(const bf16x8*)(yh + yo);     Hh1.v = *(const bf16x8*)(yh + yo + 8);
    Hl0.v = *(const bf16x8*)(yl + yo);     Hl1.v = *(const bf16x8*)(yl + yo + 8);
    float nv[16];
#pragma unroll
    for (int i = 0; i < 8; ++i) {
      nv[i]     = fmaxf(upf(Hh0.s[i]) + upf(Hl0.s[i]), ov[i]);
      nv[8 + i] = fmaxf(upf(Hh1.s[i]) + upf(Hl1.s[i]), ov[8 + i]);
    }
    U8s Oh0, Oh1, Ol0, Ol1;
    dec8(nv + 0, Oh0, Ol0);
    dec8(nv + 8, Oh1, Ol1);
    *(bf16x8*)(yh + yo)     = Oh0.v;
    *(bf16x8*)(yh + yo + 8) = Oh1.v;
    *(bf16x8*)(yl + yo)     = Ol0.v;
    *(bf16x8*)(yl + yo + 8) = Ol1.v;
  }
}

// ---------------- out = feta(x): 64 -> 64 -> 64 -> 1 (VALU; small) ----------------
__global__ __launch_bounds__(256) void k_feta(const float* __restrict__ x,
                                              const float* __restrict__ w1, const float* __restrict__ b1,
                                              const float* __restrict__ w2, const float* __restrict__ b2,
                                              const float* __restrict__ w3,
                                              float* __restrict__ out, int N) {
  int lane = threadIdx.x & 63;
  int wid = (blockIdx.x * blockDim.x + threadIdx.x) >> 6;
  int base = wid * GE;
  float xr[GE];
#pragma unroll
  for (int e = 0; e < GE; ++e) {
    int i = base + e; if (i >= N) i = N - 1;
    xr[e] = x[(size_t)i * 64 + lane];
  }
  float acc[GE];
  float bb = b1[lane];
#pragma unroll
  for (int e = 0; e < GE; ++e) acc[e] = bb;
#pragma unroll 4
  for (int k = 0; k < 64; ++k) {
    float w = w1[k * 64 + lane];
#pragma unroll
    for (int e = 0; e < GE; ++e) acc[e] = fmaf(bcast(xr[e], k), w, acc[e]);
  }
  float h1[GE];
#pragma unroll
  for (int e = 0; e < GE; ++e) h1[e] = fmaxf(acc[e], 0.f);
  float b2v = b2[lane];
#pragma unroll
  for (int e = 0; e < GE; ++e) acc[e] = b2v;
#pragma unroll 4
  for (int k = 0; k < 64; ++k) {
    float w = w2[k * 64 + lane];
#pragma unroll
    for (int e = 0; e < GE; ++e) acc[e] = fmaf(bcast(h1[e], k), w, acc[e]);
  }
  float w3l = w3[lane];
#pragma unroll
  for (int e = 0; e < GE; ++e) {
    float r = fmaxf(acc[e], 0.f) * w3l;
    for (int off = 32; off > 0; off >>= 1) r += __shfl_xor(r, off, 64);
    int i = base + e;
    if (lane == 0 && i < N) out[i] = r;
  }
}

__global__ __launch_bounds__(256) void k_copy(const float4* __restrict__ s,
                                              float4* __restrict__ d, int n4) {
  int i = blockIdx.x * blockDim.x + threadIdx.x;
  if (i < n4) d[i] = s[i];
}

extern "C" void kernel_launch(void* const* d_in, const int* in_sizes, int n_in,
                              void* d_out, int out_size, void* d_ws, size_t ws_size,
                              hipStream_t stream) {
  const float* v      = (const float*)d_in[0];
  const float* labels = (const float*)d_in[1];
  const int*   ei     = (const int*)d_in[2];
  const float* hx_w1 = (const float*)d_in[4];
  const float* hx_b1 = (const float*)d_in[5];
  const float* hx_w2 = (const float*)d_in[6];
  const float* hx_b2 = (const float*)d_in[7];
  const float* hy_w1 = (const float*)d_in[8];
  const float* hy_b1 = (const float*)d_in[9];
  const float* hy_w2 = (const float*)d_in[10];
  const float* hy_b2 = (const float*)d_in[11];
  const float* fx_w1 = (const float*)d_in[12];
  const float* fx_b1 = (const float*)d_in[13];
  const float* fx_w2 = (const float*)d_in[14];
  const float* fx_b2 = (const float*)d_in[15];
  const float* fy_w1 = (const float*)d_in[16];
  const float* fy_b1 = (const float*)d_in[17];
  const float* fy_w2 = (const float*)d_in[18];
  const float* fy_b2 = (const float*)d_in[19];
  const float* feta_w1 = (const float*)d_in[20];
  const float* feta_b1 = (const float*)d_in[21];
  const float* feta_w2 = (const float*)d_in[22];
  const float* feta_b2 = (const float*)d_in[23];
  const float* feta_w3 = (const float*)d_in[24];

  int N = in_sizes[0] / 7;
  int E = in_sizes[2] / 2;
  const int* src = ei;
  const int* dst = ei + E;

  float* ws = (float*)d_ws;
  float* goal = ws;                                        // 16 floats
  unsigned long long* goalkey = (unsigned long long*)(ws + 16);
  float* xa = ws + 32;                                     // N*64 f32
  float* xb = xa + (size_t)N * 64;                         // N*64 f32
  u16* yh = (u16*)(xb + (size_t)N * 64);                   // E*64 bf16
  u16* yl = yh + (size_t)E * 64;                           // E*64 bf16
  u16* wp = yl + (size_t)E * 64;                           // 57344 u16 weight frags
  u16* fxB1h = wp;          u16* fxB1l = wp + 12288;
  u16* fxB2h = wp + 24576;  u16* fxB2l = wp + 28672;
  u16* fyB1h = wp + 32768;  u16* fyB1l = wp + 40960;
  u16* fyB2h = wp + 49152;  u16* fyB2l = wp + 53248;

  hipMemsetAsync(goalkey, 0, sizeof(unsigned long long), stream);
  k_prep<<<14, 256, 0, stream>>>(fx_w1, fx_w2, fy_w1, fy_w2, wp);
  k_goal1<<<(N + 255) / 256, 256, 0, stream>>>(labels, N, goalkey);
  k_goal2<<<1, 64, 0, stream>>>(v, labels, goalkey, goal);
  k_hx<<<(N + 31) / 32, 256, 0, stream>>>(v, labels, goal, hx_w1, hx_b1, hx_w2, hx_b2, xa, N);
  k_hy<<<(E + 31) / 32, 256, 0, stream>>>(v, labels, src, dst, hy_w1, hy_b1, hy_w2, hy_b2, yh, yl, E);

  float* xc = xa;
  float* xo = xb;
  for (int t = 0; t < 3; ++t) {
    k_copy<<<(N * 16 + 255) / 256, 256, 0, stream>>>((const float4*)xc, (float4*)xo, N * 16);
    k_fx<<<(E + 63) / 64, 256, 0, stream>>>(xc, yh, yl, src, dst,
                                            fxB1h, fxB1l, fx_b1, fxB2h, fxB2l, fx_b2, xo, E);
    float* tmp = xc; xc = xo; xo = tmp;
    k_fy<<<(E + 63) / 64, 256, 0, stream>>>(xc, yh, yl, src, dst,
                                            fyB1h, fyB1l, fy_b1, fyB2h, fyB2l, fy_b2, E);
  }
  k_feta<<<(N + 31) / 32, 256, 0, stream>>>(xc, feta_w1, feta_b1, feta_w2, feta_b2, feta_w3,
                                            (float*)d_out, N);
}

// Round 3
// 677.047 us; speedup vs baseline: 3.6010x; 1.1845x over previous
//
#include <hip/hip_runtime.h>
#include <math.h>

typedef unsigned short u16;
typedef unsigned int u32;
typedef unsigned long long u64;
typedef __attribute__((ext_vector_type(8))) short bf16x8;
typedef __attribute__((ext_vector_type(4))) float f32x4;

union U8s { bf16x8 v; u32 u[4]; u16 s[8]; };

#define GE 8  // nodes per wave for the VALU kernels

__device__ __forceinline__ float bcast(float v, int k) {
  return __int_as_float(__builtin_amdgcn_readlane(__float_as_int(v), k));
}

// pack top-16-bits of two floats into one u32
__device__ __forceinline__ u32 pack_hi2(float f0, float f1) {
  return __builtin_amdgcn_perm(__float_as_uint(f1), __float_as_uint(f0), 0x07060302u);
}

__device__ __forceinline__ float upf(u16 s) { return __uint_as_float(((u32)s) << 16); }

// split 8 fp32 -> bf16 hi frag + bf16 lo frag (truncation split)
__device__ __forceinline__ void dec8(const float* f, U8s& h, U8s& l) {
#pragma unroll
  for (int i = 0; i < 4; ++i) {
    float a = f[2 * i], b = f[2 * i + 1];
    float ra = a - __uint_as_float(__float_as_uint(a) & 0xffff0000u);
    float rb = b - __uint_as_float(__float_as_uint(b) & 0xffff0000u);
    h.u[i] = pack_hi2(a, b);
    l.u[i] = pack_hi2(ra, rb);
  }
}

// ---------------- goal: argmax over labels[:,1]; wave-reduced atomic ----------------
__global__ __launch_bounds__(256) void k_goal1(const float* __restrict__ labels, int N,
                                               u64* __restrict__ key) {
  int i = blockIdx.x * 256 + threadIdx.x;
  float val = (i < N) ? labels[2 * (size_t)i + 1] : 0.0f;
  u64 k = ((u64)__float_as_uint(fmaxf(val, 0.0f)) << 32) | (u32)(~(u32)i);
#pragma unroll
  for (int off = 32; off > 0; off >>= 1) {
    u64 o = __shfl_xor(k, off, 64);
    if (o > k) k = o;
  }
  if ((threadIdx.x & 63) == 0) atomicMax(key, k);
}

__global__ void k_goal2(const float* __restrict__ v, const float* __restrict__ labels,
                        const u64* __restrict__ key, float* __restrict__ goal) {
  int g = (int)(~(u32)(*key));
  int c = threadIdx.x;
  if (c < 9) goal[c] = (c < 7) ? v[7 * (size_t)g + c] : labels[2 * (size_t)g + (c - 7)];
}

// ---------------- vcp[N][16] = [v(7), lab0, lab1, 0...] ----------------
__global__ __launch_bounds__(256) void k_vc(const float* __restrict__ v,
                                            const float* __restrict__ labels,
                                            float* __restrict__ vcp, int N) {
  int tid = blockIdx.x * 256 + threadIdx.x;
  if (tid >= N * 16) return;
  int n = tid >> 4, c = tid & 15;
  float val = 0.f;
  if (c < 7) val = v[(size_t)n * 7 + c];
  else if (c == 7) val = labels[2 * (size_t)n];
  else if (c == 8) val = labels[2 * (size_t)n + 1];
  vcp[tid] = val;
}

// ---------------- weight prep: folded concat + bf16 hi/lo split, frag-major ----------
// frag-major: idx = ((c*4+t)*64 + lane)*8 + j, value = Wcat[c*32 + (lane>>4)*8 + j][t*16 + (lane&15)]
__global__ __launch_bounds__(256) void k_prep(const float* __restrict__ fxw1, const float* __restrict__ fxw2,
                                              const float* __restrict__ fyw1, const float* __restrict__ fyw2,
                                              const float* __restrict__ hyw1, const float* __restrict__ hyw2,
                                              u16* __restrict__ wp) {
  u16* fxB1h = wp;          u16* fxB1l = wp + 12288;
  u16* fxB2h = wp + 24576;  u16* fxB2l = wp + 28672;
  u16* fyB1h = wp + 32768;  u16* fyB1l = wp + 40960;
  u16* fyB2h = wp + 49152;  u16* fyB2l = wp + 53248;
  u16* hyB1h = wp + 57344;  u16* hyB1l = wp + 59392;
  u16* hyB2h = wp + 61440;  u16* hyB2l = wp + 65536;
  int tid = blockIdx.x * 256 + threadIdx.x;
  int which, id;
  u16 *oh, *ol;
  if (tid < 1536)      { which = 0; id = tid;        oh = fxB1h; ol = fxB1l; }
  else if (tid < 2048) { which = 1; id = tid - 1536; oh = fxB2h; ol = fxB2l; }
  else if (tid < 3072) { which = 2; id = tid - 2048; oh = fyB1h; ol = fyB1l; }
  else if (tid < 3584) { which = 3; id = tid - 3072; oh = fyB2h; ol = fyB2l; }
  else if (tid < 3840) { which = 4; id = tid - 3584; oh = hyB1h; ol = hyB1l; }
  else if (tid < 4352) { which = 5; id = tid - 3840; oh = hyB2h; ol = hyB2l; }
  else return;
  int lane = id & 63;
  int q = lane >> 4, col = lane & 15;
  int c = id >> 8, t = (id >> 6) & 3;
#pragma unroll
  for (int j = 0; j < 8; ++j) {
    int k = c * 32 + q * 8 + j;
    int n = t * 16 + col;
    float w;
    if (which == 0) {
      w = (k < 64)  ? fxw1[k * 64 + n] + fxw1[(k + 64) * 64 + n]
        : (k < 128) ? fxw1[(k + 64) * 64 + n] - fxw1[(k - 64) * 64 + n]
                    : fxw1[(k + 64) * 64 + n];
    } else if (which == 1) {
      w = fxw2[k * 64 + n];
    } else if (which == 2) {
      w = (k < 64) ? fyw1[k * 64 + n] + fyw1[(k + 64) * 64 + n]
                   : fyw1[(k + 64) * 64 + n] - fyw1[(k - 64) * 64 + n];
    } else if (which == 3) {
      w = fyw2[k * 64 + n];
    } else if (which == 4) {
      // hy: Wcat[32][64]: k<=8 -> W0+W1 (vcj), 16<=k<=24 -> W2-W0 (vci), else 0
      if (k <= 8)                w = hyw1[k * 64 + n] + hyw1[(k + 9) * 64 + n];
      else if (k >= 16 && k <= 24) w = hyw1[(k + 2) * 64 + n] - hyw1[(k - 16) * 64 + n];
      else                       w = 0.f;
    } else {
      w = hyw2[k * 64 + n];
    }
    u32 u = __float_as_uint(w);
    u32 hr = (u + 0x7fffu + ((u >> 16) & 1u)) >> 16;
    float rres = w - __uint_as_float(hr << 16);
    u32 u2 = __float_as_uint(rres);
    u32 lr = (u2 + 0x7fffu + ((u2 >> 16) & 1u)) >> 16;
    oh[id * 8 + j] = (u16)hr;
    ol[id * 8 + j] = (u16)lr;
  }
}

// ---------------- CSR build ----------------
__global__ __launch_bounds__(256) void k_hist(const int* __restrict__ dst, int E,
                                              int* __restrict__ deg) {
  int e = blockIdx.x * 256 + threadIdx.x;
  if (e < E) atomicAdd(&deg[dst[e]], 1);
}

__global__ __launch_bounds__(256) void k_scan1(const int* __restrict__ deg, int N,
                                               int* __restrict__ bsum) {
  __shared__ int red[256];
  int b = blockIdx.x;
  int s = 0;
  for (int i = threadIdx.x; i < 1024; i += 256) {
    int idx = b * 1024 + i;
    s += (idx < N) ? deg[idx] : 0;
  }
  red[threadIdx.x] = s; __syncthreads();
  for (int st = 128; st > 0; st >>= 1) {
    if (threadIdx.x < st) red[threadIdx.x] += red[threadIdx.x + st];
    __syncthreads();
  }
  if (threadIdx.x == 0) bsum[b] = red[0];
}

__global__ void k_scan2(const int* __restrict__ bsum, int B, int* __restrict__ boff,
                        int* __restrict__ rowptr, int N, int E) {
  if (threadIdx.x == 0) {
    int acc = 0;
    for (int i = 0; i < B; ++i) { boff[i] = acc; acc += bsum[i]; }
    rowptr[N] = E;
  }
}

__global__ __launch_bounds__(256) void k_scan3(const int* __restrict__ deg,
                                               const int* __restrict__ boff, int N,
                                               int* __restrict__ rowptr, int* __restrict__ cursor) {
  __shared__ int lsum[256];
  int b = blockIdx.x;
  int tid = threadIdx.x;
  int base_i = b * 1024 + tid * 4;
  int loc[4]; int s = 0;
#pragma unroll
  for (int j = 0; j < 4; ++j) {
    int v = (base_i + j < N) ? deg[base_i + j] : 0;
    loc[j] = s; s += v;
  }
  lsum[tid] = s; __syncthreads();
  for (int st = 1; st < 256; st <<= 1) {
    int add = (tid >= st) ? lsum[tid - st] : 0;
    __syncthreads();
    lsum[tid] += add;
    __syncthreads();
  }
  int toff = boff[b] + lsum[tid] - s;
#pragma unroll
  for (int j = 0; j < 4; ++j) {
    if (base_i + j < N) {
      int r = toff + loc[j];
      rowptr[base_i + j] = r;
      cursor[base_i + j] = r;
    }
  }
}

__global__ __launch_bounds__(256) void k_scatter(const int* __restrict__ dst, int E,
                                                 int* __restrict__ cursor, int* __restrict__ eid) {
  int e = blockIdx.x * 256 + threadIdx.x;
  if (e < E) {
    int pos = atomicAdd(&cursor[dst[e]], 1);
    eid[pos] = e;
  }
}

// ---------------- x0 = MLP2([vc, goal, d, d*d]) , 36 -> 64 -> 64 (VALU; small) ----------
__global__ __launch_bounds__(256) void k_hx(const float* __restrict__ v,
                                            const float* __restrict__ labels,
                                            const float* __restrict__ goal,
                                            const float* __restrict__ w1, const float* __restrict__ b1,
                                            const float* __restrict__ w2, const float* __restrict__ b2,
                                            float* __restrict__ xout, int N) {
  int lane = threadIdx.x & 63;
  int wid = (blockIdx.x * blockDim.x + threadIdx.x) >> 6;
  int base = wid * GE;
  int c = lane % 9;
  float f[GE];
#pragma unroll
  for (int e = 0; e < GE; ++e) {
    int i = base + e; if (i >= N) i = N - 1;
    float fv = 0.f;
    if (lane < 36) {
      float vcv = (c < 7) ? v[7 * i + c] : labels[2 * i + (c - 7)];
      float gl = goal[c];
      float d = vcv - gl;
      fv = (lane < 9) ? vcv : (lane < 18) ? gl : (lane < 27) ? d : d * d;
    }
    f[e] = fv;
  }
  float acc[GE];
  float bb = b1[lane];
#pragma unroll
  for (int e = 0; e < GE; ++e) acc[e] = bb;
  for (int k = 0; k < 36; ++k) {
    float w = w1[k * 64 + lane];
#pragma unroll
    for (int e = 0; e < GE; ++e) acc[e] = fmaf(bcast(f[e], k), w, acc[e]);
  }
  float h[GE];
#pragma unroll
  for (int e = 0; e < GE; ++e) h[e] = fmaxf(acc[e], 0.f);
  float b2v = b2[lane];
#pragma unroll
  for (int e = 0; e < GE; ++e) acc[e] = b2v;
#pragma unroll 4
  for (int k = 0; k < 64; ++k) {
    float w = w2[k * 64 + lane];
#pragma unroll
    for (int e = 0; e < GE; ++e) acc[e] = fmaf(bcast(h[e], k), w, acc[e]);
  }
#pragma unroll
  for (int e = 0; e < GE; ++e) {
    int i = base + e;
    if (i < N) xout[(size_t)i * 64 + lane] = acc[e];
  }
}

// ---------------- hy (MFMA): y0 = MLP2([vcj(16) ; vci(16)] folded), K=32 ----------
__global__ __launch_bounds__(256) void k_hy(
    const float* __restrict__ vcp,
    const int* __restrict__ src, const int* __restrict__ dst,
    const u16* __restrict__ B1h, const u16* __restrict__ B1l, const float* __restrict__ b1,
    const u16* __restrict__ B2h, const u16* __restrict__ B2l, const float* __restrict__ b2,
    u16* __restrict__ yh, u16* __restrict__ yl, int E) {
  __shared__ float hbuf[4][16 * 68];
  const int lane = threadIdx.x & 63;
  const int wv = threadIdx.x >> 6;
  const int m = lane & 15, q = lane >> 4;
  const int base = blockIdx.x * 64 + wv * 16;
  int em = base + m; if (em >= E) em = E - 1;
  const int node = (q < 2) ? dst[em] : src[em];
  const float* p = vcp + (size_t)node * 16 + (q & 1) * 8;
  float f[8];
  *(float4*)(f + 0) = *(const float4*)(p);
  *(float4*)(f + 4) = *(const float4*)(p + 4);
  U8s Ah, Al;
  dec8(f, Ah, Al);

  f32x4 acc[4];
#pragma unroll
  for (int t = 0; t < 4; ++t) { float bv = b1[t * 16 + m]; acc[t] = (f32x4){bv, bv, bv, bv}; }
#pragma unroll
  for (int t = 0; t < 4; ++t) {
    bf16x8 bh = *(const bf16x8*)(B1h + ((size_t)t * 64 + lane) * 8);
    bf16x8 bl = *(const bf16x8*)(B1l + ((size_t)t * 64 + lane) * 8);
    acc[t] = __builtin_amdgcn_mfma_f32_16x16x32_bf16(Ah.v, bh, acc[t], 0, 0, 0);
    acc[t] = __builtin_amdgcn_mfma_f32_16x16x32_bf16(Al.v, bh, acc[t], 0, 0, 0);
    acc[t] = __builtin_amdgcn_mfma_f32_16x16x32_bf16(Ah.v, bl, acc[t], 0, 0, 0);
  }

  float* hb = hbuf[wv];
#pragma unroll
  for (int t = 0; t < 4; ++t)
#pragma unroll
    for (int r = 0; r < 4; ++r)
      hb[(q * 4 + r) * 68 + t * 16 + m] = fmaxf(acc[t][r], 0.f);
  __syncthreads();

  float fh[16];
  const float* hr = hb + m * 68 + q * 8;
  *(float4*)(fh + 0)  = *(const float4*)(hr);
  *(float4*)(fh + 4)  = *(const float4*)(hr + 4);
  *(float4*)(fh + 8)  = *(const float4*)(hr + 32);
  *(float4*)(fh + 12) = *(const float4*)(hr + 36);
  U8s A2h[2], A2l[2];
  dec8(fh + 0, A2h[0], A2l[0]);
  dec8(fh + 8, A2h[1], A2l[1]);
  __syncthreads();

  f32x4 acc2[4];
#pragma unroll
  for (int t = 0; t < 4; ++t) { float bv = b2[t * 16 + m]; acc2[t] = (f32x4){bv, bv, bv, bv}; }
#pragma unroll
  for (int c = 0; c < 2; ++c) {
#pragma unroll
    for (int t = 0; t < 4; ++t) {
      bf16x8 bh = *(const bf16x8*)(B2h + ((size_t)(c * 4 + t) * 64 + lane) * 8);
      bf16x8 bl = *(const bf16x8*)(B2l + ((size_t)(c * 4 + t) * 64 + lane) * 8);
      acc2[t] = __builtin_amdgcn_mfma_f32_16x16x32_bf16(A2h[c].v, bh, acc2[t], 0, 0, 0);
      acc2[t] = __builtin_amdgcn_mfma_f32_16x16x32_bf16(A2l[c].v, bh, acc2[t], 0, 0, 0);
      acc2[t] = __builtin_amdgcn_mfma_f32_16x16x32_bf16(A2h[c].v, bl, acc2[t], 0, 0, 0);
    }
  }

#pragma unroll
  for (int t = 0; t < 4; ++t)
#pragma unroll
    for (int r = 0; r < 4; ++r)
      hb[(q * 4 + r) * 68 + t * 16 + m] = acc2[t][r];
  __syncthreads();

  int row = base + m;
  if (row < E) {
    float ov[16];
    const float* orow = hb + m * 68 + q * 16;
    *(float4*)(ov + 0)  = *(const float4*)(orow);
    *(float4*)(ov + 4)  = *(const float4*)(orow + 4);
    *(float4*)(ov + 8)  = *(const float4*)(orow + 8);
    *(float4*)(ov + 12) = *(const float4*)(orow + 12);
    size_t yo = (size_t)row * 64 + q * 16;
    U8s Oh0, Oh1, Ol0, Ol1;
    dec8(ov + 0, Oh0, Ol0);
    dec8(ov + 8, Oh1, Ol1);
    *(bf16x8*)(yh + yo)     = Oh0.v;
    *(bf16x8*)(yh + yo + 8) = Oh1.v;
    *(bf16x8*)(yl + yo)     = Ol0.v;
    *(bf16x8*)(yl + yo + 8) = Ol1.v;
  }
}

// ---------------- fx: MFMA, writes m[E][64] fp32 (no atomics) ----------
__global__ __launch_bounds__(256) void k_fx(
    const float* __restrict__ x, const u16* __restrict__ yh, const u16* __restrict__ yl,
    const int* __restrict__ src, const int* __restrict__ dst,
    const u16* __restrict__ B1h, const u16* __restrict__ B1l, const float* __restrict__ b1,
    const u16* __restrict__ B2h, const u16* __restrict__ B2l, const float* __restrict__ b2,
    float* __restrict__ mb, int E) {
  __shared__ float hbuf[4][16 * 68];
  const int lane = threadIdx.x & 63;
  const int wv = threadIdx.x >> 6;
  const int m = lane & 15, q = lane >> 4;
  const int base = blockIdx.x * 64 + wv * 16;
  int em = base + m; if (em >= E) em = E - 1;
  const int si = src[em], di = dst[em];

  const float* ps = x + (size_t)si * 64 + q * 8;
  const float* pd = x + (size_t)di * 64 + q * 8;
  float fs[16], fd[16];
  *(float4*)(fs + 0)  = *(const float4*)(ps);
  *(float4*)(fs + 4)  = *(const float4*)(ps + 4);
  *(float4*)(fs + 8)  = *(const float4*)(ps + 32);
  *(float4*)(fs + 12) = *(const float4*)(ps + 36);
  *(float4*)(fd + 0)  = *(const float4*)(pd);
  *(float4*)(fd + 4)  = *(const float4*)(pd + 4);
  *(float4*)(fd + 8)  = *(const float4*)(pd + 32);
  *(float4*)(fd + 12) = *(const float4*)(pd + 36);

  U8s Ah[6], Al[6];
  dec8(fs + 0, Ah[0], Al[0]);
  dec8(fs + 8, Ah[1], Al[1]);
  dec8(fd + 0, Ah[2], Al[2]);
  dec8(fd + 8, Ah[3], Al[3]);
  const u16* pyh = yh + (size_t)em * 64 + q * 8;
  const u16* pyl = yl + (size_t)em * 64 + q * 8;
  Ah[4].v = *(const bf16x8*)(pyh);      Ah[5].v = *(const bf16x8*)(pyh + 32);
  Al[4].v = *(const bf16x8*)(pyl);      Al[5].v = *(const bf16x8*)(pyl + 32);

  f32x4 acc[4];
#pragma unroll
  for (int t = 0; t < 4; ++t) { float bv = b1[t * 16 + m]; acc[t] = (f32x4){bv, bv, bv, bv}; }
#pragma unroll
  for (int c = 0; c < 6; ++c) {
#pragma unroll
    for (int t = 0; t < 4; ++t) {
      bf16x8 bh = *(const bf16x8*)(B1h + ((size_t)(c * 4 + t) * 64 + lane) * 8);
      bf16x8 bl = *(const bf16x8*)(B1l + ((size_t)(c * 4 + t) * 64 + lane) * 8);
      acc[t] = __builtin_amdgcn_mfma_f32_16x16x32_bf16(Ah[c].v, bh, acc[t], 0, 0, 0);
      acc[t] = __builtin_amdgcn_mfma_f32_16x16x32_bf16(Al[c].v, bh, acc[t], 0, 0, 0);
      acc[t] = __builtin_amdgcn_mfma_f32_16x16x32_bf16(Ah[c].v, bl, acc[t], 0, 0, 0);
    }
  }

  float* hb = hbuf[wv];
#pragma unroll
  for (int t = 0; t < 4; ++t)
#pragma unroll
    for (int r = 0; r < 4; ++r)
      hb[(q * 4 + r) * 68 + t * 16 + m] = fmaxf(acc[t][r], 0.f);
  __syncthreads();

  float fh[16];
  const float* hr = hb + m * 68 + q * 8;
  *(float4*)(fh + 0)  = *(const float4*)(hr);
  *(float4*)(fh + 4)  = *(const float4*)(hr + 4);
  *(float4*)(fh + 8)  = *(const float4*)(hr + 32);
  *(float4*)(fh + 12) = *(const float4*)(hr + 36);
  U8s A2h[2], A2l[2];
  dec8(fh + 0, A2h[0], A2l[0]);
  dec8(fh + 8, A2h[1], A2l[1]);

  f32x4 acc2[4];
#pragma unroll
  for (int t = 0; t < 4; ++t) { float bv = b2[t * 16 + m]; acc2[t] = (f32x4){bv, bv, bv, bv}; }
#pragma unroll
  for (int c = 0; c < 2; ++c) {
#pragma unroll
    for (int t = 0; t < 4; ++t) {
      bf16x8 bh = *(const bf16x8*)(B2h + ((size_t)(c * 4 + t) * 64 + lane) * 8);
      bf16x8 bl = *(const bf16x8*)(B2l + ((size_t)(c * 4 + t) * 64 + lane) * 8);
      acc2[t] = __builtin_amdgcn_mfma_f32_16x16x32_bf16(A2h[c].v, bh, acc2[t], 0, 0, 0);
      acc2[t] = __builtin_amdgcn_mfma_f32_16x16x32_bf16(A2l[c].v, bh, acc2[t], 0, 0, 0);
      acc2[t] = __builtin_amdgcn_mfma_f32_16x16x32_bf16(A2h[c].v, bl, acc2[t], 0, 0, 0);
    }
  }

  // store m in C-layout directly (row=edge, col): no transpose, no atomics
#pragma unroll
  for (int t = 0; t < 4; ++t)
#pragma unroll
    for (int r = 0; r < 4; ++r) {
      int e2 = base + q * 4 + r;
      if (e2 < E) mb[(size_t)e2 * 64 + t * 16 + m] = acc2[t][r];
    }
}

// ---------------- agg: xnew[n] = max(x[n], max over in-edges m[e]) ----------
__global__ __launch_bounds__(256) void k_agg(const float* __restrict__ x,
                                             const float* __restrict__ mb,
                                             const int* __restrict__ rowptr,
                                             const int* __restrict__ eid,
                                             float* __restrict__ xnew, int N) {
  int w = blockIdx.x * 4 + (threadIdx.x >> 6);
  int lane = threadIdx.x & 63;
  if (w >= N) return;
  int s = rowptr[w], e = rowptr[w + 1];
  float acc = x[(size_t)w * 64 + lane];
  int j = s;
  for (; j + 1 < e; j += 2) {
    int e0 = eid[j], e1 = eid[j + 1];
    float a = mb[(size_t)e0 * 64 + lane];
    float b = mb[(size_t)e1 * 64 + lane];
    acc = fmaxf(acc, fmaxf(a, b));
  }
  if (j < e) acc = fmaxf(acc, mb[(size_t)eid[j] * 64 + lane]);
  xnew[(size_t)w * 64 + lane] = acc;
}

// ---------------- fy: MFMA, y = max(y, MLP2([xd,xs] folded)), K=128 ----------
__global__ __launch_bounds__(256) void k_fy(
    const float* __restrict__ x, u16* __restrict__ yh, u16* __restrict__ yl,
    const int* __restrict__ src, const int* __restrict__ dst,
    const u16* __restrict__ B1h, const u16* __restrict__ B1l, const float* __restrict__ b1,
    const u16* __restrict__ B2h, const u16* __restrict__ B2l, const float* __restrict__ b2,
    int E) {
  __shared__ float hbuf[4][16 * 68];
  const int lane = threadIdx.x & 63;
  const int wv = threadIdx.x >> 6;
  const int m = lane & 15, q = lane >> 4;
  const int base = blockIdx.x * 64 + wv * 16;
  int em = base + m; if (em >= E) em = E - 1;
  const int si = src[em], di = dst[em];

  const float* ps = x + (size_t)si * 64 + q * 8;
  const float* pd = x + (size_t)di * 64 + q * 8;
  float fs[16], fd[16];
  *(float4*)(fd + 0)  = *(const float4*)(pd);
  *(float4*)(fd + 4)  = *(const float4*)(pd + 4);
  *(float4*)(fd + 8)  = *(const float4*)(pd + 32);
  *(float4*)(fd + 12) = *(const float4*)(pd + 36);
  *(float4*)(fs + 0)  = *(const float4*)(ps);
  *(float4*)(fs + 4)  = *(const float4*)(ps + 4);
  *(float4*)(fs + 8)  = *(const float4*)(ps + 32);
  *(float4*)(fs + 12) = *(const float4*)(ps + 36);

  U8s Ah[4], Al[4];
  dec8(fd + 0, Ah[0], Al[0]);
  dec8(fd + 8, Ah[1], Al[1]);
  dec8(fs + 0, Ah[2], Al[2]);
  dec8(fs + 8, Ah[3], Al[3]);

  f32x4 acc[4];
#pragma unroll
  for (int t = 0; t < 4; ++t) { float bv = b1[t * 16 + m]; acc[t] = (f32x4){bv, bv, bv, bv}; }
#pragma unroll
  for (int c = 0; c < 4; ++c) {
#pragma unroll
    for (int t = 0; t < 4; ++t) {
      bf16x8 bh = *(const bf16x8*)(B1h + ((size_t)(c * 4 + t) * 64 + lane) * 8);
      bf16x8 bl = *(const bf16x8*)(B1l + ((size_t)(c * 4 + t) * 64 + lane) * 8);
      acc[t] = __builtin_amdgcn_mfma_f32_16x16x32_bf16(Ah[c].v, bh, acc[t], 0, 0, 0);
      acc[t] = __builtin_amdgcn_mfma_f32_16x16x32_bf16(Al[c].v, bh, acc[t], 0, 0, 0);
      acc[t] = __builtin_amdgcn_mfma_f32_16x16x32_bf16(Ah[c].v, bl, acc[t], 0, 0, 0);
    }
  }

  float* hb = hbuf[wv];
#pragma unroll
  for (int t = 0; t < 4; ++t)
#pragma unroll
    for (int r = 0; r < 4; ++r)
      hb[(q * 4 + r) * 68 + t * 16 + m] = fmaxf(acc[t][r], 0.f);
  __syncthreads();

  float fh[16];
  const float* hr = hb + m * 68 + q * 8;
  *(float4*)(fh + 0)  = *(const float4*)(hr);
  *(float4*)(fh + 4)  = *(const float4*)(hr + 4);
  *(float4*)(fh + 8)  = *(const float4*)(hr + 32);
  *(float4*)(fh + 12) = *(const float4*)(hr + 36);
  U8s A2h[2], A2l[2];
  dec8(fh + 0, A2h[0], A2l[0]);
  dec8(fh + 8, A2h[1], A2l[1]);
  __syncthreads();

  f32x4 acc2[4];
#pragma unroll
  for (int t = 0; t < 4; ++t) { float bv = b2[t * 16 + m]; acc2[t] = (f32x4){bv, bv, bv, bv}; }
#pragma unroll
  for (int c = 0; c < 2; ++c) {
#pragma unroll
    for (int t = 0; t < 4; ++t) {
      bf16x8 bh = *(const bf16x8*)(B2h + ((size_t)(c * 4 + t) * 64 + lane) * 8);
      bf16x8 bl = *(const bf16x8*)(B2l + ((size_t)(c * 4 + t) * 64 + lane) * 8);
      acc2[t] = __builtin_amdgcn_mfma_f32_16x16x32_bf16(A2h[c].v, bh, acc2[t], 0, 0, 0);
      acc2[t] = __builtin_amdgcn_mfma_f32_16x16x32_bf16(A2l[c].v, bh, acc2[t], 0, 0, 0);
      acc2[t] = __builtin_amdgcn_mfma_f32_16x16x32_bf16(A2h[c].v, bl, acc2[t], 0, 0, 0);
    }
  }

#pragma unroll
  for (int t = 0; t < 4; ++t)
#pragma unroll
    for (int r = 0; r < 4; ++r)
      hb[(q * 4 + r) * 68 + t * 16 + m] = acc2[t][r];
  __syncthreads();

  int row = base + m;
  if (row < E) {
    float ov[16];
    const float* orow = hb + m * 68 + q * 16;
    *(float4*)(ov + 0)  = *(const float4*)(orow);
    *(float4*)(ov + 4)  = *(const float4*)(orow + 4);
    *(float4*)(ov + 8)  = *(const float4*)(orow + 8);
    *(float4*)(ov + 12) = *(const float4*)(orow + 12);
    size_t yo = (size_t)row * 64 + q * 16;
    U8s Hh0, Hh1, Hl0, Hl1;
    Hh0.v = *(const bf16x8*)(yh + yo);     Hh1.v = *(const bf16x8*)(yh + yo + 8);
    Hl0.v = *(const bf16x8*)(yl + yo);     Hl1.v = *(const bf16x8*)(yl + yo + 8);
    float nv[16];
#pragma unroll
    for (int i = 0; i < 8; ++i) {
      nv[i]     = fmaxf(upf(Hh0.s[i]) + upf(Hl0.s[i]), ov[i]);
      nv[8 + i] = fmaxf(upf(Hh1.s[i]) + upf(Hl1.s[i]), ov[8 + i]);
    }
    U8s Oh0, Oh1, Ol0, Ol1;
    dec8(nv + 0, Oh0, Ol0);
    dec8(nv + 8, Oh1, Ol1);
    *(bf16x8*)(yh + yo)     = Oh0.v;
    *(bf16x8*)(yh + yo + 8) = Oh1.v;
    *(bf16x8*)(yl + yo)     = Ol0.v;
    *(bf16x8*)(yl + yo + 8) = Ol1.v;
  }
}

// ---------------- out = feta(x): 64 -> 64 -> 64 -> 1 (VALU; small) ----------------
__global__ __launch_bounds__(256) void k_feta(const float* __restrict__ x,
                                              const float* __restrict__ w1, const float* __restrict__ b1,
                                              const float* __restrict__ w2, const float* __restrict__ b2,
                                              const float* __restrict__ w3,
                                              float* __restrict__ out, int N) {
  int lane = threadIdx.x & 63;
  int wid = (blockIdx.x * blockDim.x + threadIdx.x) >> 6;
  int base = wid * GE;
  float xr[GE];
#pragma unroll
  for (int e = 0; e < GE; ++e) {
    int i = base + e; if (i >= N) i = N - 1;
    xr[e] = x[(size_t)i * 64 + lane];
  }
  float acc[GE];
  float bb = b1[lane];
#pragma unroll
  for (int e = 0; e < GE; ++e) acc[e] = bb;
#pragma unroll 4
  for (int k = 0; k < 64; ++k) {
    float w = w1[k * 64 + lane];
#pragma unroll
    for (int e = 0; e < GE; ++e) acc[e] = fmaf(bcast(xr[e], k), w, acc[e]);
  }
  float h1[GE];
#pragma unroll
  for (int e = 0; e < GE; ++e) h1[e] = fmaxf(acc[e], 0.f);
  float b2v = b2[lane];
#pragma unroll
  for (int e = 0; e < GE; ++e) acc[e] = b2v;
#pragma unroll 4
  for (int k = 0; k < 64; ++k) {
    float w = w2[k * 64 + lane];
#pragma unroll
    for (int e = 0; e < GE; ++e) acc[e] = fmaf(bcast(h1[e], k), w, acc[e]);
  }
  float w3l = w3[lane];
#pragma unroll
  for (int e = 0; e < GE; ++e) {
    float r = fmaxf(acc[e], 0.f) * w3l;
    for (int off = 32; off > 0; off >>= 1) r += __shfl_xor(r, off, 64);
    int i = base + e;
    if (lane == 0 && i < N) out[i] = r;
  }
}

extern "C" void kernel_launch(void* const* d_in, const int* in_sizes, int n_in,
                              void* d_out, int out_size, void* d_ws, size_t ws_size,
                              hipStream_t stream) {
  const float* v      = (const float*)d_in[0];
  const float* labels = (const float*)d_in[1];
  const int*   ei     = (const int*)d_in[2];
  const float* hx_w1 = (const float*)d_in[4];
  const float* hx_b1 = (const float*)d_in[5];
  const float* hx_w2 = (const float*)d_in[6];
  const float* hx_b2 = (const float*)d_in[7];
  const float* hy_w1 = (const float*)d_in[8];
  const float* hy_b1 = (const float*)d_in[9];
  const float* hy_w2 = (const float*)d_in[10];
  const float* hy_b2 = (const float*)d_in[11];
  const float* fx_w1 = (const float*)d_in[12];
  const float* fx_b1 = (const float*)d_in[13];
  const float* fx_w2 = (const float*)d_in[14];
  const float* fx_b2 = (const float*)d_in[15];
  const float* fy_w1 = (const float*)d_in[16];
  const float* fy_b1 = (const float*)d_in[17];
  const float* fy_w2 = (const float*)d_in[18];
  const float* fy_b2 = (const float*)d_in[19];
  const float* feta_w1 = (const float*)d_in[20];
  const float* feta_b1 = (const float*)d_in[21];
  const float* feta_w2 = (const float*)d_in[22];
  const float* feta_b2 = (const float*)d_in[23];
  const float* feta_w3 = (const float*)d_in[24];

  int N = in_sizes[0] / 7;
  int E = in_sizes[2] / 2;
  const int* src = ei;
  const int* dst = ei + E;

  char* wsb = (char*)d_ws;
  float* goal = (float*)wsb;                                     // 16 f
  u64* goalkey = (u64*)(wsb + 16 * 4);
  float* xa = (float*)(wsb + 32 * 4);                            // N*64 f
  float* xb = xa + (size_t)N * 64;                               // N*64 f
  u16* yh = (u16*)(xb + (size_t)N * 64);                         // E*64 u16
  u16* yl = yh + (size_t)E * 64;                                 // E*64 u16
  u16* wp = yl + (size_t)E * 64;                                 // 69632 u16
  float* mb = (float*)(wp + 69632);                              // E*64 f
  float* vcp = mb + (size_t)E * 64;                              // N*16 f
  int* deg = (int*)(vcp + (size_t)N * 16);                       // N
  int* rowptr = deg + N;                                         // N+1
  int* cursor = rowptr + N + 1;                                  // N
  int* eid = cursor + N;                                         // E
  int* bsum = eid + E;                                           // 64
  int* boff = bsum + 64;                                         // 64

  u16* fxB1h = wp;          u16* fxB1l = wp + 12288;
  u16* fxB2h = wp + 24576;  u16* fxB2l = wp + 28672;
  u16* fyB1h = wp + 32768;  u16* fyB1l = wp + 40960;
  u16* fyB2h = wp + 49152;  u16* fyB2l = wp + 53248;
  u16* hyB1h = wp + 57344;  u16* hyB1l = wp + 59392;
  u16* hyB2h = wp + 61440;  u16* hyB2l = wp + 65536;

  int SB = (N + 1023) / 1024;  // scan blocks

  hipMemsetAsync(goalkey, 0, sizeof(u64), stream);
  hipMemsetAsync(deg, 0, (size_t)N * 4, stream);
  k_prep<<<17, 256, 0, stream>>>(fx_w1, fx_w2, fy_w1, fy_w2, hy_w1, hy_w2, wp);
  k_vc<<<(N * 16 + 255) / 256, 256, 0, stream>>>(v, labels, vcp, N);
  k_goal1<<<(N + 255) / 256, 256, 0, stream>>>(labels, N, goalkey);
  k_goal2<<<1, 64, 0, stream>>>(v, labels, goalkey, goal);
  k_hist<<<(E + 255) / 256, 256, 0, stream>>>(dst, E, deg);
  k_scan1<<<SB, 256, 0, stream>>>(deg, N, bsum);
  k_scan2<<<1, 64, 0, stream>>>(bsum, SB, boff, rowptr, N, E);
  k_scan3<<<SB, 256, 0, stream>>>(deg, boff, N, rowptr, cursor);
  k_scatter<<<(E + 255) / 256, 256, 0, stream>>>(dst, E, cursor, eid);

  k_hx<<<(N + 31) / 32, 256, 0, stream>>>(v, labels, goal, hx_w1, hx_b1, hx_w2, hx_b2, xa, N);
  k_hy<<<(E + 63) / 64, 256, 0, stream>>>(vcp, src, dst,
                                          hyB1h, hyB1l, hy_b1, hyB2h, hyB2l, hy_b2, yh, yl, E);

  float* xc = xa;
  float* xo = xb;
  for (int t = 0; t < 3; ++t) {
    k_fx<<<(E + 63) / 64, 256, 0, stream>>>(xc, yh, yl, src, dst,
                                            fxB1h, fxB1l, fx_b1, fxB2h, fxB2l, fx_b2, mb, E);
    k_agg<<<(N + 3) / 4, 256, 0, stream>>>(xc, mb, rowptr, eid, xo, N);
    float* tmp = xc; xc = xo; xo = tmp;
    k_fy<<<(E + 63) / 64, 256, 0, stream>>>(xc, yh, yl, src, dst,
                                            fyB1h, fyB1l, fy_b1, fyB2h, fyB2l, fy_b2, E);
  }
  k_feta<<<(N + 31) / 32, 256, 0, stream>>>(xc, feta_w1, feta_b1, feta_w2, feta_b2, feta_w3,
                                            (float*)d_out, N);
}

// Round 4
// 609.704 us; speedup vs baseline: 3.9987x; 1.1105x over previous
//
#include <hip/hip_runtime.h>
#include <math.h>

typedef unsigned short u16;
typedef unsigned int u32;
typedef unsigned long long u64;
typedef __attribute__((ext_vector_type(8))) short bf16x8;
typedef __attribute__((ext_vector_type(4))) float f32x4;

union U8s { bf16x8 v; u32 u[4]; u16 s[8]; };

#define GE 8  // nodes per wave for the VALU kernels

__device__ __forceinline__ float bcast(float v, int k) {
  return __int_as_float(__builtin_amdgcn_readlane(__float_as_int(v), k));
}

__device__ __forceinline__ void atomicMaxF(float* addr, float val) {
  if (val >= 0.0f) {
    atomicMax((int*)addr, __float_as_int(val));
  } else {
    atomicMin((unsigned int*)addr, (unsigned int)__float_as_int(val));
  }
}

// pack top-16-bits of two floats into one u32
__device__ __forceinline__ u32 pack_hi2(float f0, float f1) {
  return __builtin_amdgcn_perm(__float_as_uint(f1), __float_as_uint(f0), 0x07060302u);
}

__device__ __forceinline__ float upf(u16 s) { return __uint_as_float(((u32)s) << 16); }

// split 8 fp32 -> bf16 hi frag + bf16 lo frag (truncation split)
__device__ __forceinline__ void dec8(const float* f, U8s& h, U8s& l) {
#pragma unroll
  for (int i = 0; i < 4; ++i) {
    float a = f[2 * i], b = f[2 * i + 1];
    float ra = a - __uint_as_float(__float_as_uint(a) & 0xffff0000u);
    float rb = b - __uint_as_float(__float_as_uint(b) & 0xffff0000u);
    h.u[i] = pack_hi2(a, b);
    l.u[i] = pack_hi2(ra, rb);
  }
}

// ---------------- goal: argmax over labels[:,1]; wave-reduced atomic ----------------
__global__ __launch_bounds__(256) void k_goal1(const float* __restrict__ labels, int N,
                                               u64* __restrict__ key) {
  int i = blockIdx.x * 256 + threadIdx.x;
  float val = (i < N) ? labels[2 * (size_t)i + 1] : 0.0f;
  u64 k = ((u64)__float_as_uint(fmaxf(val, 0.0f)) << 32) | (u32)(~(u32)i);
#pragma unroll
  for (int off = 32; off > 0; off >>= 1) {
    u64 o = __shfl_xor(k, off, 64);
    if (o > k) k = o;
  }
  if ((threadIdx.x & 63) == 0) atomicMax(key, k);
}

__global__ void k_goal2(const float* __restrict__ v, const float* __restrict__ labels,
                        const u64* __restrict__ key, float* __restrict__ goal) {
  int g = (int)(~(u32)(*key));
  int c = threadIdx.x;
  if (c < 9) goal[c] = (c < 7) ? v[7 * (size_t)g + c] : labels[2 * (size_t)g + (c - 7)];
}

// ---------------- vcp[N][16] = [v(7), lab0, lab1, 0...] ----------------
__global__ __launch_bounds__(256) void k_vc(const float* __restrict__ v,
                                            const float* __restrict__ labels,
                                            float* __restrict__ vcp, int N) {
  int tid = blockIdx.x * 256 + threadIdx.x;
  if (tid >= N * 16) return;
  int n = tid >> 4, c = tid & 15;
  float val = 0.f;
  if (c < 7) val = v[(size_t)n * 7 + c];
  else if (c == 7) val = labels[2 * (size_t)n];
  else if (c == 8) val = labels[2 * (size_t)n + 1];
  vcp[tid] = val;
}

// ---------------- weight prep: folded concat + bf16 hi/lo split, frag-major ----------
__global__ __launch_bounds__(256) void k_prep(const float* __restrict__ fxw1, const float* __restrict__ fxw2,
                                              const float* __restrict__ fyw1, const float* __restrict__ fyw2,
                                              const float* __restrict__ hyw1, const float* __restrict__ hyw2,
                                              u16* __restrict__ wp) {
  u16* fxB1h = wp;          u16* fxB1l = wp + 12288;
  u16* fxB2h = wp + 24576;  u16* fxB2l = wp + 28672;
  u16* fyB1h = wp + 32768;  u16* fyB1l = wp + 40960;
  u16* fyB2h = wp + 49152;  u16* fyB2l = wp + 53248;
  u16* hyB1h = wp + 57344;  u16* hyB1l = wp + 59392;
  u16* hyB2h = wp + 61440;  u16* hyB2l = wp + 65536;
  int tid = blockIdx.x * 256 + threadIdx.x;
  int which, id;
  u16 *oh, *ol;
  if (tid < 1536)      { which = 0; id = tid;        oh = fxB1h; ol = fxB1l; }
  else if (tid < 2048) { which = 1; id = tid - 1536; oh = fxB2h; ol = fxB2l; }
  else if (tid < 3072) { which = 2; id = tid - 2048; oh = fyB1h; ol = fyB1l; }
  else if (tid < 3584) { which = 3; id = tid - 3072; oh = fyB2h; ol = fyB2l; }
  else if (tid < 3840) { which = 4; id = tid - 3584; oh = hyB1h; ol = hyB1l; }
  else if (tid < 4352) { which = 5; id = tid - 3840; oh = hyB2h; ol = hyB2l; }
  else return;
  int lane = id & 63;
  int q = lane >> 4, col = lane & 15;
  int c = id >> 8, t = (id >> 6) & 3;
#pragma unroll
  for (int j = 0; j < 8; ++j) {
    int k = c * 32 + q * 8 + j;
    int n = t * 16 + col;
    float w;
    if (which == 0) {
      w = (k < 64)  ? fxw1[k * 64 + n] + fxw1[(k + 64) * 64 + n]
        : (k < 128) ? fxw1[(k + 64) * 64 + n] - fxw1[(k - 64) * 64 + n]
                    : fxw1[(k + 64) * 64 + n];
    } else if (which == 1) {
      w = fxw2[k * 64 + n];
    } else if (which == 2) {
      w = (k < 64) ? fyw1[k * 64 + n] + fyw1[(k + 64) * 64 + n]
                   : fyw1[(k + 64) * 64 + n] - fyw1[(k - 64) * 64 + n];
    } else if (which == 3) {
      w = fyw2[k * 64 + n];
    } else if (which == 4) {
      if (k <= 8)                  w = hyw1[k * 64 + n] + hyw1[(k + 9) * 64 + n];
      else if (k >= 16 && k <= 24) w = hyw1[(k + 2) * 64 + n] - hyw1[(k - 16) * 64 + n];
      else                         w = 0.f;
    } else {
      w = hyw2[k * 64 + n];
    }
    u32 u = __float_as_uint(w);
    u32 hr = (u + 0x7fffu + ((u >> 16) & 1u)) >> 16;
    float rres = w - __uint_as_float(hr << 16);
    u32 u2 = __float_as_uint(rres);
    u32 lr = (u2 + 0x7fffu + ((u2 >> 16) & 1u)) >> 16;
    oh[id * 8 + j] = (u16)hr;
    ol[id * 8 + j] = (u16)lr;
  }
}

// ---------------- CSR build ----------------
__global__ __launch_bounds__(256) void k_hist(const int* __restrict__ dst, int E,
                                              int* __restrict__ deg) {
  int e = blockIdx.x * 256 + threadIdx.x;
  if (e < E) atomicAdd(&deg[dst[e]], 1);
}

__global__ __launch_bounds__(256) void k_scan1(const int* __restrict__ deg, int N,
                                               int* __restrict__ bsum) {
  __shared__ int red[256];
  int b = blockIdx.x;
  int s = 0;
  for (int i = threadIdx.x; i < 1024; i += 256) {
    int idx = b * 1024 + i;
    s += (idx < N) ? deg[idx] : 0;
  }
  red[threadIdx.x] = s; __syncthreads();
  for (int st = 128; st > 0; st >>= 1) {
    if (threadIdx.x < st) red[threadIdx.x] += red[threadIdx.x + st];
    __syncthreads();
  }
  if (threadIdx.x == 0) bsum[b] = red[0];
}

__global__ void k_scan2(const int* __restrict__ bsum, int B, int* __restrict__ boff,
                        int* __restrict__ rowptr, int N, int E) {
  if (threadIdx.x == 0) {
    int acc = 0;
    for (int i = 0; i < B; ++i) { boff[i] = acc; acc += bsum[i]; }
    rowptr[N] = E;
  }
}

__global__ __launch_bounds__(256) void k_scan3(const int* __restrict__ deg,
                                               const int* __restrict__ boff, int N,
                                               int* __restrict__ rowptr, int* __restrict__ cursor) {
  __shared__ int lsum[256];
  int b = blockIdx.x;
  int tid = threadIdx.x;
  int base_i = b * 1024 + tid * 4;
  int loc[4]; int s = 0;
#pragma unroll
  for (int j = 0; j < 4; ++j) {
    int v = (base_i + j < N) ? deg[base_i + j] : 0;
    loc[j] = s; s += v;
  }
  lsum[tid] = s; __syncthreads();
  for (int st = 1; st < 256; st <<= 1) {
    int add = (tid >= st) ? lsum[tid - st] : 0;
    __syncthreads();
    lsum[tid] += add;
    __syncthreads();
  }
  int toff = boff[b] + lsum[tid] - s;
#pragma unroll
  for (int j = 0; j < 4; ++j) {
    if (base_i + j < N) {
      int r = toff + loc[j];
      rowptr[base_i + j] = r;
      cursor[base_i + j] = r;
    }
  }
}

__global__ __launch_bounds__(256) void k_scatter(const int* __restrict__ dst, int E,
                                                 int* __restrict__ cursor, int* __restrict__ eid) {
  int e = blockIdx.x * 256 + threadIdx.x;
  if (e < E) {
    int pos = atomicAdd(&cursor[dst[e]], 1);
    eid[pos] = e;
  }
}

// materialize permuted (dst-sorted) edge lists
__global__ __launch_bounds__(256) void k_perm(const int* __restrict__ src, const int* __restrict__ dst,
                                              const int* __restrict__ eid, int E,
                                              int* __restrict__ srcp, int* __restrict__ dstp) {
  int i = blockIdx.x * 256 + threadIdx.x;
  if (i < E) {
    int e = eid[i];
    srcp[i] = src[e];
    dstp[i] = dst[e];
  }
}

// ---------------- x0 = MLP2([vc, goal, d, d*d]) , 36 -> 64 -> 64 (VALU; small) ----------
__global__ __launch_bounds__(256) void k_hx(const float* __restrict__ v,
                                            const float* __restrict__ labels,
                                            const float* __restrict__ goal,
                                            const float* __restrict__ w1, const float* __restrict__ b1,
                                            const float* __restrict__ w2, const float* __restrict__ b2,
                                            float* __restrict__ xout, int N) {
  int lane = threadIdx.x & 63;
  int wid = (blockIdx.x * blockDim.x + threadIdx.x) >> 6;
  int base = wid * GE;
  int c = lane % 9;
  float f[GE];
#pragma unroll
  for (int e = 0; e < GE; ++e) {
    int i = base + e; if (i >= N) i = N - 1;
    float fv = 0.f;
    if (lane < 36) {
      float vcv = (c < 7) ? v[7 * i + c] : labels[2 * i + (c - 7)];
      float gl = goal[c];
      float d = vcv - gl;
      fv = (lane < 9) ? vcv : (lane < 18) ? gl : (lane < 27) ? d : d * d;
    }
    f[e] = fv;
  }
  float acc[GE];
  float bb = b1[lane];
#pragma unroll
  for (int e = 0; e < GE; ++e) acc[e] = bb;
  for (int k = 0; k < 36; ++k) {
    float w = w1[k * 64 + lane];
#pragma unroll
    for (int e = 0; e < GE; ++e) acc[e] = fmaf(bcast(f[e], k), w, acc[e]);
  }
  float h[GE];
#pragma unroll
  for (int e = 0; e < GE; ++e) h[e] = fmaxf(acc[e], 0.f);
  float b2v = b2[lane];
#pragma unroll
  for (int e = 0; e < GE; ++e) acc[e] = b2v;
#pragma unroll 4
  for (int k = 0; k < 64; ++k) {
    float w = w2[k * 64 + lane];
#pragma unroll
    for (int e = 0; e < GE; ++e) acc[e] = fmaf(bcast(h[e], k), w, acc[e]);
  }
#pragma unroll
  for (int e = 0; e < GE; ++e) {
    int i = base + e;
    if (i < N) xout[(size_t)i * 64 + lane] = acc[e];
  }
}

// ---------------- hy (MFMA): y0 = MLP2([vcj(16) ; vci(16)] folded), K=32 ----------
__global__ __launch_bounds__(256) void k_hy(
    const float* __restrict__ vcp,
    const int* __restrict__ src, const int* __restrict__ dst,
    const u16* __restrict__ B1h, const u16* __restrict__ B1l, const float* __restrict__ b1,
    const u16* __restrict__ B2h, const u16* __restrict__ B2l, const float* __restrict__ b2,
    u16* __restrict__ yh, u16* __restrict__ yl, int E) {
  __shared__ float hbuf[4][16 * 68];
  const int lane = threadIdx.x & 63;
  const int wv = threadIdx.x >> 6;
  const int m = lane & 15, q = lane >> 4;
  const int base = blockIdx.x * 64 + wv * 16;
  int em = base + m; if (em >= E) em = E - 1;
  const int node = (q < 2) ? dst[em] : src[em];
  const float* p = vcp + (size_t)node * 16 + (q & 1) * 8;
  float f[8];
  *(float4*)(f + 0) = *(const float4*)(p);
  *(float4*)(f + 4) = *(const float4*)(p + 4);
  U8s Ah, Al;
  dec8(f, Ah, Al);

  f32x4 acc[4];
#pragma unroll
  for (int t = 0; t < 4; ++t) { float bv = b1[t * 16 + m]; acc[t] = (f32x4){bv, bv, bv, bv}; }
#pragma unroll
  for (int t = 0; t < 4; ++t) {
    bf16x8 bh = *(const bf16x8*)(B1h + ((size_t)t * 64 + lane) * 8);
    bf16x8 bl = *(const bf16x8*)(B1l + ((size_t)t * 64 + lane) * 8);
    acc[t] = __builtin_amdgcn_mfma_f32_16x16x32_bf16(Ah.v, bh, acc[t], 0, 0, 0);
    acc[t] = __builtin_amdgcn_mfma_f32_16x16x32_bf16(Al.v, bh, acc[t], 0, 0, 0);
    acc[t] = __builtin_amdgcn_mfma_f32_16x16x32_bf16(Ah.v, bl, acc[t], 0, 0, 0);
  }

  float* hb = hbuf[wv];
#pragma unroll
  for (int t = 0; t < 4; ++t)
#pragma unroll
    for (int r = 0; r < 4; ++r)
      hb[(q * 4 + r) * 68 + t * 16 + m] = fmaxf(acc[t][r], 0.f);
  __syncthreads();

  float fh[16];
  const float* hr = hb + m * 68 + q * 8;
  *(float4*)(fh + 0)  = *(const float4*)(hr);
  *(float4*)(fh + 4)  = *(const float4*)(hr + 4);
  *(float4*)(fh + 8)  = *(const float4*)(hr + 32);
  *(float4*)(fh + 12) = *(const float4*)(hr + 36);
  U8s A2h[2], A2l[2];
  dec8(fh + 0, A2h[0], A2l[0]);
  dec8(fh + 8, A2h[1], A2l[1]);
  __syncthreads();

  f32x4 acc2[4];
#pragma unroll
  for (int t = 0; t < 4; ++t) { float bv = b2[t * 16 + m]; acc2[t] = (f32x4){bv, bv, bv, bv}; }
#pragma unroll
  for (int c = 0; c < 2; ++c) {
#pragma unroll
    for (int t = 0; t < 4; ++t) {
      bf16x8 bh = *(const bf16x8*)(B2h + ((size_t)(c * 4 + t) * 64 + lane) * 8);
      bf16x8 bl = *(const bf16x8*)(B2l + ((size_t)(c * 4 + t) * 64 + lane) * 8);
      acc2[t] = __builtin_amdgcn_mfma_f32_16x16x32_bf16(A2h[c].v, bh, acc2[t], 0, 0, 0);
      acc2[t] = __builtin_amdgcn_mfma_f32_16x16x32_bf16(A2l[c].v, bh, acc2[t], 0, 0, 0);
      acc2[t] = __builtin_amdgcn_mfma_f32_16x16x32_bf16(A2h[c].v, bl, acc2[t], 0, 0, 0);
    }
  }

#pragma unroll
  for (int t = 0; t < 4; ++t)
#pragma unroll
    for (int r = 0; r < 4; ++r)
      hb[(q * 4 + r) * 68 + t * 16 + m] = acc2[t][r];
  __syncthreads();

  int row = base + m;
  if (row < E) {
    float ov[16];
    const float* orow = hb + m * 68 + q * 16;
    *(float4*)(ov + 0)  = *(const float4*)(orow);
    *(float4*)(ov + 4)  = *(const float4*)(orow + 4);
    *(float4*)(ov + 8)  = *(const float4*)(orow + 8);
    *(float4*)(ov + 12) = *(const float4*)(orow + 12);
    size_t yo = (size_t)row * 64 + q * 16;
    U8s Oh0, Oh1, Ol0, Ol1;
    dec8(ov + 0, Oh0, Ol0);
    dec8(ov + 8, Oh1, Ol1);
    *(bf16x8*)(yh + yo)     = Oh0.v;
    *(bf16x8*)(yh + yo + 8) = Oh1.v;
    *(bf16x8*)(yl + yo)     = Ol0.v;
    *(bf16x8*)(yl + yo + 8) = Ol1.v;
  }
}

// ---------------- fx: MFMA + in-tile segmented max (dst-sorted edges) + atomics ----------
__global__ __launch_bounds__(256) void k_fx(
    const float* __restrict__ x, const u16* __restrict__ yh, const u16* __restrict__ yl,
    const int* __restrict__ src, const int* __restrict__ dst,
    const u16* __restrict__ B1h, const u16* __restrict__ B1l, const float* __restrict__ b1,
    const u16* __restrict__ B2h, const u16* __restrict__ B2l, const float* __restrict__ b2,
    float* __restrict__ xnew, int E) {
  __shared__ float hbuf[4][16 * 68];
  const int lane = threadIdx.x & 63;
  const int wv = threadIdx.x >> 6;
  const int m = lane & 15, q = lane >> 4;
  const int base = blockIdx.x * 64 + wv * 16;
  int em = base + m; if (em >= E) em = E - 1;
  const int si = src[em], di = dst[em];

  const float* ps = x + (size_t)si * 64 + q * 8;
  const float* pd = x + (size_t)di * 64 + q * 8;
  float fs[16], fd[16];
  *(float4*)(fs + 0)  = *(const float4*)(ps);
  *(float4*)(fs + 4)  = *(const float4*)(ps + 4);
  *(float4*)(fs + 8)  = *(const float4*)(ps + 32);
  *(float4*)(fs + 12) = *(const float4*)(ps + 36);
  *(float4*)(fd + 0)  = *(const float4*)(pd);
  *(float4*)(fd + 4)  = *(const float4*)(pd + 4);
  *(float4*)(fd + 8)  = *(const float4*)(pd + 32);
  *(float4*)(fd + 12) = *(const float4*)(pd + 36);

  U8s Ah[6], Al[6];
  dec8(fs + 0, Ah[0], Al[0]);
  dec8(fs + 8, Ah[1], Al[1]);
  dec8(fd + 0, Ah[2], Al[2]);
  dec8(fd + 8, Ah[3], Al[3]);
  const u16* pyh = yh + (size_t)em * 64 + q * 8;
  const u16* pyl = yl + (size_t)em * 64 + q * 8;
  Ah[4].v = *(const bf16x8*)(pyh);      Ah[5].v = *(const bf16x8*)(pyh + 32);
  Al[4].v = *(const bf16x8*)(pyl);      Al[5].v = *(const bf16x8*)(pyl + 32);

  f32x4 acc[4];
#pragma unroll
  for (int t = 0; t < 4; ++t) { float bv = b1[t * 16 + m]; acc[t] = (f32x4){bv, bv, bv, bv}; }
#pragma unroll
  for (int c = 0; c < 6; ++c) {
#pragma unroll
    for (int t = 0; t < 4; ++t) {
      bf16x8 bh = *(const bf16x8*)(B1h + ((size_t)(c * 4 + t) * 64 + lane) * 8);
      bf16x8 bl = *(const bf16x8*)(B1l + ((size_t)(c * 4 + t) * 64 + lane) * 8);
      acc[t] = __builtin_amdgcn_mfma_f32_16x16x32_bf16(Ah[c].v, bh, acc[t], 0, 0, 0);
      acc[t] = __builtin_amdgcn_mfma_f32_16x16x32_bf16(Al[c].v, bh, acc[t], 0, 0, 0);
      acc[t] = __builtin_amdgcn_mfma_f32_16x16x32_bf16(Ah[c].v, bl, acc[t], 0, 0, 0);
    }
  }

  float* hb = hbuf[wv];
#pragma unroll
  for (int t = 0; t < 4; ++t)
#pragma unroll
    for (int r = 0; r < 4; ++r)
      hb[(q * 4 + r) * 68 + t * 16 + m] = fmaxf(acc[t][r], 0.f);
  __syncthreads();

  float fh[16];
  const float* hr = hb + m * 68 + q * 8;
  *(float4*)(fh + 0)  = *(const float4*)(hr);
  *(float4*)(fh + 4)  = *(const float4*)(hr + 4);
  *(float4*)(fh + 8)  = *(const float4*)(hr + 32);
  *(float4*)(fh + 12) = *(const float4*)(hr + 36);
  U8s A2h[2], A2l[2];
  dec8(fh + 0, A2h[0], A2l[0]);
  dec8(fh + 8, A2h[1], A2l[1]);

  f32x4 acc2[4];
#pragma unroll
  for (int t = 0; t < 4; ++t) { float bv = b2[t * 16 + m]; acc2[t] = (f32x4){bv, bv, bv, bv}; }
#pragma unroll
  for (int c = 0; c < 2; ++c) {
#pragma unroll
    for (int t = 0; t < 4; ++t) {
      bf16x8 bh = *(const bf16x8*)(B2h + ((size_t)(c * 4 + t) * 64 + lane) * 8);
      bf16x8 bl = *(const bf16x8*)(B2l + ((size_t)(c * 4 + t) * 64 + lane) * 8);
      acc2[t] = __builtin_amdgcn_mfma_f32_16x16x32_bf16(A2h[c].v, bh, acc2[t], 0, 0, 0);
      acc2[t] = __builtin_amdgcn_mfma_f32_16x16x32_bf16(A2l[c].v, bh, acc2[t], 0, 0, 0);
      acc2[t] = __builtin_amdgcn_mfma_f32_16x16x32_bf16(A2h[c].v, bl, acc2[t], 0, 0, 0);
    }
  }

  // segmented max over dst-sorted rows, then one atomic per run (dd is q-uniform: no divergence)
  int dd[5];
  int e0 = base + q * 4;
#pragma unroll
  for (int r = 0; r < 5; ++r) {
    int e2 = e0 + r;
    dd[r] = (e2 < E) ? dst[e2] : -1;
  }
#pragma unroll
  for (int t = 0; t < 4; ++t) {
    float run = 0.f;
    bool have = false;
#pragma unroll
    for (int r = 0; r < 4; ++r) {
      if (dd[r] >= 0) {
        run = have ? fmaxf(run, acc2[t][r]) : acc2[t][r];
        have = true;
        if (r == 3 || dd[r + 1] != dd[r]) {
          atomicMaxF(&xnew[(size_t)dd[r] * 64 + t * 16 + m], run);
          have = false;
        }
      }
    }
  }
}

// ---------------- fy: MFMA, y = max(y, MLP2([xd,xs] folded)), K=128 ----------
__global__ __launch_bounds__(256) void k_fy(
    const float* __restrict__ x, u16* __restrict__ yh, u16* __restrict__ yl,
    const int* __restrict__ src, const int* __restrict__ dst,
    const u16* __restrict__ B1h, const u16* __restrict__ B1l, const float* __restrict__ b1,
    const u16* __restrict__ B2h, const u16* __restrict__ B2l, const float* __restrict__ b2,
    int E) {
  __shared__ float hbuf[4][16 * 68];
  const int lane = threadIdx.x & 63;
  const int wv = threadIdx.x >> 6;
  const int m = lane & 15, q = lane >> 4;
  const int base = blockIdx.x * 64 + wv * 16;
  int em = base + m; if (em >= E) em = E - 1;
  const int si = src[em], di = dst[em];

  const float* ps = x + (size_t)si * 64 + q * 8;
  const float* pd = x + (size_t)di * 64 + q * 8;
  float fs[16], fd[16];
  *(float4*)(fd + 0)  = *(const float4*)(pd);
  *(float4*)(fd + 4)  = *(const float4*)(pd + 4);
  *(float4*)(fd + 8)  = *(const float4*)(pd + 32);
  *(float4*)(fd + 12) = *(const float4*)(pd + 36);
  *(float4*)(fs + 0)  = *(const float4*)(ps);
  *(float4*)(fs + 4)  = *(const float4*)(ps + 4);
  *(float4*)(fs + 8)  = *(const float4*)(ps + 32);
  *(float4*)(fs + 12) = *(const float4*)(ps + 36);

  U8s Ah[4], Al[4];
  dec8(fd + 0, Ah[0], Al[0]);
  dec8(fd + 8, Ah[1], Al[1]);
  dec8(fs + 0, Ah[2], Al[2]);
  dec8(fs + 8, Ah[3], Al[3]);

  f32x4 acc[4];
#pragma unroll
  for (int t = 0; t < 4; ++t) { float bv = b1[t * 16 + m]; acc[t] = (f32x4){bv, bv, bv, bv}; }
#pragma unroll
  for (int c = 0; c < 4; ++c) {
#pragma unroll
    for (int t = 0; t < 4; ++t) {
      bf16x8 bh = *(const bf16x8*)(B1h + ((size_t)(c * 4 + t) * 64 + lane) * 8);
      bf16x8 bl = *(const bf16x8*)(B1l + ((size_t)(c * 4 + t) * 64 + lane) * 8);
      acc[t] = __builtin_amdgcn_mfma_f32_16x16x32_bf16(Ah[c].v, bh, acc[t], 0, 0, 0);
      acc[t] = __builtin_amdgcn_mfma_f32_16x16x32_bf16(Al[c].v, bh, acc[t], 0, 0, 0);
      acc[t] = __builtin_amdgcn_mfma_f32_16x16x32_bf16(Ah[c].v, bl, acc[t], 0, 0, 0);
    }
  }

  float* hb = hbuf[wv];
#pragma unroll
  for (int t = 0; t < 4; ++t)
#pragma unroll
    for (int r = 0; r < 4; ++r)
      hb[(q * 4 + r) * 68 + t * 16 + m] = fmaxf(acc[t][r], 0.f);
  __syncthreads();

  float fh[16];
  const float* hr = hb + m * 68 + q * 8;
  *(float4*)(fh + 0)  = *(const float4*)(hr);
  *(float4*)(fh + 4)  = *(const float4*)(hr + 4);
  *(float4*)(fh + 8)  = *(const float4*)(hr + 32);
  *(float4*)(fh + 12) = *(const float4*)(hr + 36);
  U8s A2h[2], A2l[2];
  dec8(fh + 0, A2h[0], A2l[0]);
  dec8(fh + 8, A2h[1], A2l[1]);
  __syncthreads();

  f32x4 acc2[4];
#pragma unroll
  for (int t = 0; t < 4; ++t) { float bv = b2[t * 16 + m]; acc2[t] = (f32x4){bv, bv, bv, bv}; }
#pragma unroll
  for (int c = 0; c < 2; ++c) {
#pragma unroll
    for (int t = 0; t < 4; ++t) {
      bf16x8 bh = *(const bf16x8*)(B2h + ((size_t)(c * 4 + t) * 64 + lane) * 8);
      bf16x8 bl = *(const bf16x8*)(B2l + ((size_t)(c * 4 + t) * 64 + lane) * 8);
      acc2[t] = __builtin_amdgcn_mfma_f32_16x16x32_bf16(A2h[c].v, bh, acc2[t], 0, 0, 0);
      acc2[t] = __builtin_amdgcn_mfma_f32_16x16x32_bf16(A2l[c].v, bh, acc2[t], 0, 0, 0);
      acc2[t] = __builtin_amdgcn_mfma_f32_16x16x32_bf16(A2h[c].v, bl, acc2[t], 0, 0, 0);
    }
  }

#pragma unroll
  for (int t = 0; t < 4; ++t)
#pragma unroll
    for (int r = 0; r < 4; ++r)
      hb[(q * 4 + r) * 68 + t * 16 + m] = acc2[t][r];
  __syncthreads();

  int row = base + m;
  if (row < E) {
    float ov[16];
    const float* orow = hb + m * 68 + q * 16;
    *(float4*)(ov + 0)  = *(const float4*)(orow);
    *(float4*)(ov + 4)  = *(const float4*)(orow + 4);
    *(float4*)(ov + 8)  = *(const float4*)(orow + 8);
    *(float4*)(ov + 12) = *(const float4*)(orow + 12);
    size_t yo = (size_t)row * 64 + q * 16;
    U8s Hh0, Hh1, Hl0, Hl1;
    Hh0.v = *(const bf16x8*)(yh + yo);     Hh1.v = *(const bf16x8*)(yh + yo + 8);
    Hl0.v = *(const bf16x8*)(yl + yo);     Hl1.v = *(const bf16x8*)(yl + yo + 8);
    float nv[16];
#pragma unroll
    for (int i = 0; i < 8; ++i) {
      nv[i]     = fmaxf(upf(Hh0.s[i]) + upf(Hl0.s[i]), ov[i]);
      nv[8 + i] = fmaxf(upf(Hh1.s[i]) + upf(Hl1.s[i]), ov[8 + i]);
    }
    U8s Oh0, Oh1, Ol0, Ol1;
    dec8(nv + 0, Oh0, Ol0);
    dec8(nv + 8, Oh1, Ol1);
    *(bf16x8*)(yh + yo)     = Oh0.v;
    *(bf16x8*)(yh + yo + 8) = Oh1.v;
    *(bf16x8*)(yl + yo)     = Ol0.v;
    *(bf16x8*)(yl + yo + 8) = Ol1.v;
  }
}

// ---------------- out = feta(x): 64 -> 64 -> 64 -> 1 (VALU; small) ----------------
__global__ __launch_bounds__(256) void k_feta(const float* __restrict__ x,
                                              const float* __restrict__ w1, const float* __restrict__ b1,
                                              const float* __restrict__ w2, const float* __restrict__ b2,
                                              const float* __restrict__ w3,
                                              float* __restrict__ out, int N) {
  int lane = threadIdx.x & 63;
  int wid = (blockIdx.x * blockDim.x + threadIdx.x) >> 6;
  int base = wid * GE;
  float xr[GE];
#pragma unroll
  for (int e = 0; e < GE; ++e) {
    int i = base + e; if (i >= N) i = N - 1;
    xr[e] = x[(size_t)i * 64 + lane];
  }
  float acc[GE];
  float bb = b1[lane];
#pragma unroll
  for (int e = 0; e < GE; ++e) acc[e] = bb;
#pragma unroll 4
  for (int k = 0; k < 64; ++k) {
    float w = w1[k * 64 + lane];
#pragma unroll
    for (int e = 0; e < GE; ++e) acc[e] = fmaf(bcast(xr[e], k), w, acc[e]);
  }
  float h1[GE];
#pragma unroll
  for (int e = 0; e < GE; ++e) h1[e] = fmaxf(acc[e], 0.f);
  float b2v = b2[lane];
#pragma unroll
  for (int e = 0; e < GE; ++e) acc[e] = b2v;
#pragma unroll 4
  for (int k = 0; k < 64; ++k) {
    float w = w2[k * 64 + lane];
#pragma unroll
    for (int e = 0; e < GE; ++e) acc[e] = fmaf(bcast(h1[e], k), w, acc[e]);
  }
  float w3l = w3[lane];
#pragma unroll
  for (int e = 0; e < GE; ++e) {
    float r = fmaxf(acc[e], 0.f) * w3l;
    for (int off = 32; off > 0; off >>= 1) r += __shfl_xor(r, off, 64);
    int i = base + e;
    if (lane == 0 && i < N) out[i] = r;
  }
}

__global__ __launch_bounds__(256) void k_copy(const float4* __restrict__ s,
                                              float4* __restrict__ d, int n4) {
  int i = blockIdx.x * 256 + threadIdx.x;
  if (i < n4) d[i] = s[i];
}

extern "C" void kernel_launch(void* const* d_in, const int* in_sizes, int n_in,
                              void* d_out, int out_size, void* d_ws, size_t ws_size,
                              hipStream_t stream) {
  const float* v      = (const float*)d_in[0];
  const float* labels = (const float*)d_in[1];
  const int*   ei     = (const int*)d_in[2];
  const float* hx_w1 = (const float*)d_in[4];
  const float* hx_b1 = (const float*)d_in[5];
  const float* hx_w2 = (const float*)d_in[6];
  const float* hx_b2 = (const float*)d_in[7];
  const float* hy_w1 = (const float*)d_in[8];
  const float* hy_b1 = (const float*)d_in[9];
  const float* hy_w2 = (const float*)d_in[10];
  const float* hy_b2 = (const float*)d_in[11];
  const float* fx_w1 = (const float*)d_in[12];
  const float* fx_b1 = (const float*)d_in[13];
  const float* fx_w2 = (const float*)d_in[14];
  const float* fx_b2 = (const float*)d_in[15];
  const float* fy_w1 = (const float*)d_in[16];
  const float* fy_b1 = (const float*)d_in[17];
  const float* fy_w2 = (const float*)d_in[18];
  const float* fy_b2 = (const float*)d_in[19];
  const float* feta_w1 = (const float*)d_in[20];
  const float* feta_b1 = (const float*)d_in[21];
  const float* feta_w2 = (const float*)d_in[22];
  const float* feta_b2 = (const float*)d_in[23];
  const float* feta_w3 = (const float*)d_in[24];

  int N = in_sizes[0] / 7;
  int E = in_sizes[2] / 2;
  const int* src = ei;
  const int* dst = ei + E;

  char* wsb = (char*)d_ws;
  float* goal = (float*)wsb;                                     // 16 f
  u64* goalkey = (u64*)(wsb + 16 * 4);
  float* xa = (float*)(wsb + 32 * 4);                            // N*64 f
  float* xb = xa + (size_t)N * 64;                               // N*64 f
  u16* yh = (u16*)(xb + (size_t)N * 64);                         // E*64 u16
  u16* yl = yh + (size_t)E * 64;                                 // E*64 u16
  u16* wp = yl + (size_t)E * 64;                                 // 69632 u16
  float* vcp = (float*)(wp + 69632);                             // N*16 f
  int* deg = (int*)(vcp + (size_t)N * 16);                       // N
  int* rowptr = deg + N;                                         // N+1
  int* cursor = rowptr + N + 1;                                  // N
  int* eid = cursor + N;                                         // E
  int* srcp = eid + E;                                           // E
  int* dstp = srcp + E;                                          // E
  int* bsum = dstp + E;                                          // 64
  int* boff = bsum + 64;                                         // 64

  u16* fxB1h = wp;          u16* fxB1l = wp + 12288;
  u16* fxB2h = wp + 24576;  u16* fxB2l = wp + 28672;
  u16* fyB1h = wp + 32768;  u16* fyB1l = wp + 40960;
  u16* fyB2h = wp + 49152;  u16* fyB2l = wp + 53248;
  u16* hyB1h = wp + 57344;  u16* hyB1l = wp + 59392;
  u16* hyB2h = wp + 61440;  u16* hyB2l = wp + 65536;

  int SB = (N + 1023) / 1024;  // scan blocks

  hipMemsetAsync(goalkey, 0, sizeof(u64), stream);
  hipMemsetAsync(deg, 0, (size_t)N * 4, stream);
  k_prep<<<17, 256, 0, stream>>>(fx_w1, fx_w2, fy_w1, fy_w2, hy_w1, hy_w2, wp);
  k_vc<<<(N * 16 + 255) / 256, 256, 0, stream>>>(v, labels, vcp, N);
  k_goal1<<<(N + 255) / 256, 256, 0, stream>>>(labels, N, goalkey);
  k_goal2<<<1, 64, 0, stream>>>(v, labels, goalkey, goal);
  k_hist<<<(E + 255) / 256, 256, 0, stream>>>(dst, E, deg);
  k_scan1<<<SB, 256, 0, stream>>>(deg, N, bsum);
  k_scan2<<<1, 64, 0, stream>>>(bsum, SB, boff, rowptr, N, E);
  k_scan3<<<SB, 256, 0, stream>>>(deg, boff, N, rowptr, cursor);
  k_scatter<<<(E + 255) / 256, 256, 0, stream>>>(dst, E, cursor, eid);
  k_perm<<<(E + 255) / 256, 256, 0, stream>>>(src, dst, eid, E, srcp, dstp);

  k_hx<<<(N + 31) / 32, 256, 0, stream>>>(v, labels, goal, hx_w1, hx_b1, hx_w2, hx_b2, xa, N);
  k_hy<<<(E + 63) / 64, 256, 0, stream>>>(vcp, srcp, dstp,
                                          hyB1h, hyB1l, hy_b1, hyB2h, hyB2l, hy_b2, yh, yl, E);

  float* xc = xa;
  float* xo = xb;
  for (int t = 0; t < 3; ++t) {
    k_copy<<<(N * 16 + 255) / 256, 256, 0, stream>>>((const float4*)xc, (float4*)xo, N * 16);
    k_fx<<<(E + 63) / 64, 256, 0, stream>>>(xc, yh, yl, srcp, dstp,
                                            fxB1h, fxB1l, fx_b1, fxB2h, fxB2l, fx_b2, xo, E);
    float* tmp = xc; xc = xo; xo = tmp;
    if (t < 2) {
      k_fy<<<(E + 63) / 64, 256, 0, stream>>>(xc, yh, yl, srcp, dstp,
                                              fyB1h, fyB1l, fy_b1, fyB2h, fyB2l, fy_b2, E);
    }
  }
  k_feta<<<(N + 31) / 32, 256, 0, stream>>>(xc, feta_w1, feta_b1, feta_w2, feta_b2, feta_w3,
                                            (float*)d_out, N);
}

// Round 6
// 581.166 us; speedup vs baseline: 4.1951x; 1.0491x over previous
//
#include <hip/hip_runtime.h>
#include <math.h>

typedef unsigned short u16;
typedef unsigned int u32;
typedef unsigned long long u64;
typedef __attribute__((ext_vector_type(8))) _Float16 f16x8;
typedef __attribute__((ext_vector_type(2))) _Float16 f16x2;
typedef __attribute__((ext_vector_type(4))) float f32x4;

union U8h { f16x8 v; f16x2 p[4]; u32 u[4]; _Float16 s[8]; };

#define GE 8  // nodes per wave for the VALU kernels

__device__ __forceinline__ float bcast(float v, int k) {
  return __int_as_float(__builtin_amdgcn_readlane(__float_as_int(v), k));
}

__device__ __forceinline__ void atomicMaxF(float* addr, float val) {
  if (val >= 0.0f) {
    atomicMax((int*)addr, __float_as_int(val));
  } else {
    atomicMin((unsigned int*)addr, (unsigned int)__float_as_int(val));
  }
}

// pack two floats -> fp16x2 (RTZ) ; builtin returns __fp16 vector, bit-cast to _Float16 vector
__device__ __forceinline__ f16x2 pk(float a, float b) {
  return __builtin_bit_cast(f16x2, __builtin_amdgcn_cvt_pkrtz(a, b));
}

// split 8 fp32 -> fp16 hi (RTZ) + fp16 lo (residual, RTZ): A = hi + lo exact to ~2^-22
__device__ __forceinline__ void dec8h(const float* f, U8h& h, U8h& l) {
#pragma unroll
  for (int i = 0; i < 4; ++i) {
    float a = f[2 * i], b = f[2 * i + 1];
    f16x2 hp = pk(a, b);
    float ra = a - (float)hp[0];
    float rb = b - (float)hp[1];
    h.p[i] = hp;
    l.p[i] = pk(ra, rb);
  }
}

// ---------------- goal: argmax over labels[:,1]; wave-reduced atomic ----------------
__global__ __launch_bounds__(256) void k_goal1(const float* __restrict__ labels, int N,
                                               u64* __restrict__ key) {
  int i = blockIdx.x * 256 + threadIdx.x;
  float val = (i < N) ? labels[2 * (size_t)i + 1] : 0.0f;
  u64 k = ((u64)__float_as_uint(fmaxf(val, 0.0f)) << 32) | (u32)(~(u32)i);
#pragma unroll
  for (int off = 32; off > 0; off >>= 1) {
    u64 o = __shfl_xor(k, off, 64);
    if (o > k) k = o;
  }
  if ((threadIdx.x & 63) == 0) atomicMax(key, k);
}

__global__ void k_goal2(const float* __restrict__ v, const float* __restrict__ labels,
                        const u64* __restrict__ key, float* __restrict__ goal) {
  int g = (int)(~(u32)(*key));
  int c = threadIdx.x;
  if (c < 9) goal[c] = (c < 7) ? v[7 * (size_t)g + c] : labels[2 * (size_t)g + (c - 7)];
}

// ---------------- vcp[N][16] = [v(7), lab0, lab1, 0...] ----------------
__global__ __launch_bounds__(256) void k_vc(const float* __restrict__ v,
                                            const float* __restrict__ labels,
                                            float* __restrict__ vcp, int N) {
  int tid = blockIdx.x * 256 + threadIdx.x;
  if (tid >= N * 16) return;
  int n = tid >> 4, c = tid & 15;
  float val = 0.f;
  if (c < 7) val = v[(size_t)n * 7 + c];
  else if (c == 7) val = labels[2 * (size_t)n];
  else if (c == 8) val = labels[2 * (size_t)n + 1];
  vcp[tid] = val;
}

// ---------------- weight prep: folded concat + single RNE fp16, frag-major ----------
// value = Wcat[c*32 + (lane>>4)*8 + j][t*16 + (lane&15)] at ((c*4+t)*64+lane)*8+j
__global__ __launch_bounds__(256) void k_prep(const float* __restrict__ fxw1, const float* __restrict__ fxw2,
                                              const float* __restrict__ fyw1, const float* __restrict__ fyw2,
                                              const float* __restrict__ hyw1, const float* __restrict__ hyw2,
                                              _Float16* __restrict__ wp) {
  _Float16* fxB1 = wp;          // 12288
  _Float16* fxB2 = wp + 12288;  // 4096
  _Float16* fyB1 = wp + 16384;  // 8192
  _Float16* fyB2 = wp + 24576;  // 4096
  _Float16* hyB1 = wp + 28672;  // 2048
  _Float16* hyB2 = wp + 30720;  // 4096
  int tid = blockIdx.x * 256 + threadIdx.x;
  int which, id;
  _Float16* oh;
  if (tid < 1536)      { which = 0; id = tid;        oh = fxB1; }
  else if (tid < 2048) { which = 1; id = tid - 1536; oh = fxB2; }
  else if (tid < 3072) { which = 2; id = tid - 2048; oh = fyB1; }
  else if (tid < 3584) { which = 3; id = tid - 3072; oh = fyB2; }
  else if (tid < 3840) { which = 4; id = tid - 3584; oh = hyB1; }
  else if (tid < 4352) { which = 5; id = tid - 3840; oh = hyB2; }
  else return;
  int lane = id & 63;
  int q = lane >> 4, col = lane & 15;
  int c = id >> 8, t = (id >> 6) & 3;
#pragma unroll
  for (int j = 0; j < 8; ++j) {
    int k = c * 32 + q * 8 + j;
    int n = t * 16 + col;
    float w;
    if (which == 0) {
      w = (k < 64)  ? fxw1[k * 64 + n] + fxw1[(k + 64) * 64 + n]
        : (k < 128) ? fxw1[(k + 64) * 64 + n] - fxw1[(k - 64) * 64 + n]
                    : fxw1[(k + 64) * 64 + n];
    } else if (which == 1) {
      w = fxw2[k * 64 + n];
    } else if (which == 2) {
      w = (k < 64) ? fyw1[k * 64 + n] + fyw1[(k + 64) * 64 + n]
                   : fyw1[(k + 64) * 64 + n] - fyw1[(k - 64) * 64 + n];
    } else if (which == 3) {
      w = fyw2[k * 64 + n];
    } else if (which == 4) {
      if (k <= 8)                  w = hyw1[k * 64 + n] + hyw1[(k + 9) * 64 + n];
      else if (k >= 16 && k <= 24) w = hyw1[(k + 2) * 64 + n] - hyw1[(k - 16) * 64 + n];
      else                         w = 0.f;
    } else {
      w = hyw2[k * 64 + n];
    }
    oh[id * 8 + j] = (_Float16)w;  // RNE
  }
}

// ---------------- CSR build ----------------
__global__ __launch_bounds__(256) void k_hist(const int* __restrict__ dst, int E,
                                              int* __restrict__ deg) {
  int e = blockIdx.x * 256 + threadIdx.x;
  if (e < E) atomicAdd(&deg[dst[e]], 1);
}

__global__ __launch_bounds__(256) void k_scan1(const int* __restrict__ deg, int N,
                                               int* __restrict__ bsum) {
  __shared__ int red[256];
  int b = blockIdx.x;
  int s = 0;
  for (int i = threadIdx.x; i < 1024; i += 256) {
    int idx = b * 1024 + i;
    s += (idx < N) ? deg[idx] : 0;
  }
  red[threadIdx.x] = s; __syncthreads();
  for (int st = 128; st > 0; st >>= 1) {
    if (threadIdx.x < st) red[threadIdx.x] += red[threadIdx.x + st];
    __syncthreads();
  }
  if (threadIdx.x == 0) bsum[b] = red[0];
}

__global__ void k_scan2(const int* __restrict__ bsum, int B, int* __restrict__ boff,
                        int* __restrict__ rowptr, int N, int E) {
  if (threadIdx.x == 0) {
    int acc = 0;
    for (int i = 0; i < B; ++i) { boff[i] = acc; acc += bsum[i]; }
    rowptr[N] = E;
  }
}

__global__ __launch_bounds__(256) void k_scan3(const int* __restrict__ deg,
                                               const int* __restrict__ boff, int N,
                                               int* __restrict__ rowptr, int* __restrict__ cursor) {
  __shared__ int lsum[256];
  int b = blockIdx.x;
  int tid = threadIdx.x;
  int base_i = b * 1024 + tid * 4;
  int loc[4]; int s = 0;
#pragma unroll
  for (int j = 0; j < 4; ++j) {
    int v = (base_i + j < N) ? deg[base_i + j] : 0;
    loc[j] = s; s += v;
  }
  lsum[tid] = s; __syncthreads();
  for (int st = 1; st < 256; st <<= 1) {
    int add = (tid >= st) ? lsum[tid - st] : 0;
    __syncthreads();
    lsum[tid] += add;
    __syncthreads();
  }
  int toff = boff[b] + lsum[tid] - s;
#pragma unroll
  for (int j = 0; j < 4; ++j) {
    if (base_i + j < N) {
      int r = toff + loc[j];
      rowptr[base_i + j] = r;
      cursor[base_i + j] = r;
    }
  }
}

__global__ __launch_bounds__(256) void k_scatter(const int* __restrict__ dst, int E,
                                                 int* __restrict__ cursor, int* __restrict__ eid) {
  int e = blockIdx.x * 256 + threadIdx.x;
  if (e < E) {
    int pos = atomicAdd(&cursor[dst[e]], 1);
    eid[pos] = e;
  }
}

__global__ __launch_bounds__(256) void k_perm(const int* __restrict__ src, const int* __restrict__ dst,
                                              const int* __restrict__ eid, int E,
                                              int* __restrict__ srcp, int* __restrict__ dstp) {
  int i = blockIdx.x * 256 + threadIdx.x;
  if (i < E) {
    int e = eid[i];
    srcp[i] = src[e];
    dstp[i] = dst[e];
  }
}

// ---------------- x0 = MLP2([vc, goal, d, d*d]) , 36 -> 64 -> 64 (VALU; small) ----------
__global__ __launch_bounds__(256) void k_hx(const float* __restrict__ v,
                                            const float* __restrict__ labels,
                                            const float* __restrict__ goal,
                                            const float* __restrict__ w1, const float* __restrict__ b1,
                                            const float* __restrict__ w2, const float* __restrict__ b2,
                                            float* __restrict__ xout, int N) {
  int lane = threadIdx.x & 63;
  int wid = (blockIdx.x * blockDim.x + threadIdx.x) >> 6;
  int base = wid * GE;
  int c = lane % 9;
  float f[GE];
#pragma unroll
  for (int e = 0; e < GE; ++e) {
    int i = base + e; if (i >= N) i = N - 1;
    float fv = 0.f;
    if (lane < 36) {
      float vcv = (c < 7) ? v[7 * i + c] : labels[2 * i + (c - 7)];
      float gl = goal[c];
      float d = vcv - gl;
      fv = (lane < 9) ? vcv : (lane < 18) ? gl : (lane < 27) ? d : d * d;
    }
    f[e] = fv;
  }
  float acc[GE];
  float bb = b1[lane];
#pragma unroll
  for (int e = 0; e < GE; ++e) acc[e] = bb;
  for (int k = 0; k < 36; ++k) {
    float w = w1[k * 64 + lane];
#pragma unroll
    for (int e = 0; e < GE; ++e) acc[e] = fmaf(bcast(f[e], k), w, acc[e]);
  }
  float h[GE];
#pragma unroll
  for (int e = 0; e < GE; ++e) h[e] = fmaxf(acc[e], 0.f);
  float b2v = b2[lane];
#pragma unroll
  for (int e = 0; e < GE; ++e) acc[e] = b2v;
#pragma unroll 4
  for (int k = 0; k < 64; ++k) {
    float w = w2[k * 64 + lane];
#pragma unroll
    for (int e = 0; e < GE; ++e) acc[e] = fmaf(bcast(h[e], k), w, acc[e]);
  }
#pragma unroll
  for (int e = 0; e < GE; ++e) {
    int i = base + e;
    if (i < N) xout[(size_t)i * 64 + lane] = acc[e];
  }
}

// ---------------- hy (MFMA fp16): y0 = MLP2([vcj(16) ; vci(16)] folded), K=32 ----------
__global__ __launch_bounds__(256) void k_hy(
    const float* __restrict__ vcp,
    const int* __restrict__ src, const int* __restrict__ dst,
    const _Float16* __restrict__ B1, const float* __restrict__ b1,
    const _Float16* __restrict__ B2, const float* __restrict__ b2,
    _Float16* __restrict__ yh, _Float16* __restrict__ yl, int E) {
  __shared__ float hbuf[4][2][16 * 68];  // wave-private; no barriers
  const int lane = threadIdx.x & 63;
  const int wv = threadIdx.x >> 6;
  const int m = lane & 15, q = lane >> 4;
  const int base = blockIdx.x * 64 + wv * 16;
  int em = base + m; if (em >= E) em = E - 1;
  const int node = (q < 2) ? dst[em] : src[em];
  const float* p = vcp + (size_t)node * 16 + (q & 1) * 8;
  float f[8];
  *(float4*)(f + 0) = *(const float4*)(p);
  *(float4*)(f + 4) = *(const float4*)(p + 4);
  U8h Ah, Al;
  dec8h(f, Ah, Al);

  f32x4 acc[4];
#pragma unroll
  for (int t = 0; t < 4; ++t) { float bv = b1[t * 16 + m]; acc[t] = (f32x4){bv, bv, bv, bv}; }
#pragma unroll
  for (int t = 0; t < 4; ++t) {
    f16x8 b = *(const f16x8*)(B1 + ((size_t)t * 64 + lane) * 8);
    acc[t] = __builtin_amdgcn_mfma_f32_16x16x32_f16(Ah.v, b, acc[t], 0, 0, 0);
    acc[t] = __builtin_amdgcn_mfma_f32_16x16x32_f16(Al.v, b, acc[t], 0, 0, 0);
  }

  float* hb = hbuf[wv][0];
#pragma unroll
  for (int t = 0; t < 4; ++t)
#pragma unroll
    for (int r = 0; r < 4; ++r)
      hb[(q * 4 + r) * 68 + t * 16 + m] = fmaxf(acc[t][r], 0.f);

  float fh[16];
  const float* hr = hb + m * 68 + q * 8;
  *(float4*)(fh + 0)  = *(const float4*)(hr);
  *(float4*)(fh + 4)  = *(const float4*)(hr + 4);
  *(float4*)(fh + 8)  = *(const float4*)(hr + 32);
  *(float4*)(fh + 12) = *(const float4*)(hr + 36);
  U8h A2h[2], A2l[2];
  dec8h(fh + 0, A2h[0], A2l[0]);
  dec8h(fh + 8, A2h[1], A2l[1]);

  f32x4 acc2[4];
#pragma unroll
  for (int t = 0; t < 4; ++t) { float bv = b2[t * 16 + m]; acc2[t] = (f32x4){bv, bv, bv, bv}; }
#pragma unroll
  for (int c = 0; c < 2; ++c) {
#pragma unroll
    for (int t = 0; t < 4; ++t) {
      f16x8 b = *(const f16x8*)(B2 + ((size_t)(c * 4 + t) * 64 + lane) * 8);
      acc2[t] = __builtin_amdgcn_mfma_f32_16x16x32_f16(A2h[c].v, b, acc2[t], 0, 0, 0);
      acc2[t] = __builtin_amdgcn_mfma_f32_16x16x32_f16(A2l[c].v, b, acc2[t], 0, 0, 0);
    }
  }

  float* ob = hbuf[wv][1];
#pragma unroll
  for (int t = 0; t < 4; ++t)
#pragma unroll
    for (int r = 0; r < 4; ++r)
      ob[(q * 4 + r) * 68 + t * 16 + m] = acc2[t][r];

  int row = base + m;
  if (row < E) {
    float ov[16];
    const float* orow = ob + m * 68 + q * 16;
    *(float4*)(ov + 0)  = *(const float4*)(orow);
    *(float4*)(ov + 4)  = *(const float4*)(orow + 4);
    *(float4*)(ov + 8)  = *(const float4*)(orow + 8);
    *(float4*)(ov + 12) = *(const float4*)(orow + 12);
    size_t yo = (size_t)row * 64 + q * 16;
    U8h H0, H1, L0, L1;
    dec8h(ov + 0, H0, L0);
    dec8h(ov + 8, H1, L1);
    *(f16x8*)(yh + yo)     = H0.v;
    *(f16x8*)(yh + yo + 8) = H1.v;
    *(f16x8*)(yl + yo)     = L0.v;
    *(f16x8*)(yl + yo + 8) = L1.v;
  }
}

// ---------------- fx: MFMA fp16 + segmented max (dst-sorted) + atomics ----------
__global__ __launch_bounds__(256) void k_fx(
    const float* __restrict__ x, const _Float16* __restrict__ yh, const _Float16* __restrict__ yl,
    const int* __restrict__ src, const int* __restrict__ dst,
    const _Float16* __restrict__ B1, const float* __restrict__ b1,
    const _Float16* __restrict__ B2, const float* __restrict__ b2,
    float* __restrict__ xnew, int E) {
  __shared__ float hbuf[4][16 * 68];  // wave-private; no barriers
  const int lane = threadIdx.x & 63;
  const int wv = threadIdx.x >> 6;
  const int m = lane & 15, q = lane >> 4;
  const int base = blockIdx.x * 64 + wv * 16;
  int em = base + m; if (em >= E) em = E - 1;
  const int si = src[em], di = dst[em];

  const float* ps = x + (size_t)si * 64 + q * 8;
  const float* pd = x + (size_t)di * 64 + q * 8;
  float fs[16], fd[16];
  *(float4*)(fs + 0)  = *(const float4*)(ps);
  *(float4*)(fs + 4)  = *(const float4*)(ps + 4);
  *(float4*)(fs + 8)  = *(const float4*)(ps + 32);
  *(float4*)(fs + 12) = *(const float4*)(ps + 36);
  *(float4*)(fd + 0)  = *(const float4*)(pd);
  *(float4*)(fd + 4)  = *(const float4*)(pd + 4);
  *(float4*)(fd + 8)  = *(const float4*)(pd + 32);
  *(float4*)(fd + 12) = *(const float4*)(pd + 36);

  U8h Ah[6], Al[6];
  dec8h(fs + 0, Ah[0], Al[0]);
  dec8h(fs + 8, Ah[1], Al[1]);
  dec8h(fd + 0, Ah[2], Al[2]);
  dec8h(fd + 8, Ah[3], Al[3]);
  const _Float16* pyh = yh + (size_t)em * 64 + q * 8;
  const _Float16* pyl = yl + (size_t)em * 64 + q * 8;
  Ah[4].v = *(const f16x8*)(pyh);      Ah[5].v = *(const f16x8*)(pyh + 32);
  Al[4].v = *(const f16x8*)(pyl);      Al[5].v = *(const f16x8*)(pyl + 32);

  f32x4 acc[4];
#pragma unroll
  for (int t = 0; t < 4; ++t) { float bv = b1[t * 16 + m]; acc[t] = (f32x4){bv, bv, bv, bv}; }
#pragma unroll
  for (int c = 0; c < 6; ++c) {
#pragma unroll
    for (int t = 0; t < 4; ++t) {
      f16x8 b = *(const f16x8*)(B1 + ((size_t)(c * 4 + t) * 64 + lane) * 8);
      acc[t] = __builtin_amdgcn_mfma_f32_16x16x32_f16(Ah[c].v, b, acc[t], 0, 0, 0);
      acc[t] = __builtin_amdgcn_mfma_f32_16x16x32_f16(Al[c].v, b, acc[t], 0, 0, 0);
    }
  }

  float* hb = hbuf[wv];
#pragma unroll
  for (int t = 0; t < 4; ++t)
#pragma unroll
    for (int r = 0; r < 4; ++r)
      hb[(q * 4 + r) * 68 + t * 16 + m] = fmaxf(acc[t][r], 0.f);

  float fh[16];
  const float* hr = hb + m * 68 + q * 8;
  *(float4*)(fh + 0)  = *(const float4*)(hr);
  *(float4*)(fh + 4)  = *(const float4*)(hr + 4);
  *(float4*)(fh + 8)  = *(const float4*)(hr + 32);
  *(float4*)(fh + 12) = *(const float4*)(hr + 36);
  U8h A2h[2], A2l[2];
  dec8h(fh + 0, A2h[0], A2l[0]);
  dec8h(fh + 8, A2h[1], A2l[1]);

  f32x4 acc2[4];
#pragma unroll
  for (int t = 0; t < 4; ++t) { float bv = b2[t * 16 + m]; acc2[t] = (f32x4){bv, bv, bv, bv}; }
#pragma unroll
  for (int c = 0; c < 2; ++c) {
#pragma unroll
    for (int t = 0; t < 4; ++t) {
      f16x8 b = *(const f16x8*)(B2 + ((size_t)(c * 4 + t) * 64 + lane) * 8);
      acc2[t] = __builtin_amdgcn_mfma_f32_16x16x32_f16(A2h[c].v, b, acc2[t], 0, 0, 0);
      acc2[t] = __builtin_amdgcn_mfma_f32_16x16x32_f16(A2l[c].v, b, acc2[t], 0, 0, 0);
    }
  }

  // segmented max over dst-sorted rows, one atomic per run (dd is q-uniform: no divergence)
  int dd[5];
  int e0 = base + q * 4;
#pragma unroll
  for (int r = 0; r < 5; ++r) {
    int e2 = e0 + r;
    dd[r] = (e2 < E) ? dst[e2] : -1;
  }
#pragma unroll
  for (int t = 0; t < 4; ++t) {
    float run = 0.f;
    bool have = false;
#pragma unroll
    for (int r = 0; r < 4; ++r) {
      if (dd[r] >= 0) {
        run = have ? fmaxf(run, acc2[t][r]) : acc2[t][r];
        have = true;
        if (r == 3 || dd[r + 1] != dd[r]) {
          atomicMaxF(&xnew[(size_t)dd[r] * 64 + t * 16 + m], run);
          have = false;
        }
      }
    }
  }
}

// ---------------- fy: MFMA fp16, y = max(y, MLP2([xd,xs] folded)), K=128 ----------
__global__ __launch_bounds__(256) void k_fy(
    const float* __restrict__ x, _Float16* __restrict__ yh, _Float16* __restrict__ yl,
    const int* __restrict__ src, const int* __restrict__ dst,
    const _Float16* __restrict__ B1, const float* __restrict__ b1,
    const _Float16* __restrict__ B2, const float* __restrict__ b2,
    int E) {
  __shared__ float hbuf[4][2][16 * 68];  // wave-private; no barriers
  const int lane = threadIdx.x & 63;
  const int wv = threadIdx.x >> 6;
  const int m = lane & 15, q = lane >> 4;
  const int base = blockIdx.x * 64 + wv * 16;
  int em = base + m; if (em >= E) em = E - 1;
  const int si = src[em], di = dst[em];

  const float* ps = x + (size_t)si * 64 + q * 8;
  const float* pd = x + (size_t)di * 64 + q * 8;
  float fs[16], fd[16];
  *(float4*)(fd + 0)  = *(const float4*)(pd);
  *(float4*)(fd + 4)  = *(const float4*)(pd + 4);
  *(float4*)(fd + 8)  = *(const float4*)(pd + 32);
  *(float4*)(fd + 12) = *(const float4*)(pd + 36);
  *(float4*)(fs + 0)  = *(const float4*)(ps);
  *(float4*)(fs + 4)  = *(const float4*)(ps + 4);
  *(float4*)(fs + 8)  = *(const float4*)(ps + 32);
  *(float4*)(fs + 12) = *(const float4*)(ps + 36);

  U8h Ah[4], Al[4];
  dec8h(fd + 0, Ah[0], Al[0]);   // chunks 0,1: xd (W0+W1)
  dec8h(fd + 8, Ah[1], Al[1]);
  dec8h(fs + 0, Ah[2], Al[2]);   // chunks 2,3: xs (W2-W0)
  dec8h(fs + 8, Ah[3], Al[3]);

  f32x4 acc[4];
#pragma unroll
  for (int t = 0; t < 4; ++t) { float bv = b1[t * 16 + m]; acc[t] = (f32x4){bv, bv, bv, bv}; }
#pragma unroll
  for (int c = 0; c < 4; ++c) {
#pragma unroll
    for (int t = 0; t < 4; ++t) {
      f16x8 b = *(const f16x8*)(B1 + ((size_t)(c * 4 + t) * 64 + lane) * 8);
      acc[t] = __builtin_amdgcn_mfma_f32_16x16x32_f16(Ah[c].v, b, acc[t], 0, 0, 0);
      acc[t] = __builtin_amdgcn_mfma_f32_16x16x32_f16(Al[c].v, b, acc[t], 0, 0, 0);
    }
  }

  float* hb = hbuf[wv][0];
#pragma unroll
  for (int t = 0; t < 4; ++t)
#pragma unroll
    for (int r = 0; r < 4; ++r)
      hb[(q * 4 + r) * 68 + t * 16 + m] = fmaxf(acc[t][r], 0.f);

  float fh[16];
  const float* hr = hb + m * 68 + q * 8;
  *(float4*)(fh + 0)  = *(const float4*)(hr);
  *(float4*)(fh + 4)  = *(const float4*)(hr + 4);
  *(float4*)(fh + 8)  = *(const float4*)(hr + 32);
  *(float4*)(fh + 12) = *(const float4*)(hr + 36);
  U8h A2h[2], A2l[2];
  dec8h(fh + 0, A2h[0], A2l[0]);
  dec8h(fh + 8, A2h[1], A2l[1]);

  f32x4 acc2[4];
#pragma unroll
  for (int t = 0; t < 4; ++t) { float bv = b2[t * 16 + m]; acc2[t] = (f32x4){bv, bv, bv, bv}; }
#pragma unroll
  for (int c = 0; c < 2; ++c) {
#pragma unroll
    for (int t = 0; t < 4; ++t) {
      f16x8 b = *(const f16x8*)(B2 + ((size_t)(c * 4 + t) * 64 + lane) * 8);
      acc2[t] = __builtin_amdgcn_mfma_f32_16x16x32_f16(A2h[c].v, b, acc2[t], 0, 0, 0);
      acc2[t] = __builtin_amdgcn_mfma_f32_16x16x32_f16(A2l[c].v, b, acc2[t], 0, 0, 0);
    }
  }

  float* ob = hbuf[wv][1];
#pragma unroll
  for (int t = 0; t < 4; ++t)
#pragma unroll
    for (int r = 0; r < 4; ++r)
      ob[(q * 4 + r) * 68 + t * 16 + m] = acc2[t][r];

  int row = base + m;
  if (row < E) {
    float ov[16];
    const float* orow = ob + m * 68 + q * 16;
    *(float4*)(ov + 0)  = *(const float4*)(orow);
    *(float4*)(ov + 4)  = *(const float4*)(orow + 4);
    *(float4*)(ov + 8)  = *(const float4*)(orow + 8);
    *(float4*)(ov + 12) = *(const float4*)(orow + 12);
    size_t yo = (size_t)row * 64 + q * 16;
    U8h H0, H1, L0, L1;
    H0.v = *(const f16x8*)(yh + yo);     H1.v = *(const f16x8*)(yh + yo + 8);
    L0.v = *(const f16x8*)(yl + yo);     L1.v = *(const f16x8*)(yl + yo + 8);
    float nv[16];
#pragma unroll
    for (int i = 0; i < 8; ++i) {
      nv[i]     = fmaxf((float)H0.s[i] + (float)L0.s[i], ov[i]);
      nv[8 + i] = fmaxf((float)H1.s[i] + (float)L1.s[i], ov[8 + i]);
    }
    U8h O0, O1, P0, P1;
    dec8h(nv + 0, O0, P0);
    dec8h(nv + 8, O1, P1);
    *(f16x8*)(yh + yo)     = O0.v;
    *(f16x8*)(yh + yo + 8) = O1.v;
    *(f16x8*)(yl + yo)     = P0.v;
    *(f16x8*)(yl + yo + 8) = P1.v;
  }
}

// ---------------- out = feta(x): 64 -> 64 -> 64 -> 1 (VALU; small) ----------------
__global__ __launch_bounds__(256) void k_feta(const float* __restrict__ x,
                                              const float* __restrict__ w1, const float* __restrict__ b1,
                                              const float* __restrict__ w2, const float* __restrict__ b2,
                                              const float* __restrict__ w3,
                                              float* __restrict__ out, int N) {
  int lane = threadIdx.x & 63;
  int wid = (blockIdx.x * blockDim.x + threadIdx.x) >> 6;
  int base = wid * GE;
  float xr[GE];
#pragma unroll
  for (int e = 0; e < GE; ++e) {
    int i = base + e; if (i >= N) i = N - 1;
    xr[e] = x[(size_t)i * 64 + lane];
  }
  float acc[GE];
  float bb = b1[lane];
#pragma unroll
  for (int e = 0; e < GE; ++e) acc[e] = bb;
#pragma unroll 4
  for (int k = 0; k < 64; ++k) {
    float w = w1[k * 64 + lane];
#pragma unroll
    for (int e = 0; e < GE; ++e) acc[e] = fmaf(bcast(xr[e], k), w, acc[e]);
  }
  float h1[GE];
#pragma unroll
  for (int e = 0; e < GE; ++e) h1[e] = fmaxf(acc[e], 0.f);
  float b2v = b2[lane];
#pragma unroll
  for (int e = 0; e < GE; ++e) acc[e] = b2v;
#pragma unroll 4
  for (int k = 0; k < 64; ++k) {
    float w = w2[k * 64 + lane];
#pragma unroll
    for (int e = 0; e < GE; ++e) acc[e] = fmaf(bcast(h1[e], k), w, acc[e]);
  }
  float w3l = w3[lane];
#pragma unroll
  for (int e = 0; e < GE; ++e) {
    float r = fmaxf(acc[e], 0.f) * w3l;
    for (int off = 32; off > 0; off >>= 1) r += __shfl_xor(r, off, 64);
    int i = base + e;
    if (lane == 0 && i < N) out[i] = r;
  }
}

__global__ __launch_bounds__(256) void k_copy(const float4* __restrict__ s,
                                              float4* __restrict__ d, int n4) {
  int i = blockIdx.x * 256 + threadIdx.x;
  if (i < n4) d[i] = s[i];
}

extern "C" void kernel_launch(void* const* d_in, const int* in_sizes, int n_in,
                              void* d_out, int out_size, void* d_ws, size_t ws_size,
                              hipStream_t stream) {
  const float* v      = (const float*)d_in[0];
  const float* labels = (const float*)d_in[1];
  const int*   ei     = (const int*)d_in[2];
  const float* hx_w1 = (const float*)d_in[4];
  const float* hx_b1 = (const float*)d_in[5];
  const float* hx_w2 = (const float*)d_in[6];
  const float* hx_b2 = (const float*)d_in[7];
  const float* hy_w1 = (const float*)d_in[8];
  const float* hy_b1 = (const float*)d_in[9];
  const float* hy_w2 = (const float*)d_in[10];
  const float* hy_b2 = (const float*)d_in[11];
  const float* fx_w1 = (const float*)d_in[12];
  const float* fx_b1 = (const float*)d_in[13];
  const float* fx_w2 = (const float*)d_in[14];
  const float* fx_b2 = (const float*)d_in[15];
  const float* fy_w1 = (const float*)d_in[16];
  const float* fy_b1 = (const float*)d_in[17];
  const float* fy_w2 = (const float*)d_in[18];
  const float* fy_b2 = (const float*)d_in[19];
  const float* feta_w1 = (const float*)d_in[20];
  const float* feta_b1 = (const float*)d_in[21];
  const float* feta_w2 = (const float*)d_in[22];
  const float* feta_b2 = (const float*)d_in[23];
  const float* feta_w3 = (const float*)d_in[24];

  int N = in_sizes[0] / 7;
  int E = in_sizes[2] / 2;
  const int* src = ei;
  const int* dst = ei + E;

  char* wsb = (char*)d_ws;
  float* goal = (float*)wsb;                                     // 16 f
  u64* goalkey = (u64*)(wsb + 16 * 4);
  float* xa = (float*)(wsb + 32 * 4);                            // N*64 f
  float* xb = xa + (size_t)N * 64;                               // N*64 f
  _Float16* yh = (_Float16*)(xb + (size_t)N * 64);               // E*64 f16
  _Float16* yl = yh + (size_t)E * 64;                            // E*64 f16
  _Float16* wp = yl + (size_t)E * 64;                            // 34816 f16
  float* vcp = (float*)(wp + 34816);                             // N*16 f
  int* deg = (int*)(vcp + (size_t)N * 16);                       // N
  int* rowptr = deg + N;                                         // N+1
  int* cursor = rowptr + N + 1;                                  // N
  int* eid = cursor + N;                                         // E
  int* srcp = eid + E;                                           // E
  int* dstp = srcp + E;                                          // E
  int* bsum = dstp + E;                                          // 64
  int* boff = bsum + 64;                                         // 64

  _Float16* fxB1 = wp;          _Float16* fxB2 = wp + 12288;
  _Float16* fyB1 = wp + 16384;  _Float16* fyB2 = wp + 24576;
  _Float16* hyB1 = wp + 28672;  _Float16* hyB2 = wp + 30720;

  int SB = (N + 1023) / 1024;  // scan blocks

  hipMemsetAsync(goalkey, 0, sizeof(u64), stream);
  hipMemsetAsync(deg, 0, (size_t)N * 4, stream);
  k_prep<<<17, 256, 0, stream>>>(fx_w1, fx_w2, fy_w1, fy_w2, hy_w1, hy_w2, wp);
  k_vc<<<(N * 16 + 255) / 256, 256, 0, stream>>>(v, labels, vcp, N);
  k_goal1<<<(N + 255) / 256, 256, 0, stream>>>(labels, N, goalkey);
  k_goal2<<<1, 64, 0, stream>>>(v, labels, goalkey, goal);
  k_hist<<<(E + 255) / 256, 256, 0, stream>>>(dst, E, deg);
  k_scan1<<<SB, 256, 0, stream>>>(deg, N, bsum);
  k_scan2<<<1, 64, 0, stream>>>(bsum, SB, boff, rowptr, N, E);
  k_scan3<<<SB, 256, 0, stream>>>(deg, boff, N, rowptr, cursor);
  k_scatter<<<(E + 255) / 256, 256, 0, stream>>>(dst, E, cursor, eid);
  k_perm<<<(E + 255) / 256, 256, 0, stream>>>(src, dst, eid, E, srcp, dstp);

  k_hx<<<(N + 31) / 32, 256, 0, stream>>>(v, labels, goal, hx_w1, hx_b1, hx_w2, hx_b2, xa, N);
  k_hy<<<(E + 63) / 64, 256, 0, stream>>>(vcp, srcp, dstp,
                                          hyB1, hy_b1, hyB2, hy_b2, yh, yl, E);

  float* xc = xa;
  float* xo = xb;
  for (int t = 0; t < 3; ++t) {
    k_copy<<<(N * 16 + 255) / 256, 256, 0, stream>>>((const float4*)xc, (float4*)xo, N * 16);
    k_fx<<<(E + 63) / 64, 256, 0, stream>>>(xc, yh, yl, srcp, dstp,
                                            fxB1, fx_b1, fxB2, fx_b2, xo, E);
    float* tmp = xc; xc = xo; xo = tmp;
    if (t < 2) {
      k_fy<<<(E + 63) / 64, 256, 0, stream>>>(xc, yh, yl, srcp, dstp,
                                              fyB1, fy_b1, fyB2, fy_b2, E);
    }
  }
  k_feta<<<(N + 31) / 32, 256, 0, stream>>>(xc, feta_w1, feta_b1, feta_w2, feta_b2, feta_w3,
                                            (float*)d_out, N);
}

// Round 7
// 565.156 us; speedup vs baseline: 4.3139x; 1.0283x over previous
//
#include <hip/hip_runtime.h>
#include <math.h>

typedef unsigned short u16;
typedef unsigned int u32;
typedef unsigned long long u64;
typedef __attribute__((ext_vector_type(8))) _Float16 f16x8;
typedef __attribute__((ext_vector_type(2))) _Float16 f16x2;
typedef __attribute__((ext_vector_type(4))) float f32x4;

union U8h { f16x8 v; f16x2 p[4]; u32 u[4]; _Float16 s[8]; };

#define GE 8  // nodes per wave for the VALU kernels

__device__ __forceinline__ float bcast(float v, int k) {
  return __int_as_float(__builtin_amdgcn_readlane(__float_as_int(v), k));
}

__device__ __forceinline__ void atomicMaxF(float* addr, float val) {
  if (val >= 0.0f) {
    atomicMax((int*)addr, __float_as_int(val));
  } else {
    atomicMin((unsigned int*)addr, (unsigned int)__float_as_int(val));
  }
}

__device__ __forceinline__ f16x2 pk(float a, float b) {
  return __builtin_bit_cast(f16x2, __builtin_amdgcn_cvt_pkrtz(a, b));
}

// split 8 fp32 -> fp16 hi (RTZ) + lo (residual): hi+lo exact to ~2^-22 (both consumed)
__device__ __forceinline__ void dec8h(const float* f, U8h& h, U8h& l) {
#pragma unroll
  for (int i = 0; i < 4; ++i) {
    float a = f[2 * i], b = f[2 * i + 1];
    f16x2 hp = pk(a, b);
    float ra = a - (float)hp[0];
    float rb = b - (float)hp[1];
    h.p[i] = hp;
    l.p[i] = pk(ra, rb);
  }
}

// split with RNE hi (hi alone is best fp16 approx; hi+lo still ~2^-22) — for y storage
__device__ __forceinline__ void dec8h_rne(const float* f, U8h& h, U8h& l) {
#pragma unroll
  for (int i = 0; i < 8; ++i) {
    _Float16 hh = (_Float16)f[i];  // RNE
    h.s[i] = hh;
    l.s[i] = (_Float16)(f[i] - (float)hh);
  }
}

// load lane's two 8-float chunks of a 64-float row (chunks at q*8 and q*8+32)
__device__ __forceinline__ void load_row(const float* p, float* f) {
  *(float4*)(f + 0)  = *(const float4*)(p);
  *(float4*)(f + 4)  = *(const float4*)(p + 4);
  *(float4*)(f + 8)  = *(const float4*)(p + 32);
  *(float4*)(f + 12) = *(const float4*)(p + 36);
}

// ---------------- goal: argmax over labels[:,1]; wave-reduced atomic ----------------
__global__ __launch_bounds__(256) void k_goal1(const float* __restrict__ labels, int N,
                                               u64* __restrict__ key) {
  int i = blockIdx.x * 256 + threadIdx.x;
  float val = (i < N) ? labels[2 * (size_t)i + 1] : 0.0f;
  u64 k = ((u64)__float_as_uint(fmaxf(val, 0.0f)) << 32) | (u32)(~(u32)i);
#pragma unroll
  for (int off = 32; off > 0; off >>= 1) {
    u64 o = __shfl_xor(k, off, 64);
    if (o > k) k = o;
  }
  if ((threadIdx.x & 63) == 0) atomicMax(key, k);
}

__global__ void k_goal2(const float* __restrict__ v, const float* __restrict__ labels,
                        const u64* __restrict__ key, float* __restrict__ goal) {
  int g = (int)(~(u32)(*key));
  int c = threadIdx.x;
  if (c < 9) goal[c] = (c < 7) ? v[7 * (size_t)g + c] : labels[2 * (size_t)g + (c - 7)];
}

// ---------------- vcp build + degree histogram (fused) ----------------
__global__ __launch_bounds__(256) void k_vch(const float* __restrict__ v,
                                             const float* __restrict__ labels,
                                             float* __restrict__ vcp, int N,
                                             const int* __restrict__ dst, int E,
                                             int* __restrict__ deg) {
  int tid = blockIdx.x * 256 + threadIdx.x;
  if (tid < N * 16) {
    int n = tid >> 4, c = tid & 15;
    float val = 0.f;
    if (c < 7) val = v[(size_t)n * 7 + c];
    else if (c == 7) val = labels[2 * (size_t)n];
    else if (c == 8) val = labels[2 * (size_t)n + 1];
    vcp[tid] = val;
  }
  if (tid < E) atomicAdd(&deg[dst[tid]], 1);
}

// ---------------- weight prep: folded concat + single RNE fp16, frag-major ----------
__global__ __launch_bounds__(256) void k_prep(const float* __restrict__ fxw1, const float* __restrict__ fxw2,
                                              const float* __restrict__ fyw1, const float* __restrict__ fyw2,
                                              const float* __restrict__ hyw1, const float* __restrict__ hyw2,
                                              _Float16* __restrict__ wp) {
  _Float16* fxB1 = wp;          // 12288
  _Float16* fxB2 = wp + 12288;  // 4096
  _Float16* fyB1 = wp + 16384;  // 8192
  _Float16* fyB2 = wp + 24576;  // 4096
  _Float16* hyB1 = wp + 28672;  // 2048
  _Float16* hyB2 = wp + 30720;  // 4096
  int tid = blockIdx.x * 256 + threadIdx.x;
  int which, id;
  _Float16* oh;
  if (tid < 1536)      { which = 0; id = tid;        oh = fxB1; }
  else if (tid < 2048) { which = 1; id = tid - 1536; oh = fxB2; }
  else if (tid < 3072) { which = 2; id = tid - 2048; oh = fyB1; }
  else if (tid < 3584) { which = 3; id = tid - 3072; oh = fyB2; }
  else if (tid < 3840) { which = 4; id = tid - 3584; oh = hyB1; }
  else if (tid < 4352) { which = 5; id = tid - 3840; oh = hyB2; }
  else return;
  int lane = id & 63;
  int q = lane >> 4, col = lane & 15;
  int c = id >> 8, t = (id >> 6) & 3;
#pragma unroll
  for (int j = 0; j < 8; ++j) {
    int k = c * 32 + q * 8 + j;
    int n = t * 16 + col;
    float w;
    if (which == 0) {
      w = (k < 64)  ? fxw1[k * 64 + n] + fxw1[(k + 64) * 64 + n]
        : (k < 128) ? fxw1[(k + 64) * 64 + n] - fxw1[(k - 64) * 64 + n]
                    : fxw1[(k + 64) * 64 + n];
    } else if (which == 1) {
      w = fxw2[k * 64 + n];
    } else if (which == 2) {
      w = (k < 64) ? fyw1[k * 64 + n] + fyw1[(k + 64) * 64 + n]
                   : fyw1[(k + 64) * 64 + n] - fyw1[(k - 64) * 64 + n];
    } else if (which == 3) {
      w = fyw2[k * 64 + n];
    } else if (which == 4) {
      if (k <= 8)                  w = hyw1[k * 64 + n] + hyw1[(k + 9) * 64 + n];
      else if (k >= 16 && k <= 24) w = hyw1[(k + 2) * 64 + n] - hyw1[(k - 16) * 64 + n];
      else                         w = 0.f;
    } else {
      w = hyw2[k * 64 + n];
    }
    oh[id * 8 + j] = (_Float16)w;  // RNE
  }
}

// ---------------- CSR scan (deg -> cursor) ----------------
__global__ __launch_bounds__(256) void k_scan1(const int* __restrict__ deg, int N,
                                               int* __restrict__ bsum) {
  __shared__ int red[256];
  int b = blockIdx.x;
  int s = 0;
  for (int i = threadIdx.x; i < 1024; i += 256) {
    int idx = b * 1024 + i;
    s += (idx < N) ? deg[idx] : 0;
  }
  red[threadIdx.x] = s; __syncthreads();
  for (int st = 128; st > 0; st >>= 1) {
    if (threadIdx.x < st) red[threadIdx.x] += red[threadIdx.x + st];
    __syncthreads();
  }
  if (threadIdx.x == 0) bsum[b] = red[0];
}

__global__ void k_scan2(const int* __restrict__ bsum, int B, int* __restrict__ boff) {
  if (threadIdx.x == 0) {
    int acc = 0;
    for (int i = 0; i < B; ++i) { boff[i] = acc; acc += bsum[i]; }
  }
}

__global__ __launch_bounds__(256) void k_scan3(const int* __restrict__ deg,
                                               const int* __restrict__ boff, int N,
                                               int* __restrict__ cursor) {
  __shared__ int lsum[256];
  int b = blockIdx.x;
  int tid = threadIdx.x;
  int base_i = b * 1024 + tid * 4;
  int loc[4]; int s = 0;
#pragma unroll
  for (int j = 0; j < 4; ++j) {
    int v = (base_i + j < N) ? deg[base_i + j] : 0;
    loc[j] = s; s += v;
  }
  lsum[tid] = s; __syncthreads();
  for (int st = 1; st < 256; st <<= 1) {
    int add = (tid >= st) ? lsum[tid - st] : 0;
    __syncthreads();
    lsum[tid] += add;
    __syncthreads();
  }
  int toff = boff[b] + lsum[tid] - s;
#pragma unroll
  for (int j = 0; j < 4; ++j) {
    if (base_i + j < N) cursor[base_i + j] = toff + loc[j];
  }
}

// scatter edges into dst-sorted order, writing srcp/dstp directly
__global__ __launch_bounds__(256) void k_scatter(const int* __restrict__ src,
                                                 const int* __restrict__ dst, int E,
                                                 int* __restrict__ cursor,
                                                 int* __restrict__ srcp, int* __restrict__ dstp) {
  int e = blockIdx.x * 256 + threadIdx.x;
  if (e < E) {
    int d = dst[e];
    int pos = atomicAdd(&cursor[d], 1);
    srcp[pos] = src[e];
    dstp[pos] = d;
  }
}

// ---------------- x0 = MLP2([vc, goal, d, d*d]) , 36 -> 64 -> 64 (VALU; small) ----------
__global__ __launch_bounds__(256) void k_hx(const float* __restrict__ v,
                                            const float* __restrict__ labels,
                                            const float* __restrict__ goal,
                                            const float* __restrict__ w1, const float* __restrict__ b1,
                                            const float* __restrict__ w2, const float* __restrict__ b2,
                                            float* __restrict__ xout, int N) {
  int lane = threadIdx.x & 63;
  int wid = (blockIdx.x * blockDim.x + threadIdx.x) >> 6;
  int base = wid * GE;
  int c = lane % 9;
  float f[GE];
#pragma unroll
  for (int e = 0; e < GE; ++e) {
    int i = base + e; if (i >= N) i = N - 1;
    float fv = 0.f;
    if (lane < 36) {
      float vcv = (c < 7) ? v[7 * i + c] : labels[2 * i + (c - 7)];
      float gl = goal[c];
      float d = vcv - gl;
      fv = (lane < 9) ? vcv : (lane < 18) ? gl : (lane < 27) ? d : d * d;
    }
    f[e] = fv;
  }
  float acc[GE];
  float bb = b1[lane];
#pragma unroll
  for (int e = 0; e < GE; ++e) acc[e] = bb;
  for (int k = 0; k < 36; ++k) {
    float w = w1[k * 64 + lane];
#pragma unroll
    for (int e = 0; e < GE; ++e) acc[e] = fmaf(bcast(f[e], k), w, acc[e]);
  }
  float h[GE];
#pragma unroll
  for (int e = 0; e < GE; ++e) h[e] = fmaxf(acc[e], 0.f);
  float b2v = b2[lane];
#pragma unroll
  for (int e = 0; e < GE; ++e) acc[e] = b2v;
#pragma unroll 4
  for (int k = 0; k < 64; ++k) {
    float w = w2[k * 64 + lane];
#pragma unroll
    for (int e = 0; e < GE; ++e) acc[e] = fmaf(bcast(h[e], k), w, acc[e]);
  }
#pragma unroll
  for (int e = 0; e < GE; ++e) {
    int i = base + e;
    if (i < N) xout[(size_t)i * 64 + lane] = acc[e];
  }
}

// ---------------- hy (MFMA fp16): y0 = MLP2([vcj(16) ; vci(16)] folded), K=32 ----------
__global__ __launch_bounds__(256) void k_hy(
    const float* __restrict__ vcp,
    const int* __restrict__ src, const int* __restrict__ dst,
    const _Float16* __restrict__ B1, const float* __restrict__ b1,
    const _Float16* __restrict__ B2, const float* __restrict__ b2,
    _Float16* __restrict__ yh, _Float16* __restrict__ yl, int E) {
  __shared__ float hbuf[4][2][16 * 68];  // wave-private; no barriers
  const int lane = threadIdx.x & 63;
  const int wv = threadIdx.x >> 6;
  const int m = lane & 15, q = lane >> 4;
  const int base = blockIdx.x * 64 + wv * 16;
  int em = base + m; if (em >= E) em = E - 1;
  const int node = (q < 2) ? dst[em] : src[em];
  const float* p = vcp + (size_t)node * 16 + (q & 1) * 8;
  float f[8];
  *(float4*)(f + 0) = *(const float4*)(p);
  *(float4*)(f + 4) = *(const float4*)(p + 4);
  U8h Ah, Al;
  dec8h(f, Ah, Al);

  f32x4 acc[4];
#pragma unroll
  for (int t = 0; t < 4; ++t) { float bv = b1[t * 16 + m]; acc[t] = (f32x4){bv, bv, bv, bv}; }
#pragma unroll
  for (int t = 0; t < 4; ++t) {
    f16x8 b = *(const f16x8*)(B1 + ((size_t)t * 64 + lane) * 8);
    acc[t] = __builtin_amdgcn_mfma_f32_16x16x32_f16(Ah.v, b, acc[t], 0, 0, 0);
    acc[t] = __builtin_amdgcn_mfma_f32_16x16x32_f16(Al.v, b, acc[t], 0, 0, 0);
  }

  float* hb = hbuf[wv][0];
#pragma unroll
  for (int t = 0; t < 4; ++t)
#pragma unroll
    for (int r = 0; r < 4; ++r)
      hb[(q * 4 + r) * 68 + t * 16 + m] = fmaxf(acc[t][r], 0.f);

  float fh[16];
  const float* hr = hb + m * 68 + q * 8;
  *(float4*)(fh + 0)  = *(const float4*)(hr);
  *(float4*)(fh + 4)  = *(const float4*)(hr + 4);
  *(float4*)(fh + 8)  = *(const float4*)(hr + 32);
  *(float4*)(fh + 12) = *(const float4*)(hr + 36);
  U8h A2h[2], A2l[2];
  dec8h(fh + 0, A2h[0], A2l[0]);
  dec8h(fh + 8, A2h[1], A2l[1]);

  f32x4 acc2[4];
#pragma unroll
  for (int t = 0; t < 4; ++t) { float bv = b2[t * 16 + m]; acc2[t] = (f32x4){bv, bv, bv, bv}; }
#pragma unroll
  for (int c = 0; c < 2; ++c) {
#pragma unroll
    for (int t = 0; t < 4; ++t) {
      f16x8 b = *(const f16x8*)(B2 + ((size_t)(c * 4 + t) * 64 + lane) * 8);
      acc2[t] = __builtin_amdgcn_mfma_f32_16x16x32_f16(A2h[c].v, b, acc2[t], 0, 0, 0);
      acc2[t] = __builtin_amdgcn_mfma_f32_16x16x32_f16(A2l[c].v, b, acc2[t], 0, 0, 0);
    }
  }

  float* ob = hbuf[wv][1];
#pragma unroll
  for (int t = 0; t < 4; ++t)
#pragma unroll
    for (int r = 0; r < 4; ++r)
      ob[(q * 4 + r) * 68 + t * 16 + m] = acc2[t][r];

  int row = base + m;
  if (row < E) {
    float ov[16];
    const float* orow = ob + m * 68 + q * 16;
    *(float4*)(ov + 0)  = *(const float4*)(orow);
    *(float4*)(ov + 4)  = *(const float4*)(orow + 4);
    *(float4*)(ov + 8)  = *(const float4*)(orow + 8);
    *(float4*)(ov + 12) = *(const float4*)(orow + 12);
    size_t yo = (size_t)row * 64 + q * 16;
    U8h H0, H1, L0, L1;
    dec8h_rne(ov + 0, H0, L0);
    dec8h_rne(ov + 8, H1, L1);
    *(f16x8*)(yh + yo)     = H0.v;
    *(f16x8*)(yh + yo + 8) = H1.v;
    *(f16x8*)(yl + yo)     = L0.v;
    *(f16x8*)(yl + yo + 8) = L1.v;
  }
}

// ---------------- fx: 2-tile MFMA fp16 (yh only) + segmented max + atomics ----------
__global__ __launch_bounds__(256) void k_fx(
    const float* __restrict__ x, const _Float16* __restrict__ yh,
    const int* __restrict__ src, const int* __restrict__ dst,
    const _Float16* __restrict__ B1, const float* __restrict__ b1,
    const _Float16* __restrict__ B2, const float* __restrict__ b2,
    float* __restrict__ xnew, int E) {
  __shared__ float hbuf[4][2][16 * 68];  // wave-private; no barriers
  const int lane = threadIdx.x & 63;
  const int wv = threadIdx.x >> 6;
  const int m = lane & 15, q = lane >> 4;
  const int base = blockIdx.x * 128 + wv * 32;  // 2 tiles of 16
  int em0 = base + m;       if (em0 >= E) em0 = E - 1;
  int em1 = base + 16 + m;  if (em1 >= E) em1 = E - 1;
  const int si0 = src[em0], di0 = dst[em0];
  const int si1 = src[em1], di1 = dst[em1];

  // issue ALL gathers for both tiles before compute (MLP)
  float fs0[16], fd0[16], fs1[16], fd1[16];
  load_row(x + (size_t)si0 * 64 + q * 8, fs0);
  load_row(x + (size_t)di0 * 64 + q * 8, fd0);
  load_row(x + (size_t)si1 * 64 + q * 8, fs1);
  load_row(x + (size_t)di1 * 64 + q * 8, fd1);
  U8h Y0[2], Y1[2];
  {
    const _Float16* p0 = yh + (size_t)em0 * 64 + q * 8;
    const _Float16* p1 = yh + (size_t)em1 * 64 + q * 8;
    Y0[0].v = *(const f16x8*)(p0);  Y0[1].v = *(const f16x8*)(p0 + 32);
    Y1[0].v = *(const f16x8*)(p1);  Y1[1].v = *(const f16x8*)(p1 + 32);
  }

  U8h Ah0[4], Al0[4], Ah1[4], Al1[4];
  dec8h(fs0 + 0, Ah0[0], Al0[0]);
  dec8h(fs0 + 8, Ah0[1], Al0[1]);
  dec8h(fd0 + 0, Ah0[2], Al0[2]);
  dec8h(fd0 + 8, Ah0[3], Al0[3]);
  dec8h(fs1 + 0, Ah1[0], Al1[0]);
  dec8h(fs1 + 8, Ah1[1], Al1[1]);
  dec8h(fd1 + 0, Ah1[2], Al1[2]);
  dec8h(fd1 + 8, Ah1[3], Al1[3]);

  f32x4 acc0[4], acc1[4];
#pragma unroll
  for (int t = 0; t < 4; ++t) {
    float bv = b1[t * 16 + m];
    acc0[t] = (f32x4){bv, bv, bv, bv};
    acc1[t] = (f32x4){bv, bv, bv, bv};
  }
#pragma unroll
  for (int c = 0; c < 4; ++c) {
#pragma unroll
    for (int t = 0; t < 4; ++t) {
      f16x8 b = *(const f16x8*)(B1 + ((size_t)(c * 4 + t) * 64 + lane) * 8);
      acc0[t] = __builtin_amdgcn_mfma_f32_16x16x32_f16(Ah0[c].v, b, acc0[t], 0, 0, 0);
      acc0[t] = __builtin_amdgcn_mfma_f32_16x16x32_f16(Al0[c].v, b, acc0[t], 0, 0, 0);
      acc1[t] = __builtin_amdgcn_mfma_f32_16x16x32_f16(Ah1[c].v, b, acc1[t], 0, 0, 0);
      acc1[t] = __builtin_amdgcn_mfma_f32_16x16x32_f16(Al1[c].v, b, acc1[t], 0, 0, 0);
    }
  }
#pragma unroll
  for (int c = 4; c < 6; ++c) {
#pragma unroll
    for (int t = 0; t < 4; ++t) {
      f16x8 b = *(const f16x8*)(B1 + ((size_t)(c * 4 + t) * 64 + lane) * 8);
      acc0[t] = __builtin_amdgcn_mfma_f32_16x16x32_f16(Y0[c - 4].v, b, acc0[t], 0, 0, 0);
      acc1[t] = __builtin_amdgcn_mfma_f32_16x16x32_f16(Y1[c - 4].v, b, acc1[t], 0, 0, 0);
    }
  }

  // ReLU + transpose both tiles (wave-private LDS)
  float* hb0 = hbuf[wv][0];
  float* hb1 = hbuf[wv][1];
#pragma unroll
  for (int t = 0; t < 4; ++t)
#pragma unroll
    for (int r = 0; r < 4; ++r) {
      hb0[(q * 4 + r) * 68 + t * 16 + m] = fmaxf(acc0[t][r], 0.f);
      hb1[(q * 4 + r) * 68 + t * 16 + m] = fmaxf(acc1[t][r], 0.f);
    }

  float fh0[16], fh1[16];
  load_row(hb0 + m * 68 + q * 8 - ((q * 8 >= 32) ? 0 : 0), fh0);  // layout matches load_row
  load_row(hb1 + m * 68 + q * 8, fh1);
  U8h A2h0[2], A2l0[2], A2h1[2], A2l1[2];
  dec8h(fh0 + 0, A2h0[0], A2l0[0]);
  dec8h(fh0 + 8, A2h0[1], A2l0[1]);
  dec8h(fh1 + 0, A2h1[0], A2l1[0]);
  dec8h(fh1 + 8, A2h1[1], A2l1[1]);

  f32x4 o0[4], o1[4];
#pragma unroll
  for (int t = 0; t < 4; ++t) {
    float bv = b2[t * 16 + m];
    o0[t] = (f32x4){bv, bv, bv, bv};
    o1[t] = (f32x4){bv, bv, bv, bv};
  }
#pragma unroll
  for (int c = 0; c < 2; ++c) {
#pragma unroll
    for (int t = 0; t < 4; ++t) {
      f16x8 b = *(const f16x8*)(B2 + ((size_t)(c * 4 + t) * 64 + lane) * 8);
      o0[t] = __builtin_amdgcn_mfma_f32_16x16x32_f16(A2h0[c].v, b, o0[t], 0, 0, 0);
      o0[t] = __builtin_amdgcn_mfma_f32_16x16x32_f16(A2l0[c].v, b, o0[t], 0, 0, 0);
      o1[t] = __builtin_amdgcn_mfma_f32_16x16x32_f16(A2h1[c].v, b, o1[t], 0, 0, 0);
      o1[t] = __builtin_amdgcn_mfma_f32_16x16x32_f16(A2l1[c].v, b, o1[t], 0, 0, 0);
    }
  }

  // segmented max per tile (dst-sorted), one atomic per run; dd is q-uniform
#pragma unroll
  for (int ti = 0; ti < 2; ++ti) {
    const f32x4* oo = ti ? o1 : o0;
    int tb = base + ti * 16;
    int dd[5];
    int e0 = tb + q * 4;
#pragma unroll
    for (int r = 0; r < 5; ++r) {
      int e2 = e0 + r;
      dd[r] = (e2 < E) ? dst[e2] : -1;
    }
#pragma unroll
    for (int t = 0; t < 4; ++t) {
      float run = 0.f;
      bool have = false;
#pragma unroll
      for (int r = 0; r < 4; ++r) {
        if (dd[r] >= 0) {
          run = have ? fmaxf(run, oo[t][r]) : oo[t][r];
          have = true;
          if (r == 3 || dd[r + 1] != dd[r]) {
            atomicMaxF(&xnew[(size_t)dd[r] * 64 + t * 16 + m], run);
            have = false;
          }
        }
      }
    }
  }
}

// ---------------- fy: 2-tile MFMA fp16, y = max(y, MLP2([xd,xs] folded)), K=128 ----------
__global__ __launch_bounds__(256) void k_fy(
    const float* __restrict__ x, _Float16* __restrict__ yh, _Float16* __restrict__ yl,
    const int* __restrict__ src, const int* __restrict__ dst,
    const _Float16* __restrict__ B1, const float* __restrict__ b1,
    const _Float16* __restrict__ B2, const float* __restrict__ b2,
    int E) {
  __shared__ float hbuf[4][2][16 * 68];  // wave-private; region reused h->out per tile
  const int lane = threadIdx.x & 63;
  const int wv = threadIdx.x >> 6;
  const int m = lane & 15, q = lane >> 4;
  const int base = blockIdx.x * 128 + wv * 32;
  int em0 = base + m;       if (em0 >= E) em0 = E - 1;
  int em1 = base + 16 + m;  if (em1 >= E) em1 = E - 1;
  const int si0 = src[em0], di0 = dst[em0];
  const int si1 = src[em1], di1 = dst[em1];

  float fd0[16], fs0[16], fd1[16], fs1[16];
  load_row(x + (size_t)di0 * 64 + q * 8, fd0);
  load_row(x + (size_t)si0 * 64 + q * 8, fs0);
  load_row(x + (size_t)di1 * 64 + q * 8, fd1);
  load_row(x + (size_t)si1 * 64 + q * 8, fs1);

  U8h Ah0[4], Al0[4], Ah1[4], Al1[4];
  dec8h(fd0 + 0, Ah0[0], Al0[0]);   // chunks 0,1: xd (W0+W1)
  dec8h(fd0 + 8, Ah0[1], Al0[1]);
  dec8h(fs0 + 0, Ah0[2], Al0[2]);   // chunks 2,3: xs (W2-W0)
  dec8h(fs0 + 8, Ah0[3], Al0[3]);
  dec8h(fd1 + 0, Ah1[0], Al1[0]);
  dec8h(fd1 + 8, Ah1[1], Al1[1]);
  dec8h(fs1 + 0, Ah1[2], Al1[2]);
  dec8h(fs1 + 8, Ah1[3], Al1[3]);

  f32x4 acc0[4], acc1[4];
#pragma unroll
  for (int t = 0; t < 4; ++t) {
    float bv = b1[t * 16 + m];
    acc0[t] = (f32x4){bv, bv, bv, bv};
    acc1[t] = (f32x4){bv, bv, bv, bv};
  }
#pragma unroll
  for (int c = 0; c < 4; ++c) {
#pragma unroll
    for (int t = 0; t < 4; ++t) {
      f16x8 b = *(const f16x8*)(B1 + ((size_t)(c * 4 + t) * 64 + lane) * 8);
      acc0[t] = __builtin_amdgcn_mfma_f32_16x16x32_f16(Ah0[c].v, b, acc0[t], 0, 0, 0);
      acc0[t] = __builtin_amdgcn_mfma_f32_16x16x32_f16(Al0[c].v, b, acc0[t], 0, 0, 0);
      acc1[t] = __builtin_amdgcn_mfma_f32_16x16x32_f16(Ah1[c].v, b, acc1[t], 0, 0, 0);
      acc1[t] = __builtin_amdgcn_mfma_f32_16x16x32_f16(Al1[c].v, b, acc1[t], 0, 0, 0);
    }
  }

  float* hb0 = hbuf[wv][0];
  float* hb1 = hbuf[wv][1];
#pragma unroll
  for (int t = 0; t < 4; ++t)
#pragma unroll
    for (int r = 0; r < 4; ++r) {
      hb0[(q * 4 + r) * 68 + t * 16 + m] = fmaxf(acc0[t][r], 0.f);
      hb1[(q * 4 + r) * 68 + t * 16 + m] = fmaxf(acc1[t][r], 0.f);
    }

  float fh0[16], fh1[16];
  load_row(hb0 + m * 68 + q * 8, fh0);
  load_row(hb1 + m * 68 + q * 8, fh1);
  U8h A2h0[2], A2l0[2], A2h1[2], A2l1[2];
  dec8h(fh0 + 0, A2h0[0], A2l0[0]);
  dec8h(fh0 + 8, A2h0[1], A2l0[1]);
  dec8h(fh1 + 0, A2h1[0], A2l1[0]);
  dec8h(fh1 + 8, A2h1[1], A2l1[1]);

  f32x4 o0[4], o1[4];
#pragma unroll
  for (int t = 0; t < 4; ++t) {
    float bv = b2[t * 16 + m];
    o0[t] = (f32x4){bv, bv, bv, bv};
    o1[t] = (f32x4){bv, bv, bv, bv};
  }
#pragma unroll
  for (int c = 0; c < 2; ++c) {
#pragma unroll
    for (int t = 0; t < 4; ++t) {
      f16x8 b = *(const f16x8*)(B2 + ((size_t)(c * 4 + t) * 64 + lane) * 8);
      o0[t] = __builtin_amdgcn_mfma_f32_16x16x32_f16(A2h0[c].v, b, o0[t], 0, 0, 0);
      o0[t] = __builtin_amdgcn_mfma_f32_16x16x32_f16(A2l0[c].v, b, o0[t], 0, 0, 0);
      o1[t] = __builtin_amdgcn_mfma_f32_16x16x32_f16(A2h1[c].v, b, o1[t], 0, 0, 0);
      o1[t] = __builtin_amdgcn_mfma_f32_16x16x32_f16(A2l1[c].v, b, o1[t], 0, 0, 0);
    }
  }

  // transpose out (reuse h regions; wave-level LDS ops are in-order) + max-update y
#pragma unroll
  for (int t = 0; t < 4; ++t)
#pragma unroll
    for (int r = 0; r < 4; ++r) {
      hb0[(q * 4 + r) * 68 + t * 16 + m] = o0[t][r];
      hb1[(q * 4 + r) * 68 + t * 16 + m] = o1[t][r];
    }

#pragma unroll
  for (int ti = 0; ti < 2; ++ti) {
    int row = base + ti * 16 + m;
    if (row < E) {
      const float* ob = ti ? hb1 : hb0;
      float ov[16];
      const float* orow = ob + m * 68 + q * 16;
      *(float4*)(ov + 0)  = *(const float4*)(orow);
      *(float4*)(ov + 4)  = *(const float4*)(orow + 4);
      *(float4*)(ov + 8)  = *(const float4*)(orow + 8);
      *(float4*)(ov + 12) = *(const float4*)(orow + 12);
      size_t yo = (size_t)row * 64 + q * 16;
      U8h H0, H1, L0, L1;
      H0.v = *(const f16x8*)(yh + yo);     H1.v = *(const f16x8*)(yh + yo + 8);
      L0.v = *(const f16x8*)(yl + yo);     L1.v = *(const f16x8*)(yl + yo + 8);
      float nv[16];
#pragma unroll
      for (int i = 0; i < 8; ++i) {
        nv[i]     = fmaxf((float)H0.s[i] + (float)L0.s[i], ov[i]);
        nv[8 + i] = fmaxf((float)H1.s[i] + (float)L1.s[i], ov[8 + i]);
      }
      U8h O0, O1, P0, P1;
      dec8h_rne(nv + 0, O0, P0);
      dec8h_rne(nv + 8, O1, P1);
      *(f16x8*)(yh + yo)     = O0.v;
      *(f16x8*)(yh + yo + 8) = O1.v;
      *(f16x8*)(yl + yo)     = P0.v;
      *(f16x8*)(yl + yo + 8) = P1.v;
    }
  }
}

// ---------------- out = feta(x): 64 -> 64 -> 64 -> 1 (VALU; small) ----------------
__global__ __launch_bounds__(256) void k_feta(const float* __restrict__ x,
                                              const float* __restrict__ w1, const float* __restrict__ b1,
                                              const float* __restrict__ w2, const float* __restrict__ b2,
                                              const float* __restrict__ w3,
                                              float* __restrict__ out, int N) {
  int lane = threadIdx.x & 63;
  int wid = (blockIdx.x * blockDim.x + threadIdx.x) >> 6;
  int base = wid * GE;
  float xr[GE];
#pragma unroll
  for (int e = 0; e < GE; ++e) {
    int i = base + e; if (i >= N) i = N - 1;
    xr[e] = x[(size_t)i * 64 + lane];
  }
  float acc[GE];
  float bb = b1[lane];
#pragma unroll
  for (int e = 0; e < GE; ++e) acc[e] = bb;
#pragma unroll 4
  for (int k = 0; k < 64; ++k) {
    float w = w1[k * 64 + lane];
#pragma unroll
    for (int e = 0; e < GE; ++e) acc[e] = fmaf(bcast(xr[e], k), w, acc[e]);
  }
  float h1[GE];
#pragma unroll
  for (int e = 0; e < GE; ++e) h1[e] = fmaxf(acc[e], 0.f);
  float b2v = b2[lane];
#pragma unroll
  for (int e = 0; e < GE; ++e) acc[e] = b2v;
#pragma unroll 4
  for (int k = 0; k < 64; ++k) {
    float w = w2[k * 64 + lane];
#pragma unroll
    for (int e = 0; e < GE; ++e) acc[e] = fmaf(bcast(h1[e], k), w, acc[e]);
  }
  float w3l = w3[lane];
#pragma unroll
  for (int e = 0; e < GE; ++e) {
    float r = fmaxf(acc[e], 0.f) * w3l;
    for (int off = 32; off > 0; off >>= 1) r += __shfl_xor(r, off, 64);
    int i = base + e;
    if (lane == 0 && i < N) out[i] = r;
  }
}

__global__ __launch_bounds__(256) void k_copy(const float4* __restrict__ s,
                                              float4* __restrict__ d, int n4) {
  int i = blockIdx.x * 256 + threadIdx.x;
  if (i < n4) d[i] = s[i];
}

extern "C" void kernel_launch(void* const* d_in, const int* in_sizes, int n_in,
                              void* d_out, int out_size, void* d_ws, size_t ws_size,
                              hipStream_t stream) {
  const float* v      = (const float*)d_in[0];
  const float* labels = (const float*)d_in[1];
  const int*   ei     = (const int*)d_in[2];
  const float* hx_w1 = (const float*)d_in[4];
  const float* hx_b1 = (const float*)d_in[5];
  const float* hx_w2 = (const float*)d_in[6];
  const float* hx_b2 = (const float*)d_in[7];
  const float* hy_w1 = (const float*)d_in[8];
  const float* hy_b1 = (const float*)d_in[9];
  const float* hy_w2 = (const float*)d_in[10];
  const float* hy_b2 = (const float*)d_in[11];
  const float* fx_w1 = (const float*)d_in[12];
  const float* fx_b1 = (const float*)d_in[13];
  const float* fx_w2 = (const float*)d_in[14];
  const float* fx_b2 = (const float*)d_in[15];
  const float* fy_w1 = (const float*)d_in[16];
  const float* fy_b1 = (const float*)d_in[17];
  const float* fy_w2 = (const float*)d_in[18];
  const float* fy_b2 = (const float*)d_in[19];
  const float* feta_w1 = (const float*)d_in[20];
  const float* feta_b1 = (const float*)d_in[21];
  const float* feta_w2 = (const float*)d_in[22];
  const float* feta_b2 = (const float*)d_in[23];
  const float* feta_w3 = (const float*)d_in[24];

  int N = in_sizes[0] / 7;
  int E = in_sizes[2] / 2;
  const int* src = ei;
  const int* dst = ei + E;

  char* wsb = (char*)d_ws;
  float* goal = (float*)wsb;                                     // 16 f
  u64* goalkey = (u64*)(wsb + 16 * 4);
  float* xa = (float*)(wsb + 32 * 4);                            // N*64 f
  float* xb = xa + (size_t)N * 64;                               // N*64 f
  _Float16* yh = (_Float16*)(xb + (size_t)N * 64);               // E*64 f16
  _Float16* yl = yh + (size_t)E * 64;                            // E*64 f16
  _Float16* wp = yl + (size_t)E * 64;                            // 34816 f16
  float* vcp = (float*)(wp + 34816);                             // N*16 f
  int* deg = (int*)(vcp + (size_t)N * 16);                       // N
  int* cursor = deg + N;                                         // N
  int* srcp = cursor + N;                                        // E
  int* dstp = srcp + E;                                          // E
  int* bsum = dstp + E;                                          // 64
  int* boff = bsum + 64;                                         // 64

  _Float16* fxB1 = wp;          _Float16* fxB2 = wp + 12288;
  _Float16* fyB1 = wp + 16384;  _Float16* fyB2 = wp + 24576;
  _Float16* hyB1 = wp + 28672;  _Float16* hyB2 = wp + 30720;

  int SB = (N + 1023) / 1024;  // scan blocks

  hipMemsetAsync(goalkey, 0, sizeof(u64), stream);
  hipMemsetAsync(deg, 0, (size_t)N * 4, stream);
  k_prep<<<17, 256, 0, stream>>>(fx_w1, fx_w2, fy_w1, fy_w2, hy_w1, hy_w2, wp);
  k_vch<<<(N * 16 + 255) / 256, 256, 0, stream>>>(v, labels, vcp, N, dst, E, deg);
  k_goal1<<<(N + 255) / 256, 256, 0, stream>>>(labels, N, goalkey);
  k_goal2<<<1, 64, 0, stream>>>(v, labels, goalkey, goal);
  k_scan1<<<SB, 256, 0, stream>>>(deg, N, bsum);
  k_scan2<<<1, 64, 0, stream>>>(bsum, SB, boff);
  k_scan3<<<SB, 256, 0, stream>>>(deg, boff, N, cursor);
  k_scatter<<<(E + 255) / 256, 256, 0, stream>>>(src, dst, E, cursor, srcp, dstp);

  k_hx<<<(N + 31) / 32, 256, 0, stream>>>(v, labels, goal, hx_w1, hx_b1, hx_w2, hx_b2, xa, N);
  k_hy<<<(E + 63) / 64, 256, 0, stream>>>(vcp, srcp, dstp,
                                          hyB1, hy_b1, hyB2, hy_b2, yh, yl, E);

  float* xc = xa;
  float* xo = xb;
  for (int t = 0; t < 3; ++t) {
    k_copy<<<(N * 16 + 255) / 256, 256, 0, stream>>>((const float4*)xc, (float4*)xo, N * 16);
    k_fx<<<(E + 127) / 128, 256, 0, stream>>>(xc, yh, srcp, dstp,
                                              fxB1, fx_b1, fxB2, fx_b2, xo, E);
    float* tmp = xc; xc = xo; xo = tmp;
    if (t < 2) {
      k_fy<<<(E + 127) / 128, 256, 0, stream>>>(xc, yh, yl, srcp, dstp,
                                                fyB1, fy_b1, fyB2, fy_b2, E);
    }
  }
  k_feta<<<(N + 31) / 32, 256, 0, stream>>>(xc, feta_w1, feta_b1, feta_w2, feta_b2, feta_w3,
                                            (float*)d_out, N);
}

// Round 8
// 457.862 us; speedup vs baseline: 5.3248x; 1.2343x over previous
//
#include <hip/hip_runtime.h>
#include <math.h>

typedef unsigned short u16;
typedef unsigned int u32;
typedef unsigned long long u64;
typedef __attribute__((ext_vector_type(8))) _Float16 f16x8;
typedef __attribute__((ext_vector_type(2))) _Float16 f16x2;
typedef __attribute__((ext_vector_type(4))) float f32x4;

union U8h { f16x8 v; f16x2 p[4]; u32 u[4]; _Float16 s[8]; };

#define GE 8  // nodes per wave for the VALU kernels

__device__ __forceinline__ float bcast(float v, int k) {
  return __int_as_float(__builtin_amdgcn_readlane(__float_as_int(v), k));
}

__device__ __forceinline__ void atomicMaxF(float* addr, float val) {
  if (val >= 0.0f) {
    atomicMax((int*)addr, __float_as_int(val));
  } else {
    atomicMin((unsigned int*)addr, (unsigned int)__float_as_int(val));
  }
}

__device__ __forceinline__ f16x2 pk(float a, float b) {
  return __builtin_bit_cast(f16x2, __builtin_amdgcn_cvt_pkrtz(a, b));
}

// split 8 fp32 -> fp16 hi (RTZ) + lo (residual): hi+lo exact to ~2^-22
__device__ __forceinline__ void dec8h(const float* f, U8h& h, U8h& l) {
#pragma unroll
  for (int i = 0; i < 4; ++i) {
    float a = f[2 * i], b = f[2 * i + 1];
    f16x2 hp = pk(a, b);
    float ra = a - (float)hp[0];
    float rb = b - (float)hp[1];
    h.p[i] = hp;
    l.p[i] = pk(ra, rb);
  }
}

// split with RNE hi — for hy's y storage (fx1 reads hi alone)
__device__ __forceinline__ void dec8h_rne(const float* f, U8h& h, U8h& l) {
#pragma unroll
  for (int i = 0; i < 8; ++i) {
    _Float16 hh = (_Float16)f[i];
    h.s[i] = hh;
    l.s[i] = (_Float16)(f[i] - (float)hh);
  }
}

// lane's two 8-float chunks of a 64-float row (cols q*8.. and 32+q*8..)
__device__ __forceinline__ void load_row(const float* p, float* f) {
  *(float4*)(f + 0)  = *(const float4*)(p);
  *(float4*)(f + 4)  = *(const float4*)(p + 4);
  *(float4*)(f + 8)  = *(const float4*)(p + 32);
  *(float4*)(f + 12) = *(const float4*)(p + 36);
}

// ---- cross-q segmented-run merge for dst-sorted scatter-max (atomic count ~/1.7) ----
struct RunCtx { bool chain1, chain2, chain3, suppress; };

__device__ __forceinline__ RunCtx run_ctx(const int dd[4], int lane, int q) {
  bool allsame = (dd[0] == dd[1]) && (dd[1] == dd[2]) && (dd[2] == dd[3]);
  int nfd1 = __shfl(dd[0], lane + 16, 64);
  int nfd2 = __shfl(dd[0], lane + 32, 64);
  int nfd3 = __shfl(dd[0], lane + 48, 64);
  int as = allsame ? 1 : 0;
  int nas1 = __shfl(as, lane + 16, 64);
  int nas2 = __shfl(as, lane + 32, 64);
  int pld = __shfl(dd[3], lane - 16, 64);
  RunCtx c;
  c.chain1 = (q < 3) && (nfd1 == dd[3]);
  c.chain2 = c.chain1 && (nas1 != 0) && (q < 2) && (nfd2 == dd[3]);
  c.chain3 = c.chain2 && (nas2 != 0) && (q < 1) && (nfd3 == dd[3]);
  c.suppress = (q > 0) && (pld == dd[0]);
  return c;
}

__device__ __forceinline__ void emit_t(const f32x4 o, const int dd[4], const RunCtx c,
                                       int lane, int m, int t, float* __restrict__ xnew) {
  // value of this lane's FIRST run (to be absorbed leftward)
  float fv = o[0];
  bool c01 = dd[1] == dd[0];
  fv = c01 ? fmaxf(fv, o[1]) : fv;
  bool c012 = c01 && (dd[2] == dd[1]);
  fv = c012 ? fmaxf(fv, o[2]) : fv;
  bool c0123 = c012 && (dd[3] == dd[2]);
  fv = c0123 ? fmaxf(fv, o[3]) : fv;
  float nfv1 = __shfl(fv, lane + 16, 64);
  float nfv2 = __shfl(fv, lane + 32, 64);
  float nfv3 = __shfl(fv, lane + 48, 64);
  float run = o[0];
  bool first = true;
#pragma unroll
  for (int r = 0; r < 4; ++r) {
    if (r > 0) run = (dd[r] == dd[r - 1]) ? fmaxf(run, o[r]) : o[r];
    bool end = (r == 3) || (dd[r + 1] != dd[r]);
    if (end) {
      float val = run;
      if (r == 3) {
        if (c.chain1) val = fmaxf(val, nfv1);
        if (c.chain2) val = fmaxf(val, nfv2);
        if (c.chain3) val = fmaxf(val, nfv3);
      }
      if (!(first && c.suppress) && dd[r] >= 0)
        atomicMaxF(&xnew[(size_t)dd[r] * 64 + t * 16 + m], val);
      first = false;
    }
  }
}

// ---------------- goal ----------------
__global__ __launch_bounds__(256) void k_goal1(const float* __restrict__ labels, int N,
                                               u64* __restrict__ key) {
  int i = blockIdx.x * 256 + threadIdx.x;
  float val = (i < N) ? labels[2 * (size_t)i + 1] : 0.0f;
  u64 k = ((u64)__float_as_uint(fmaxf(val, 0.0f)) << 32) | (u32)(~(u32)i);
#pragma unroll
  for (int off = 32; off > 0; off >>= 1) {
    u64 o = __shfl_xor(k, off, 64);
    if (o > k) k = o;
  }
  if ((threadIdx.x & 63) == 0) atomicMax(key, k);
}

__global__ void k_goal2(const float* __restrict__ v, const float* __restrict__ labels,
                        const u64* __restrict__ key, float* __restrict__ goal) {
  int g = (int)(~(u32)(*key));
  int c = threadIdx.x;
  if (c < 9) goal[c] = (c < 7) ? v[7 * (size_t)g + c] : labels[2 * (size_t)g + (c - 7)];
}

// ---------------- vcp build + degree histogram (fused) ----------------
__global__ __launch_bounds__(256) void k_vch(const float* __restrict__ v,
                                             const float* __restrict__ labels,
                                             float* __restrict__ vcp, int N,
                                             const int* __restrict__ dst, int E,
                                             int* __restrict__ deg) {
  int tid = blockIdx.x * 256 + threadIdx.x;
  if (tid < N * 16) {
    int n = tid >> 4, c = tid & 15;
    float val = 0.f;
    if (c < 7) val = v[(size_t)n * 7 + c];
    else if (c == 7) val = labels[2 * (size_t)n];
    else if (c == 8) val = labels[2 * (size_t)n + 1];
    vcp[tid] = val;
  }
  if (tid < E) atomicAdd(&deg[dst[tid]], 1);
}

// ---------------- weight prep ----------------
__global__ __launch_bounds__(256) void k_prep(const float* __restrict__ fxw1, const float* __restrict__ fxw2,
                                              const float* __restrict__ fyw1, const float* __restrict__ fyw2,
                                              const float* __restrict__ hyw1, const float* __restrict__ hyw2,
                                              _Float16* __restrict__ wp) {
  _Float16* fxB1 = wp;
  _Float16* fxB2 = wp + 12288;
  _Float16* fyB1 = wp + 16384;
  _Float16* fyB2 = wp + 24576;
  _Float16* hyB1 = wp + 28672;
  _Float16* hyB2 = wp + 30720;
  int tid = blockIdx.x * 256 + threadIdx.x;
  int which, id;
  _Float16* oh;
  if (tid < 1536)      { which = 0; id = tid;        oh = fxB1; }
  else if (tid < 2048) { which = 1; id = tid - 1536; oh = fxB2; }
  else if (tid < 3072) { which = 2; id = tid - 2048; oh = fyB1; }
  else if (tid < 3584) { which = 3; id = tid - 3072; oh = fyB2; }
  else if (tid < 3840) { which = 4; id = tid - 3584; oh = hyB1; }
  else if (tid < 4352) { which = 5; id = tid - 3840; oh = hyB2; }
  else return;
  int lane = id & 63;
  int q = lane >> 4, col = lane & 15;
  int c = id >> 8, t = (id >> 6) & 3;
#pragma unroll
  for (int j = 0; j < 8; ++j) {
    int k = c * 32 + q * 8 + j;
    int n = t * 16 + col;
    float w;
    if (which == 0) {
      w = (k < 64)  ? fxw1[k * 64 + n] + fxw1[(k + 64) * 64 + n]
        : (k < 128) ? fxw1[(k + 64) * 64 + n] - fxw1[(k - 64) * 64 + n]
                    : fxw1[(k + 64) * 64 + n];
    } else if (which == 1) {
      w = fxw2[k * 64 + n];
    } else if (which == 2) {
      w = (k < 64) ? fyw1[k * 64 + n] + fyw1[(k + 64) * 64 + n]
                   : fyw1[(k + 64) * 64 + n] - fyw1[(k - 64) * 64 + n];
    } else if (which == 3) {
      w = fyw2[k * 64 + n];
    } else if (which == 4) {
      if (k <= 8)                  w = hyw1[k * 64 + n] + hyw1[(k + 9) * 64 + n];
      else if (k >= 16 && k <= 24) w = hyw1[(k + 2) * 64 + n] - hyw1[(k - 16) * 64 + n];
      else                         w = 0.f;
    } else {
      w = hyw2[k * 64 + n];
    }
    oh[id * 8 + j] = (_Float16)w;
  }
}

// ---------------- CSR scan ----------------
__global__ __launch_bounds__(256) void k_scan1(const int* __restrict__ deg, int N,
                                               int* __restrict__ bsum) {
  __shared__ int red[256];
  int b = blockIdx.x;
  int s = 0;
  for (int i = threadIdx.x; i < 1024; i += 256) {
    int idx = b * 1024 + i;
    s += (idx < N) ? deg[idx] : 0;
  }
  red[threadIdx.x] = s; __syncthreads();
  for (int st = 128; st > 0; st >>= 1) {
    if (threadIdx.x < st) red[threadIdx.x] += red[threadIdx.x + st];
    __syncthreads();
  }
  if (threadIdx.x == 0) bsum[b] = red[0];
}

__global__ void k_scan2(const int* __restrict__ bsum, int B, int* __restrict__ boff) {
  if (threadIdx.x == 0) {
    int acc = 0;
    for (int i = 0; i < B; ++i) { boff[i] = acc; acc += bsum[i]; }
  }
}

__global__ __launch_bounds__(256) void k_scan3(const int* __restrict__ deg,
                                               const int* __restrict__ boff, int N,
                                               int* __restrict__ cursor) {
  __shared__ int lsum[256];
  int b = blockIdx.x;
  int tid = threadIdx.x;
  int base_i = b * 1024 + tid * 4;
  int loc[4]; int s = 0;
#pragma unroll
  for (int j = 0; j < 4; ++j) {
    int v = (base_i + j < N) ? deg[base_i + j] : 0;
    loc[j] = s; s += v;
  }
  lsum[tid] = s; __syncthreads();
  for (int st = 1; st < 256; st <<= 1) {
    int add = (tid >= st) ? lsum[tid - st] : 0;
    __syncthreads();
    lsum[tid] += add;
    __syncthreads();
  }
  int toff = boff[b] + lsum[tid] - s;
#pragma unroll
  for (int j = 0; j < 4; ++j) {
    if (base_i + j < N) cursor[base_i + j] = toff + loc[j];
  }
}

__global__ __launch_bounds__(256) void k_scatter(const int* __restrict__ src,
                                                 const int* __restrict__ dst, int E,
                                                 int* __restrict__ cursor,
                                                 int* __restrict__ srcp, int* __restrict__ dstp) {
  int e = blockIdx.x * 256 + threadIdx.x;
  if (e < E) {
    int d = dst[e];
    int pos = atomicAdd(&cursor[d], 1);
    srcp[pos] = src[e];
    dstp[pos] = d;
  }
}

// ---------------- hx (VALU) ----------------
__global__ __launch_bounds__(256) void k_hx(const float* __restrict__ v,
                                            const float* __restrict__ labels,
                                            const float* __restrict__ goal,
                                            const float* __restrict__ w1, const float* __restrict__ b1,
                                            const float* __restrict__ w2, const float* __restrict__ b2,
                                            float* __restrict__ xout, int N) {
  int lane = threadIdx.x & 63;
  int wid = (blockIdx.x * blockDim.x + threadIdx.x) >> 6;
  int base = wid * GE;
  int c = lane % 9;
  float f[GE];
#pragma unroll
  for (int e = 0; e < GE; ++e) {
    int i = base + e; if (i >= N) i = N - 1;
    float fv = 0.f;
    if (lane < 36) {
      float vcv = (c < 7) ? v[7 * i + c] : labels[2 * i + (c - 7)];
      float gl = goal[c];
      float d = vcv - gl;
      fv = (lane < 9) ? vcv : (lane < 18) ? gl : (lane < 27) ? d : d * d;
    }
    f[e] = fv;
  }
  float acc[GE];
  float bb = b1[lane];
#pragma unroll
  for (int e = 0; e < GE; ++e) acc[e] = bb;
  for (int k = 0; k < 36; ++k) {
    float w = w1[k * 64 + lane];
#pragma unroll
    for (int e = 0; e < GE; ++e) acc[e] = fmaf(bcast(f[e], k), w, acc[e]);
  }
  float h[GE];
#pragma unroll
  for (int e = 0; e < GE; ++e) h[e] = fmaxf(acc[e], 0.f);
  float b2v = b2[lane];
#pragma unroll
  for (int e = 0; e < GE; ++e) acc[e] = b2v;
#pragma unroll 4
  for (int k = 0; k < 64; ++k) {
    float w = w2[k * 64 + lane];
#pragma unroll
    for (int e = 0; e < GE; ++e) acc[e] = fmaf(bcast(h[e], k), w, acc[e]);
  }
#pragma unroll
  for (int e = 0; e < GE; ++e) {
    int i = base + e;
    if (i < N) xout[(size_t)i * 64 + lane] = acc[e];
  }
}

// ---------------- hy (MFMA fp16) ----------------
__global__ __launch_bounds__(256) void k_hy(
    const float* __restrict__ vcp,
    const int* __restrict__ src, const int* __restrict__ dst,
    const _Float16* __restrict__ B1, const float* __restrict__ b1,
    const _Float16* __restrict__ B2, const float* __restrict__ b2,
    _Float16* __restrict__ yh, _Float16* __restrict__ yl, int E) {
  __shared__ float hbuf[4][2][16 * 68];
  const int lane = threadIdx.x & 63;
  const int wv = threadIdx.x >> 6;
  const int m = lane & 15, q = lane >> 4;
  const int base = blockIdx.x * 64 + wv * 16;
  int em = base + m; if (em >= E) em = E - 1;
  const int node = (q < 2) ? dst[em] : src[em];
  const float* p = vcp + (size_t)node * 16 + (q & 1) * 8;
  float f[8];
  *(float4*)(f + 0) = *(const float4*)(p);
  *(float4*)(f + 4) = *(const float4*)(p + 4);
  U8h Ah, Al;
  dec8h(f, Ah, Al);

  f32x4 acc[4];
#pragma unroll
  for (int t = 0; t < 4; ++t) { float bv = b1[t * 16 + m]; acc[t] = (f32x4){bv, bv, bv, bv}; }
#pragma unroll
  for (int t = 0; t < 4; ++t) {
    f16x8 b = *(const f16x8*)(B1 + ((size_t)t * 64 + lane) * 8);
    acc[t] = __builtin_amdgcn_mfma_f32_16x16x32_f16(Ah.v, b, acc[t], 0, 0, 0);
    acc[t] = __builtin_amdgcn_mfma_f32_16x16x32_f16(Al.v, b, acc[t], 0, 0, 0);
  }

  float* hb = hbuf[wv][0];
#pragma unroll
  for (int t = 0; t < 4; ++t)
#pragma unroll
    for (int r = 0; r < 4; ++r)
      hb[(q * 4 + r) * 68 + t * 16 + m] = fmaxf(acc[t][r], 0.f);

  float fh[16];
  load_row(hb + m * 68 + q * 8, fh);
  U8h A2h[2], A2l[2];
  dec8h(fh + 0, A2h[0], A2l[0]);
  dec8h(fh + 8, A2h[1], A2l[1]);

  f32x4 acc2[4];
#pragma unroll
  for (int t = 0; t < 4; ++t) { float bv = b2[t * 16 + m]; acc2[t] = (f32x4){bv, bv, bv, bv}; }
#pragma unroll
  for (int c = 0; c < 2; ++c) {
#pragma unroll
    for (int t = 0; t < 4; ++t) {
      f16x8 b = *(const f16x8*)(B2 + ((size_t)(c * 4 + t) * 64 + lane) * 8);
      acc2[t] = __builtin_amdgcn_mfma_f32_16x16x32_f16(A2h[c].v, b, acc2[t], 0, 0, 0);
      acc2[t] = __builtin_amdgcn_mfma_f32_16x16x32_f16(A2l[c].v, b, acc2[t], 0, 0, 0);
    }
  }

  float* ob = hbuf[wv][1];
#pragma unroll
  for (int t = 0; t < 4; ++t)
#pragma unroll
    for (int r = 0; r < 4; ++r)
      ob[(q * 4 + r) * 68 + t * 16 + m] = acc2[t][r];

  int row = base + m;
  if (row < E) {
    float ov[16];
    const float* orow = ob + m * 68 + q * 16;
    *(float4*)(ov + 0)  = *(const float4*)(orow);
    *(float4*)(ov + 4)  = *(const float4*)(orow + 4);
    *(float4*)(ov + 8)  = *(const float4*)(orow + 8);
    *(float4*)(ov + 12) = *(const float4*)(orow + 12);
    size_t yo = (size_t)row * 64 + q * 16;
    U8h H0, H1, L0, L1;
    dec8h_rne(ov + 0, H0, L0);
    dec8h_rne(ov + 8, H1, L1);
    *(f16x8*)(yh + yo)     = H0.v;
    *(f16x8*)(yh + yo + 8) = H1.v;
    *(f16x8*)(yl + yo)     = L0.v;
    *(f16x8*)(yl + yo + 8) = L1.v;
  }
}

// ---------------- fx standalone (t=0): 1-tile MFMA fp16, yh only, merged atomics ----------
__global__ __launch_bounds__(256) void k_fx(
    const float* __restrict__ x, const _Float16* __restrict__ yh,
    const int* __restrict__ src, const int* __restrict__ dst,
    const _Float16* __restrict__ B1, const float* __restrict__ b1,
    const _Float16* __restrict__ B2, const float* __restrict__ b2,
    float* __restrict__ xnew, int E) {
  __shared__ float hbuf[4][16 * 68];
  const int lane = threadIdx.x & 63;
  const int wv = threadIdx.x >> 6;
  const int m = lane & 15, q = lane >> 4;
  const int base = blockIdx.x * 64 + wv * 16;
  int em = base + m; if (em >= E) em = E - 1;
  const int si = src[em], di = dst[em];

  float fs[16], fd[16];
  load_row(x + (size_t)si * 64 + q * 8, fs);
  load_row(x + (size_t)di * 64 + q * 8, fd);
  U8h Y[2];
  {
    const _Float16* p0 = yh + (size_t)em * 64 + q * 8;
    Y[0].v = *(const f16x8*)(p0);  Y[1].v = *(const f16x8*)(p0 + 32);
  }

  U8h Ah[4], Al[4];
  dec8h(fs + 0, Ah[0], Al[0]);
  dec8h(fs + 8, Ah[1], Al[1]);
  dec8h(fd + 0, Ah[2], Al[2]);
  dec8h(fd + 8, Ah[3], Al[3]);

  f32x4 acc[4];
#pragma unroll
  for (int t = 0; t < 4; ++t) { float bv = b1[t * 16 + m]; acc[t] = (f32x4){bv, bv, bv, bv}; }
#pragma unroll
  for (int c = 0; c < 4; ++c) {
#pragma unroll
    for (int t = 0; t < 4; ++t) {
      f16x8 b = *(const f16x8*)(B1 + ((size_t)(c * 4 + t) * 64 + lane) * 8);
      acc[t] = __builtin_amdgcn_mfma_f32_16x16x32_f16(Ah[c].v, b, acc[t], 0, 0, 0);
      acc[t] = __builtin_amdgcn_mfma_f32_16x16x32_f16(Al[c].v, b, acc[t], 0, 0, 0);
    }
  }
#pragma unroll
  for (int c = 4; c < 6; ++c) {
#pragma unroll
    for (int t = 0; t < 4; ++t) {
      f16x8 b = *(const f16x8*)(B1 + ((size_t)(c * 4 + t) * 64 + lane) * 8);
      acc[t] = __builtin_amdgcn_mfma_f32_16x16x32_f16(Y[c - 4].v, b, acc[t], 0, 0, 0);
    }
  }

  float* hb = hbuf[wv];
#pragma unroll
  for (int t = 0; t < 4; ++t)
#pragma unroll
    for (int r = 0; r < 4; ++r)
      hb[(q * 4 + r) * 68 + t * 16 + m] = fmaxf(acc[t][r], 0.f);

  float fh[16];
  load_row(hb + m * 68 + q * 8, fh);
  U8h A2h[2], A2l[2];
  dec8h(fh + 0, A2h[0], A2l[0]);
  dec8h(fh + 8, A2h[1], A2l[1]);

  f32x4 o[4];
#pragma unroll
  for (int t = 0; t < 4; ++t) { float bv = b2[t * 16 + m]; o[t] = (f32x4){bv, bv, bv, bv}; }
#pragma unroll
  for (int c = 0; c < 2; ++c) {
#pragma unroll
    for (int t = 0; t < 4; ++t) {
      f16x8 b = *(const f16x8*)(B2 + ((size_t)(c * 4 + t) * 64 + lane) * 8);
      o[t] = __builtin_amdgcn_mfma_f32_16x16x32_f16(A2h[c].v, b, o[t], 0, 0, 0);
      o[t] = __builtin_amdgcn_mfma_f32_16x16x32_f16(A2l[c].v, b, o[t], 0, 0, 0);
    }
  }

  int dd[4];
  int e0 = base + q * 4;
#pragma unroll
  for (int r = 0; r < 4; ++r) {
    int e2 = e0 + r;
    dd[r] = (e2 < E) ? dst[e2] : -1;
  }
  RunCtx c = run_ctx(dd, lane, q);
#pragma unroll
  for (int t = 0; t < 4; ++t) emit_t(o[t], dd, c, lane, m, t, xnew);
}

// ---------------- fused: fy (updates y with x) then fx (same x, fresh y) ----------
__global__ __launch_bounds__(256) void k_fyfx(
    const float* __restrict__ x, _Float16* __restrict__ yh, _Float16* __restrict__ yl,
    const int* __restrict__ src, const int* __restrict__ dst,
    const _Float16* __restrict__ yB1, const float* __restrict__ yb1,
    const _Float16* __restrict__ yB2, const float* __restrict__ yb2,
    const _Float16* __restrict__ xB1, const float* __restrict__ xb1,
    const _Float16* __restrict__ xB2, const float* __restrict__ xb2,
    float* __restrict__ xnew, int E) {
  __shared__ float hbuf[4][16 * 68];  // wave-private, sequentially reused
  const int lane = threadIdx.x & 63;
  const int wv = threadIdx.x >> 6;
  const int m = lane & 15, q = lane >> 4;
  const int base = blockIdx.x * 64 + wv * 16;
  int em = base + m; if (em >= E) em = E - 1;
  const int si = src[em], di = dst[em];
  const int row = base + m;
  const bool live = row < E;

  // gathers (x rows shared by fy and fx) + old y (A-fragment col split: q*8, 32+q*8)
  float fs[16], fd[16];
  load_row(x + (size_t)si * 64 + q * 8, fs);
  load_row(x + (size_t)di * 64 + q * 8, fd);
  U8h Ho[2], Lo[2];
  {
    size_t yo = (size_t)em * 64 + q * 8;
    Ho[0].v = *(const f16x8*)(yh + yo);  Ho[1].v = *(const f16x8*)(yh + yo + 32);
    Lo[0].v = *(const f16x8*)(yl + yo);  Lo[1].v = *(const f16x8*)(yl + yo + 32);
  }

  U8h Ah[4], Al[4];             // [0,1]=xd  [2,3]=xs  (fy chunk order)
  dec8h(fd + 0, Ah[0], Al[0]);
  dec8h(fd + 8, Ah[1], Al[1]);
  dec8h(fs + 0, Ah[2], Al[2]);
  dec8h(fs + 8, Ah[3], Al[3]);

  // ---- fy layer 1 ----
  f32x4 acc[4];
#pragma unroll
  for (int t = 0; t < 4; ++t) { float bv = yb1[t * 16 + m]; acc[t] = (f32x4){bv, bv, bv, bv}; }
#pragma unroll
  for (int c = 0; c < 4; ++c) {
#pragma unroll
    for (int t = 0; t < 4; ++t) {
      f16x8 b = *(const f16x8*)(yB1 + ((size_t)(c * 4 + t) * 64 + lane) * 8);
      acc[t] = __builtin_amdgcn_mfma_f32_16x16x32_f16(Ah[c].v, b, acc[t], 0, 0, 0);
      acc[t] = __builtin_amdgcn_mfma_f32_16x16x32_f16(Al[c].v, b, acc[t], 0, 0, 0);
    }
  }

  float* hb = hbuf[wv];
#pragma unroll
  for (int t = 0; t < 4; ++t)
#pragma unroll
    for (int r = 0; r < 4; ++r)
      hb[(q * 4 + r) * 68 + t * 16 + m] = fmaxf(acc[t][r], 0.f);

  float fh[16];
  load_row(hb + m * 68 + q * 8, fh);
  U8h A2h[2], A2l[2];
  dec8h(fh + 0, A2h[0], A2l[0]);
  dec8h(fh + 8, A2h[1], A2l[1]);

  // ---- fy layer 2 ----
  f32x4 o[4];
#pragma unroll
  for (int t = 0; t < 4; ++t) { float bv = yb2[t * 16 + m]; o[t] = (f32x4){bv, bv, bv, bv}; }
#pragma unroll
  for (int c = 0; c < 2; ++c) {
#pragma unroll
    for (int t = 0; t < 4; ++t) {
      f16x8 b = *(const f16x8*)(yB2 + ((size_t)(c * 4 + t) * 64 + lane) * 8);
      o[t] = __builtin_amdgcn_mfma_f32_16x16x32_f16(A2h[c].v, b, o[t], 0, 0, 0);
      o[t] = __builtin_amdgcn_mfma_f32_16x16x32_f16(A2l[c].v, b, o[t], 0, 0, 0);
    }
  }

  // transpose fy out, read back in A-fragment col split (q*8 / 32+q*8)
#pragma unroll
  for (int t = 0; t < 4; ++t)
#pragma unroll
    for (int r = 0; r < 4; ++r)
      hb[(q * 4 + r) * 68 + t * 16 + m] = o[t][r];

  float nv[16];
  load_row(hb + m * 68 + q * 8, nv);
  // nv = max(y_old, fy_out)  (per row em; cols q*8.. / 32+q*8..)
#pragma unroll
  for (int i = 0; i < 8; ++i) {
    nv[i]     = fmaxf((float)Ho[0].s[i] + (float)Lo[0].s[i], nv[i]);
    nv[8 + i] = fmaxf((float)Ho[1].s[i] + (float)Lo[1].s[i], nv[8 + i]);
  }
  // y fragments for fx (RTZ hi) + store new y (hi+lo)
  U8h Yh0, Yh1, Yl0, Yl1;
  dec8h(nv + 0, Yh0, Yl0);
  dec8h(nv + 8, Yh1, Yl1);
  if (live) {
    size_t yo = (size_t)row * 64 + q * 8;
    *(f16x8*)(yh + yo)      = Yh0.v;
    *(f16x8*)(yh + yo + 32) = Yh1.v;
    *(f16x8*)(yl + yo)      = Yl0.v;
    *(f16x8*)(yl + yo + 32) = Yl1.v;
  }

  // ---- fx layer 1: chunks [xs0,xs1,xd0,xd1,y0,y1] = Ah[2],Ah[3],Ah[0],Ah[1],Yh0,Yh1 ----
  f32x4 acc2[4];
#pragma unroll
  for (int t = 0; t < 4; ++t) { float bv = xb1[t * 16 + m]; acc2[t] = (f32x4){bv, bv, bv, bv}; }
  const int remap[4] = {2, 3, 0, 1};
#pragma unroll
  for (int c = 0; c < 4; ++c) {
    int a = remap[c];
#pragma unroll
    for (int t = 0; t < 4; ++t) {
      f16x8 b = *(const f16x8*)(xB1 + ((size_t)(c * 4 + t) * 64 + lane) * 8);
      acc2[t] = __builtin_amdgcn_mfma_f32_16x16x32_f16(Ah[a].v, b, acc2[t], 0, 0, 0);
      acc2[t] = __builtin_amdgcn_mfma_f32_16x16x32_f16(Al[a].v, b, acc2[t], 0, 0, 0);
    }
  }
#pragma unroll
  for (int t = 0; t < 4; ++t) {
    f16x8 b4 = *(const f16x8*)(xB1 + ((size_t)(4 * 4 + t) * 64 + lane) * 8);
    f16x8 b5 = *(const f16x8*)(xB1 + ((size_t)(5 * 4 + t) * 64 + lane) * 8);
    acc2[t] = __builtin_amdgcn_mfma_f32_16x16x32_f16(Yh0.v, b4, acc2[t], 0, 0, 0);
    acc2[t] = __builtin_amdgcn_mfma_f32_16x16x32_f16(Yh1.v, b5, acc2[t], 0, 0, 0);
  }

#pragma unroll
  for (int t = 0; t < 4; ++t)
#pragma unroll
    for (int r = 0; r < 4; ++r)
      hb[(q * 4 + r) * 68 + t * 16 + m] = fmaxf(acc2[t][r], 0.f);

  float fh2[16];
  load_row(hb + m * 68 + q * 8, fh2);
  U8h B2h[2], B2l[2];
  dec8h(fh2 + 0, B2h[0], B2l[0]);
  dec8h(fh2 + 8, B2h[1], B2l[1]);

  f32x4 o2[4];
#pragma unroll
  for (int t = 0; t < 4; ++t) { float bv = xb2[t * 16 + m]; o2[t] = (f32x4){bv, bv, bv, bv}; }
#pragma unroll
  for (int c = 0; c < 2; ++c) {
#pragma unroll
    for (int t = 0; t < 4; ++t) {
      f16x8 b = *(const f16x8*)(xB2 + ((size_t)(c * 4 + t) * 64 + lane) * 8);
      o2[t] = __builtin_amdgcn_mfma_f32_16x16x32_f16(B2h[c].v, b, o2[t], 0, 0, 0);
      o2[t] = __builtin_amdgcn_mfma_f32_16x16x32_f16(B2l[c].v, b, o2[t], 0, 0, 0);
    }
  }

  int dd[4];
  int e0 = base + q * 4;
#pragma unroll
  for (int r = 0; r < 4; ++r) {
    int e2 = e0 + r;
    dd[r] = (e2 < E) ? dst[e2] : -1;
  }
  RunCtx rc = run_ctx(dd, lane, q);
#pragma unroll
  for (int t = 0; t < 4; ++t) emit_t(o2[t], dd, rc, lane, m, t, xnew);
}

// ---------------- feta (VALU) ----------------
__global__ __launch_bounds__(256) void k_feta(const float* __restrict__ x,
                                              const float* __restrict__ w1, const float* __restrict__ b1,
                                              const float* __restrict__ w2, const float* __restrict__ b2,
                                              const float* __restrict__ w3,
                                              float* __restrict__ out, int N) {
  int lane = threadIdx.x & 63;
  int wid = (blockIdx.x * blockDim.x + threadIdx.x) >> 6;
  int base = wid * GE;
  float xr[GE];
#pragma unroll
  for (int e = 0; e < GE; ++e) {
    int i = base + e; if (i >= N) i = N - 1;
    xr[e] = x[(size_t)i * 64 + lane];
  }
  float acc[GE];
  float bb = b1[lane];
#pragma unroll
  for (int e = 0; e < GE; ++e) acc[e] = bb;
#pragma unroll 4
  for (int k = 0; k < 64; ++k) {
    float w = w1[k * 64 + lane];
#pragma unroll
    for (int e = 0; e < GE; ++e) acc[e] = fmaf(bcast(xr[e], k), w, acc[e]);
  }
  float h1[GE];
#pragma unroll
  for (int e = 0; e < GE; ++e) h1[e] = fmaxf(acc[e], 0.f);
  float b2v = b2[lane];
#pragma unroll
  for (int e = 0; e < GE; ++e) acc[e] = b2v;
#pragma unroll 4
  for (int k = 0; k < 64; ++k) {
    float w = w2[k * 64 + lane];
#pragma unroll
    for (int e = 0; e < GE; ++e) acc[e] = fmaf(bcast(h1[e], k), w, acc[e]);
  }
  float w3l = w3[lane];
#pragma unroll
  for (int e = 0; e < GE; ++e) {
    float r = fmaxf(acc[e], 0.f) * w3l;
    for (int off = 32; off > 0; off >>= 1) r += __shfl_xor(r, off, 64);
    int i = base + e;
    if (lane == 0 && i < N) out[i] = r;
  }
}

__global__ __launch_bounds__(256) void k_copy(const float4* __restrict__ s,
                                              float4* __restrict__ d, int n4) {
  int i = blockIdx.x * 256 + threadIdx.x;
  if (i < n4) d[i] = s[i];
}

extern "C" void kernel_launch(void* const* d_in, const int* in_sizes, int n_in,
                              void* d_out, int out_size, void* d_ws, size_t ws_size,
                              hipStream_t stream) {
  const float* v      = (const float*)d_in[0];
  const float* labels = (const float*)d_in[1];
  const int*   ei     = (const int*)d_in[2];
  const float* hx_w1 = (const float*)d_in[4];
  const float* hx_b1 = (const float*)d_in[5];
  const float* hx_w2 = (const float*)d_in[6];
  const float* hx_b2 = (const float*)d_in[7];
  const float* hy_w1 = (const float*)d_in[8];
  const float* hy_b1 = (const float*)d_in[9];
  const float* hy_w2 = (const float*)d_in[10];
  const float* hy_b2 = (const float*)d_in[11];
  const float* fx_w1 = (const float*)d_in[12];
  const float* fx_b1 = (const float*)d_in[13];
  const float* fx_w2 = (const float*)d_in[14];
  const float* fx_b2 = (const float*)d_in[15];
  const float* fy_w1 = (const float*)d_in[16];
  const float* fy_b1 = (const float*)d_in[17];
  const float* fy_w2 = (const float*)d_in[18];
  const float* fy_b2 = (const float*)d_in[19];
  const float* feta_w1 = (const float*)d_in[20];
  const float* feta_b1 = (const float*)d_in[21];
  const float* feta_w2 = (const float*)d_in[22];
  const float* feta_b2 = (const float*)d_in[23];
  const float* feta_w3 = (const float*)d_in[24];

  int N = in_sizes[0] / 7;
  int E = in_sizes[2] / 2;
  const int* src = ei;
  const int* dst = ei + E;

  char* wsb = (char*)d_ws;
  float* goal = (float*)wsb;
  u64* goalkey = (u64*)(wsb + 16 * 4);
  float* xa = (float*)(wsb + 32 * 4);                            // N*64 f
  float* xb = xa + (size_t)N * 64;                               // N*64 f
  _Float16* yh = (_Float16*)(xb + (size_t)N * 64);               // E*64 f16
  _Float16* yl = yh + (size_t)E * 64;                            // E*64 f16
  _Float16* wp = yl + (size_t)E * 64;                            // 34816 f16
  float* vcp = (float*)(wp + 34816);                             // N*16 f
  int* deg = (int*)(vcp + (size_t)N * 16);                       // N
  int* cursor = deg + N;                                         // N
  int* srcp = cursor + N;                                        // E
  int* dstp = srcp + E;                                          // E
  int* bsum = dstp + E;                                          // 64
  int* boff = bsum + 64;                                         // 64

  _Float16* fxB1 = wp;          _Float16* fxB2 = wp + 12288;
  _Float16* fyB1 = wp + 16384;  _Float16* fyB2 = wp + 24576;
  _Float16* hyB1 = wp + 28672;  _Float16* hyB2 = wp + 30720;

  int SB = (N + 1023) / 1024;

  hipMemsetAsync(goalkey, 0, sizeof(u64), stream);
  hipMemsetAsync(deg, 0, (size_t)N * 4, stream);
  k_prep<<<17, 256, 0, stream>>>(fx_w1, fx_w2, fy_w1, fy_w2, hy_w1, hy_w2, wp);
  k_vch<<<(N * 16 + 255) / 256, 256, 0, stream>>>(v, labels, vcp, N, dst, E, deg);
  k_goal1<<<(N + 255) / 256, 256, 0, stream>>>(labels, N, goalkey);
  k_goal2<<<1, 64, 0, stream>>>(v, labels, goalkey, goal);
  k_scan1<<<SB, 256, 0, stream>>>(deg, N, bsum);
  k_scan2<<<1, 64, 0, stream>>>(bsum, SB, boff);
  k_scan3<<<SB, 256, 0, stream>>>(deg, boff, N, cursor);
  k_scatter<<<(E + 255) / 256, 256, 0, stream>>>(src, dst, E, cursor, srcp, dstp);

  k_hx<<<(N + 31) / 32, 256, 0, stream>>>(v, labels, goal, hx_w1, hx_b1, hx_w2, hx_b2, xa, N);
  k_hy<<<(E + 63) / 64, 256, 0, stream>>>(vcp, srcp, dstp,
                                          hyB1, hy_b1, hyB2, hy_b2, yh, yl, E);

  int EB = (E + 63) / 64;
  // t=0: x2 = max-agg(fx(x1)) into copy of x1
  k_copy<<<(N * 16 + 255) / 256, 256, 0, stream>>>((const float4*)xa, (float4*)xb, N * 16);
  k_fx<<<EB, 256, 0, stream>>>(xa, yh, srcp, dstp, fxB1, fx_b1, fxB2, fx_b2, xb, E);
  // t=1: fy(x2) updates y; fx(x2, y_new) -> x3 (into copy of x2)
  k_copy<<<(N * 16 + 255) / 256, 256, 0, stream>>>((const float4*)xb, (float4*)xa, N * 16);
  k_fyfx<<<EB, 256, 0, stream>>>(xb, yh, yl, srcp, dstp,
                                 fyB1, fy_b1, fyB2, fy_b2,
                                 fxB1, fx_b1, fxB2, fx_b2, xa, E);
  // t=2: fy(x3) updates y; fx(x3, y_new) -> x4
  k_copy<<<(N * 16 + 255) / 256, 256, 0, stream>>>((const float4*)xa, (float4*)xb, N * 16);
  k_fyfx<<<EB, 256, 0, stream>>>(xa, yh, yl, srcp, dstp,
                                 fyB1, fy_b1, fyB2, fy_b2,
                                 fxB1, fx_b1, fxB2, fx_b2, xb, E);

  k_feta<<<(N + 31) / 32, 256, 0, stream>>>(xb, feta_w1, feta_b1, feta_w2, feta_b2, feta_w3,
                                            (float*)d_out, N);
}

// Round 9
// 432.469 us; speedup vs baseline: 5.6375x; 1.0587x over previous
//
#include <hip/hip_runtime.h>
#include <math.h>

typedef unsigned short u16;
typedef unsigned int u32;
typedef unsigned long long u64;
typedef __attribute__((ext_vector_type(8))) _Float16 f16x8;
typedef __attribute__((ext_vector_type(2))) _Float16 f16x2;
typedef __attribute__((ext_vector_type(4))) float f32x4;

union U8h { f16x8 v; f16x2 p[4]; u32 u[4]; _Float16 s[8]; };

#define GE 8

__device__ __forceinline__ float bcast(float v, int k) {
  return __int_as_float(__builtin_amdgcn_readlane(__float_as_int(v), k));
}

__device__ __forceinline__ void atomicMaxF(float* addr, float val) {
  if (val >= 0.0f) {
    atomicMax((int*)addr, __float_as_int(val));
  } else {
    atomicMin((unsigned int*)addr, (unsigned int)__float_as_int(val));
  }
}

__device__ __forceinline__ f16x2 pk(float a, float b) {
  return __builtin_bit_cast(f16x2, __builtin_amdgcn_cvt_pkrtz(a, b));
}

// split 8 fp32 -> fp16 hi (RTZ) + lo (residual): hi+lo exact to ~2^-22
__device__ __forceinline__ void dec8h(const float* f, U8h& h, U8h& l) {
#pragma unroll
  for (int i = 0; i < 4; ++i) {
    float a = f[2 * i], b = f[2 * i + 1];
    f16x2 hp = pk(a, b);
    float ra = a - (float)hp[0];
    float rb = b - (float)hp[1];
    h.p[i] = hp;
    l.p[i] = pk(ra, rb);
  }
}

// 8 fp32 -> fp16 RNE (single)
__device__ __forceinline__ void conv8_rne(const float* f, U8h& h) {
#pragma unroll
  for (int i = 0; i < 8; ++i) h.s[i] = (_Float16)f[i];
}

// lane's two 8-float chunks of a 64-float row (cols q*8.. and 32+q*8..)
__device__ __forceinline__ void load_row(const float* p, float* f) {
  *(float4*)(f + 0)  = *(const float4*)(p);
  *(float4*)(f + 4)  = *(const float4*)(p + 4);
  *(float4*)(f + 8)  = *(const float4*)(p + 32);
  *(float4*)(f + 12) = *(const float4*)(p + 36);
}

// ---- cross-q segmented-run merge for dst-sorted scatter-max ----
struct RunCtx { bool chain1, chain2, chain3, suppress; };

__device__ __forceinline__ RunCtx run_ctx(const int dd[4], int lane, int q) {
  bool allsame = (dd[0] == dd[1]) && (dd[1] == dd[2]) && (dd[2] == dd[3]);
  int nfd1 = __shfl(dd[0], lane + 16, 64);
  int nfd2 = __shfl(dd[0], lane + 32, 64);
  int nfd3 = __shfl(dd[0], lane + 48, 64);
  int as = allsame ? 1 : 0;
  int nas1 = __shfl(as, lane + 16, 64);
  int nas2 = __shfl(as, lane + 32, 64);
  int pld = __shfl(dd[3], lane - 16, 64);
  RunCtx c;
  c.chain1 = (q < 3) && (nfd1 == dd[3]);
  c.chain2 = c.chain1 && (nas1 != 0) && (q < 2) && (nfd2 == dd[3]);
  c.chain3 = c.chain2 && (nas2 != 0) && (q < 1) && (nfd3 == dd[3]);
  c.suppress = (q > 0) && (pld == dd[0]);
  return c;
}

__device__ __forceinline__ void emit_t(const f32x4 o, const int dd[4], const RunCtx c,
                                       int lane, int m, int t, float* __restrict__ xnew) {
  float fv = o[0];
  bool c01 = dd[1] == dd[0];
  fv = c01 ? fmaxf(fv, o[1]) : fv;
  bool c012 = c01 && (dd[2] == dd[1]);
  fv = c012 ? fmaxf(fv, o[2]) : fv;
  bool c0123 = c012 && (dd[3] == dd[2]);
  fv = c0123 ? fmaxf(fv, o[3]) : fv;
  float nfv1 = __shfl(fv, lane + 16, 64);
  float nfv2 = __shfl(fv, lane + 32, 64);
  float nfv3 = __shfl(fv, lane + 48, 64);
  float run = o[0];
  bool first = true;
#pragma unroll
  for (int r = 0; r < 4; ++r) {
    if (r > 0) run = (dd[r] == dd[r - 1]) ? fmaxf(run, o[r]) : o[r];
    bool end = (r == 3) || (dd[r + 1] != dd[r]);
    if (end) {
      float val = run;
      if (r == 3) {
        if (c.chain1) val = fmaxf(val, nfv1);
        if (c.chain2) val = fmaxf(val, nfv2);
        if (c.chain3) val = fmaxf(val, nfv3);
      }
      if (!(first && c.suppress) && dd[r] >= 0)
        atomicMaxF(&xnew[(size_t)dd[r] * 64 + t * 16 + m], val);
      first = false;
    }
  }
}

// ---------------- goal ----------------
__global__ __launch_bounds__(256) void k_goal1(const float* __restrict__ labels, int N,
                                               u64* __restrict__ key) {
  int i = blockIdx.x * 256 + threadIdx.x;
  float val = (i < N) ? labels[2 * (size_t)i + 1] : 0.0f;
  u64 k = ((u64)__float_as_uint(fmaxf(val, 0.0f)) << 32) | (u32)(~(u32)i);
#pragma unroll
  for (int off = 32; off > 0; off >>= 1) {
    u64 o = __shfl_xor(k, off, 64);
    if (o > k) k = o;
  }
  if ((threadIdx.x & 63) == 0) atomicMax(key, k);
}

__global__ void k_goal2(const float* __restrict__ v, const float* __restrict__ labels,
                        const u64* __restrict__ key, float* __restrict__ goal) {
  int g = (int)(~(u32)(*key));
  int c = threadIdx.x;
  if (c < 9) goal[c] = (c < 7) ? v[7 * (size_t)g + c] : labels[2 * (size_t)g + (c - 7)];
}

// ---------------- vcp build + degree histogram ----------------
__global__ __launch_bounds__(256) void k_vch(const float* __restrict__ v,
                                             const float* __restrict__ labels,
                                             float* __restrict__ vcp, int N,
                                             const int* __restrict__ dst, int E,
                                             int* __restrict__ deg) {
  int tid = blockIdx.x * 256 + threadIdx.x;
  if (tid < N * 16) {
    int n = tid >> 4, c = tid & 15;
    float val = 0.f;
    if (c < 7) val = v[(size_t)n * 7 + c];
    else if (c == 7) val = labels[2 * (size_t)n];
    else if (c == 8) val = labels[2 * (size_t)n + 1];
    vcp[tid] = val;
  }
  if (tid < E) atomicAdd(&deg[dst[tid]], 1);
}

// ---------------- weight prep ----------------
__global__ __launch_bounds__(256) void k_prep(const float* __restrict__ fxw1, const float* __restrict__ fxw2,
                                              const float* __restrict__ fyw1, const float* __restrict__ fyw2,
                                              const float* __restrict__ hyw1, const float* __restrict__ hyw2,
                                              _Float16* __restrict__ wp) {
  _Float16* fxB1 = wp;
  _Float16* fxB2 = wp + 12288;
  _Float16* fyB1 = wp + 16384;
  _Float16* fyB2 = wp + 24576;
  _Float16* hyB1 = wp + 28672;
  _Float16* hyB2 = wp + 30720;
  int tid = blockIdx.x * 256 + threadIdx.x;
  int which, id;
  _Float16* oh;
  if (tid < 1536)      { which = 0; id = tid;        oh = fxB1; }
  else if (tid < 2048) { which = 1; id = tid - 1536; oh = fxB2; }
  else if (tid < 3072) { which = 2; id = tid - 2048; oh = fyB1; }
  else if (tid < 3584) { which = 3; id = tid - 3072; oh = fyB2; }
  else if (tid < 3840) { which = 4; id = tid - 3584; oh = hyB1; }
  else if (tid < 4352) { which = 5; id = tid - 3840; oh = hyB2; }
  else return;
  int lane = id & 63;
  int q = lane >> 4, col = lane & 15;
  int c = id >> 8, t = (id >> 6) & 3;
#pragma unroll
  for (int j = 0; j < 8; ++j) {
    int k = c * 32 + q * 8 + j;
    int n = t * 16 + col;
    float w;
    if (which == 0) {
      w = (k < 64)  ? fxw1[k * 64 + n] + fxw1[(k + 64) * 64 + n]
        : (k < 128) ? fxw1[(k + 64) * 64 + n] - fxw1[(k - 64) * 64 + n]
                    : fxw1[(k + 64) * 64 + n];
    } else if (which == 1) {
      w = fxw2[k * 64 + n];
    } else if (which == 2) {
      w = (k < 64) ? fyw1[k * 64 + n] + fyw1[(k + 64) * 64 + n]
                   : fyw1[(k + 64) * 64 + n] - fyw1[(k - 64) * 64 + n];
    } else if (which == 3) {
      w = fyw2[k * 64 + n];
    } else if (which == 4) {
      if (k <= 8)                  w = hyw1[k * 64 + n] + hyw1[(k + 9) * 64 + n];
      else if (k >= 16 && k <= 24) w = hyw1[(k + 2) * 64 + n] - hyw1[(k - 16) * 64 + n];
      else                         w = 0.f;
    } else {
      w = hyw2[k * 64 + n];
    }
    oh[id * 8 + j] = (_Float16)w;
  }
}

// ---------------- CSR scan ----------------
__global__ __launch_bounds__(256) void k_scan1(const int* __restrict__ deg, int N,
                                               int* __restrict__ bsum) {
  __shared__ int red[256];
  int b = blockIdx.x;
  int s = 0;
  for (int i = threadIdx.x; i < 1024; i += 256) {
    int idx = b * 1024 + i;
    s += (idx < N) ? deg[idx] : 0;
  }
  red[threadIdx.x] = s; __syncthreads();
  for (int st = 128; st > 0; st >>= 1) {
    if (threadIdx.x < st) red[threadIdx.x] += red[threadIdx.x + st];
    __syncthreads();
  }
  if (threadIdx.x == 0) bsum[b] = red[0];
}

__global__ void k_scan2(const int* __restrict__ bsum, int B, int* __restrict__ boff) {
  if (threadIdx.x == 0) {
    int acc = 0;
    for (int i = 0; i < B; ++i) { boff[i] = acc; acc += bsum[i]; }
  }
}

__global__ __launch_bounds__(256) void k_scan3(const int* __restrict__ deg,
                                               const int* __restrict__ boff, int N,
                                               int* __restrict__ cursor) {
  __shared__ int lsum[256];
  int b = blockIdx.x;
  int tid = threadIdx.x;
  int base_i = b * 1024 + tid * 4;
  int loc[4]; int s = 0;
#pragma unroll
  for (int j = 0; j < 4; ++j) {
    int v = (base_i + j < N) ? deg[base_i + j] : 0;
    loc[j] = s; s += v;
  }
  lsum[tid] = s; __syncthreads();
  for (int st = 1; st < 256; st <<= 1) {
    int add = (tid >= st) ? lsum[tid - st] : 0;
    __syncthreads();
    lsum[tid] += add;
    __syncthreads();
  }
  int toff = boff[b] + lsum[tid] - s;
#pragma unroll
  for (int j = 0; j < 4; ++j) {
    if (base_i + j < N) cursor[base_i + j] = toff + loc[j];
  }
}

__global__ __launch_bounds__(256) void k_scatter(const int* __restrict__ src,
                                                 const int* __restrict__ dst, int E,
                                                 int* __restrict__ cursor,
                                                 int* __restrict__ srcp, int* __restrict__ dstp) {
  int e = blockIdx.x * 256 + threadIdx.x;
  if (e < E) {
    int d = dst[e];
    int pos = atomicAdd(&cursor[d], 1);
    srcp[pos] = src[e];
    dstp[pos] = d;
  }
}

// ---------------- hx (VALU): writes x to TWO buffers (seeds t=0 atomic target) ----------
__global__ __launch_bounds__(256) void k_hx(const float* __restrict__ v,
                                            const float* __restrict__ labels,
                                            const float* __restrict__ goal,
                                            const float* __restrict__ w1, const float* __restrict__ b1,
                                            const float* __restrict__ w2, const float* __restrict__ b2,
                                            float* __restrict__ xout, float* __restrict__ xout2, int N) {
  int lane = threadIdx.x & 63;
  int wid = (blockIdx.x * blockDim.x + threadIdx.x) >> 6;
  int base = wid * GE;
  int c = lane % 9;
  float f[GE];
#pragma unroll
  for (int e = 0; e < GE; ++e) {
    int i = base + e; if (i >= N) i = N - 1;
    float fv = 0.f;
    if (lane < 36) {
      float vcv = (c < 7) ? v[7 * i + c] : labels[2 * i + (c - 7)];
      float gl = goal[c];
      float d = vcv - gl;
      fv = (lane < 9) ? vcv : (lane < 18) ? gl : (lane < 27) ? d : d * d;
    }
    f[e] = fv;
  }
  float acc[GE];
  float bb = b1[lane];
#pragma unroll
  for (int e = 0; e < GE; ++e) acc[e] = bb;
  for (int k = 0; k < 36; ++k) {
    float w = w1[k * 64 + lane];
#pragma unroll
    for (int e = 0; e < GE; ++e) acc[e] = fmaf(bcast(f[e], k), w, acc[e]);
  }
  float h[GE];
#pragma unroll
  for (int e = 0; e < GE; ++e) h[e] = fmaxf(acc[e], 0.f);
  float b2v = b2[lane];
#pragma unroll
  for (int e = 0; e < GE; ++e) acc[e] = b2v;
#pragma unroll 4
  for (int k = 0; k < 64; ++k) {
    float w = w2[k * 64 + lane];
#pragma unroll
    for (int e = 0; e < GE; ++e) acc[e] = fmaf(bcast(h[e], k), w, acc[e]);
  }
#pragma unroll
  for (int e = 0; e < GE; ++e) {
    int i = base + e;
    if (i < N) {
      xout[(size_t)i * 64 + lane] = acc[e];
      xout2[(size_t)i * 64 + lane] = acc[e];
    }
  }
}

// ---------------- fused hy + fx (t=0): compute y0, store fp16, run fx with it ----------
__global__ __launch_bounds__(256) void k_hyfx(
    const float* __restrict__ vcp, const float* __restrict__ x,
    const int* __restrict__ src, const int* __restrict__ dst,
    const _Float16* __restrict__ hB1, const float* __restrict__ hb1,
    const _Float16* __restrict__ hB2, const float* __restrict__ hb2,
    const _Float16* __restrict__ xB1, const float* __restrict__ xb1,
    const _Float16* __restrict__ xB2, const float* __restrict__ xb2,
    _Float16* __restrict__ y, float* __restrict__ xnew, int E) {
  __shared__ float hbuf[4][16 * 68];  // wave-private, sequentially reused
  const int lane = threadIdx.x & 63;
  const int wv = threadIdx.x >> 6;
  const int m = lane & 15, q = lane >> 4;
  const int base = blockIdx.x * 64 + wv * 16;
  int em = base + m; if (em >= E) em = E - 1;
  const int si = src[em], di = dst[em];
  const int row = base + m;
  const bool live = row < E;

  // issue gathers early: vcp (hy A-frag) + x rows (fx)
  const int node = (q < 2) ? di : si;
  const float* p = vcp + (size_t)node * 16 + (q & 1) * 8;
  float f[8];
  *(float4*)(f + 0) = *(const float4*)(p);
  *(float4*)(f + 4) = *(const float4*)(p + 4);
  float fs[16], fd[16];
  load_row(x + (size_t)si * 64 + q * 8, fs);
  load_row(x + (size_t)di * 64 + q * 8, fd);

  U8h Ah, Al;
  dec8h(f, Ah, Al);

  // hy L1 (K=32)
  f32x4 acc[4];
#pragma unroll
  for (int t = 0; t < 4; ++t) { float bv = hb1[t * 16 + m]; acc[t] = (f32x4){bv, bv, bv, bv}; }
#pragma unroll
  for (int t = 0; t < 4; ++t) {
    f16x8 b = *(const f16x8*)(hB1 + ((size_t)t * 64 + lane) * 8);
    acc[t] = __builtin_amdgcn_mfma_f32_16x16x32_f16(Ah.v, b, acc[t], 0, 0, 0);
    acc[t] = __builtin_amdgcn_mfma_f32_16x16x32_f16(Al.v, b, acc[t], 0, 0, 0);
  }

  float* hb = hbuf[wv];
#pragma unroll
  for (int t = 0; t < 4; ++t)
#pragma unroll
    for (int r = 0; r < 4; ++r)
      hb[(q * 4 + r) * 68 + t * 16 + m] = fmaxf(acc[t][r], 0.f);

  float fh[16];
  load_row(hb + m * 68 + q * 8, fh);
  U8h A2h[2], A2l[2];
  dec8h(fh + 0, A2h[0], A2l[0]);
  dec8h(fh + 8, A2h[1], A2l[1]);

  // hy L2
  f32x4 o[4];
#pragma unroll
  for (int t = 0; t < 4; ++t) { float bv = hb2[t * 16 + m]; o[t] = (f32x4){bv, bv, bv, bv}; }
#pragma unroll
  for (int c = 0; c < 2; ++c) {
#pragma unroll
    for (int t = 0; t < 4; ++t) {
      f16x8 b = *(const f16x8*)(hB2 + ((size_t)(c * 4 + t) * 64 + lane) * 8);
      o[t] = __builtin_amdgcn_mfma_f32_16x16x32_f16(A2h[c].v, b, o[t], 0, 0, 0);
      o[t] = __builtin_amdgcn_mfma_f32_16x16x32_f16(A2l[c].v, b, o[t], 0, 0, 0);
    }
  }

  // transpose y0 -> row layout, read in A-frag col split, quantize RNE, store
#pragma unroll
  for (int t = 0; t < 4; ++t)
#pragma unroll
    for (int r = 0; r < 4; ++r)
      hb[(q * 4 + r) * 68 + t * 16 + m] = o[t][r];

  float nv[16];
  load_row(hb + m * 68 + q * 8, nv);
  U8h Yh0, Yh1;
  conv8_rne(nv + 0, Yh0);
  conv8_rne(nv + 8, Yh1);
  if (live) {
    size_t yo = (size_t)row * 64 + q * 8;
    *(f16x8*)(y + yo)      = Yh0.v;
    *(f16x8*)(y + yo + 32) = Yh1.v;
  }

  // fx L1: [xs0,xs1,xd0,xd1,y0,y1]
  U8h Bh[4], Bl[4];
  dec8h(fs + 0, Bh[0], Bl[0]);
  dec8h(fs + 8, Bh[1], Bl[1]);
  dec8h(fd + 0, Bh[2], Bl[2]);
  dec8h(fd + 8, Bh[3], Bl[3]);

  f32x4 acc2[4];
#pragma unroll
  for (int t = 0; t < 4; ++t) { float bv = xb1[t * 16 + m]; acc2[t] = (f32x4){bv, bv, bv, bv}; }
#pragma unroll
  for (int c = 0; c < 4; ++c) {
#pragma unroll
    for (int t = 0; t < 4; ++t) {
      f16x8 b = *(const f16x8*)(xB1 + ((size_t)(c * 4 + t) * 64 + lane) * 8);
      acc2[t] = __builtin_amdgcn_mfma_f32_16x16x32_f16(Bh[c].v, b, acc2[t], 0, 0, 0);
      acc2[t] = __builtin_amdgcn_mfma_f32_16x16x32_f16(Bl[c].v, b, acc2[t], 0, 0, 0);
    }
  }
#pragma unroll
  for (int t = 0; t < 4; ++t) {
    f16x8 b4 = *(const f16x8*)(xB1 + ((size_t)(4 * 4 + t) * 64 + lane) * 8);
    f16x8 b5 = *(const f16x8*)(xB1 + ((size_t)(5 * 4 + t) * 64 + lane) * 8);
    acc2[t] = __builtin_amdgcn_mfma_f32_16x16x32_f16(Yh0.v, b4, acc2[t], 0, 0, 0);
    acc2[t] = __builtin_amdgcn_mfma_f32_16x16x32_f16(Yh1.v, b5, acc2[t], 0, 0, 0);
  }

#pragma unroll
  for (int t = 0; t < 4; ++t)
#pragma unroll
    for (int r = 0; r < 4; ++r)
      hb[(q * 4 + r) * 68 + t * 16 + m] = fmaxf(acc2[t][r], 0.f);

  float fh2[16];
  load_row(hb + m * 68 + q * 8, fh2);
  U8h C2h[2], C2l[2];
  dec8h(fh2 + 0, C2h[0], C2l[0]);
  dec8h(fh2 + 8, C2h[1], C2l[1]);

  f32x4 o2[4];
#pragma unroll
  for (int t = 0; t < 4; ++t) { float bv = xb2[t * 16 + m]; o2[t] = (f32x4){bv, bv, bv, bv}; }
#pragma unroll
  for (int c = 0; c < 2; ++c) {
#pragma unroll
    for (int t = 0; t < 4; ++t) {
      f16x8 b = *(const f16x8*)(xB2 + ((size_t)(c * 4 + t) * 64 + lane) * 8);
      o2[t] = __builtin_amdgcn_mfma_f32_16x16x32_f16(C2h[c].v, b, o2[t], 0, 0, 0);
      o2[t] = __builtin_amdgcn_mfma_f32_16x16x32_f16(C2l[c].v, b, o2[t], 0, 0, 0);
    }
  }

  int dd[4];
  int e0 = base + q * 4;
#pragma unroll
  for (int r = 0; r < 4; ++r) {
    int e2 = e0 + r;
    dd[r] = (e2 < E) ? dst[e2] : -1;
  }
  RunCtx rc = run_ctx(dd, lane, q);
#pragma unroll
  for (int t = 0; t < 4; ++t) emit_t(o2[t], dd, rc, lane, m, t, xnew);
}

// ---------------- fused fy + fx (t=1,2): y single fp16 ----------
__global__ __launch_bounds__(256) void k_fyfx(
    const float* __restrict__ x, _Float16* __restrict__ y,
    const int* __restrict__ src, const int* __restrict__ dst,
    const _Float16* __restrict__ yB1, const float* __restrict__ yb1,
    const _Float16* __restrict__ yB2, const float* __restrict__ yb2,
    const _Float16* __restrict__ xB1, const float* __restrict__ xb1,
    const _Float16* __restrict__ xB2, const float* __restrict__ xb2,
    float* __restrict__ xnew, int E) {
  __shared__ float hbuf[4][16 * 68];
  const int lane = threadIdx.x & 63;
  const int wv = threadIdx.x >> 6;
  const int m = lane & 15, q = lane >> 4;
  const int base = blockIdx.x * 64 + wv * 16;
  int em = base + m; if (em >= E) em = E - 1;
  const int si = src[em], di = dst[em];
  const int row = base + m;
  const bool live = row < E;

  float fs[16], fd[16];
  load_row(x + (size_t)si * 64 + q * 8, fs);
  load_row(x + (size_t)di * 64 + q * 8, fd);
  U8h Ho[2];
  {
    size_t yo = (size_t)em * 64 + q * 8;
    Ho[0].v = *(const f16x8*)(y + yo);  Ho[1].v = *(const f16x8*)(y + yo + 32);
  }

  U8h Ah[4], Al[4];             // [0,1]=xd  [2,3]=xs
  dec8h(fd + 0, Ah[0], Al[0]);
  dec8h(fd + 8, Ah[1], Al[1]);
  dec8h(fs + 0, Ah[2], Al[2]);
  dec8h(fs + 8, Ah[3], Al[3]);

  // fy L1
  f32x4 acc[4];
#pragma unroll
  for (int t = 0; t < 4; ++t) { float bv = yb1[t * 16 + m]; acc[t] = (f32x4){bv, bv, bv, bv}; }
#pragma unroll
  for (int c = 0; c < 4; ++c) {
#pragma unroll
    for (int t = 0; t < 4; ++t) {
      f16x8 b = *(const f16x8*)(yB1 + ((size_t)(c * 4 + t) * 64 + lane) * 8);
      acc[t] = __builtin_amdgcn_mfma_f32_16x16x32_f16(Ah[c].v, b, acc[t], 0, 0, 0);
      acc[t] = __builtin_amdgcn_mfma_f32_16x16x32_f16(Al[c].v, b, acc[t], 0, 0, 0);
    }
  }

  float* hb = hbuf[wv];
#pragma unroll
  for (int t = 0; t < 4; ++t)
#pragma unroll
    for (int r = 0; r < 4; ++r)
      hb[(q * 4 + r) * 68 + t * 16 + m] = fmaxf(acc[t][r], 0.f);

  float fh[16];
  load_row(hb + m * 68 + q * 8, fh);
  U8h A2h[2], A2l[2];
  dec8h(fh + 0, A2h[0], A2l[0]);
  dec8h(fh + 8, A2h[1], A2l[1]);

  // fy L2
  f32x4 o[4];
#pragma unroll
  for (int t = 0; t < 4; ++t) { float bv = yb2[t * 16 + m]; o[t] = (f32x4){bv, bv, bv, bv}; }
#pragma unroll
  for (int c = 0; c < 2; ++c) {
#pragma unroll
    for (int t = 0; t < 4; ++t) {
      f16x8 b = *(const f16x8*)(yB2 + ((size_t)(c * 4 + t) * 64 + lane) * 8);
      o[t] = __builtin_amdgcn_mfma_f32_16x16x32_f16(A2h[c].v, b, o[t], 0, 0, 0);
      o[t] = __builtin_amdgcn_mfma_f32_16x16x32_f16(A2l[c].v, b, o[t], 0, 0, 0);
    }
  }

  // transpose fy out -> read A-frag split
#pragma unroll
  for (int t = 0; t < 4; ++t)
#pragma unroll
    for (int r = 0; r < 4; ++r)
      hb[(q * 4 + r) * 68 + t * 16 + m] = o[t][r];

  float nv[16];
  load_row(hb + m * 68 + q * 8, nv);
#pragma unroll
  for (int i = 0; i < 8; ++i) {
    nv[i]     = fmaxf((float)Ho[0].s[i], nv[i]);
    nv[8 + i] = fmaxf((float)Ho[1].s[i], nv[8 + i]);
  }
  U8h Yh0, Yh1;
  conv8_rne(nv + 0, Yh0);
  conv8_rne(nv + 8, Yh1);
  if (live) {
    size_t yo = (size_t)row * 64 + q * 8;
    *(f16x8*)(y + yo)      = Yh0.v;
    *(f16x8*)(y + yo + 32) = Yh1.v;
  }

  // fx L1: [xs0,xs1,xd0,xd1] = Ah[2],Ah[3],Ah[0],Ah[1] ; then y
  f32x4 acc2[4];
#pragma unroll
  for (int t = 0; t < 4; ++t) { float bv = xb1[t * 16 + m]; acc2[t] = (f32x4){bv, bv, bv, bv}; }
  const int remap[4] = {2, 3, 0, 1};
#pragma unroll
  for (int c = 0; c < 4; ++c) {
    int a = remap[c];
#pragma unroll
    for (int t = 0; t < 4; ++t) {
      f16x8 b = *(const f16x8*)(xB1 + ((size_t)(c * 4 + t) * 64 + lane) * 8);
      acc2[t] = __builtin_amdgcn_mfma_f32_16x16x32_f16(Ah[a].v, b, acc2[t], 0, 0, 0);
      acc2[t] = __builtin_amdgcn_mfma_f32_16x16x32_f16(Al[a].v, b, acc2[t], 0, 0, 0);
    }
  }
#pragma unroll
  for (int t = 0; t < 4; ++t) {
    f16x8 b4 = *(const f16x8*)(xB1 + ((size_t)(4 * 4 + t) * 64 + lane) * 8);
    f16x8 b5 = *(const f16x8*)(xB1 + ((size_t)(5 * 4 + t) * 64 + lane) * 8);
    acc2[t] = __builtin_amdgcn_mfma_f32_16x16x32_f16(Yh0.v, b4, acc2[t], 0, 0, 0);
    acc2[t] = __builtin_amdgcn_mfma_f32_16x16x32_f16(Yh1.v, b5, acc2[t], 0, 0, 0);
  }

#pragma unroll
  for (int t = 0; t < 4; ++t)
#pragma unroll
    for (int r = 0; r < 4; ++r)
      hb[(q * 4 + r) * 68 + t * 16 + m] = fmaxf(acc2[t][r], 0.f);

  float fh2[16];
  load_row(hb + m * 68 + q * 8, fh2);
  U8h B2h[2], B2l[2];
  dec8h(fh2 + 0, B2h[0], B2l[0]);
  dec8h(fh2 + 8, B2h[1], B2l[1]);

  f32x4 o2[4];
#pragma unroll
  for (int t = 0; t < 4; ++t) { float bv = xb2[t * 16 + m]; o2[t] = (f32x4){bv, bv, bv, bv}; }
#pragma unroll
  for (int c = 0; c < 2; ++c) {
#pragma unroll
    for (int t = 0; t < 4; ++t) {
      f16x8 b = *(const f16x8*)(xB2 + ((size_t)(c * 4 + t) * 64 + lane) * 8);
      o2[t] = __builtin_amdgcn_mfma_f32_16x16x32_f16(B2h[c].v, b, o2[t], 0, 0, 0);
      o2[t] = __builtin_amdgcn_mfma_f32_16x16x32_f16(B2l[c].v, b, o2[t], 0, 0, 0);
    }
  }

  int dd[4];
  int e0 = base + q * 4;
#pragma unroll
  for (int r = 0; r < 4; ++r) {
    int e2 = e0 + r;
    dd[r] = (e2 < E) ? dst[e2] : -1;
  }
  RunCtx rc = run_ctx(dd, lane, q);
#pragma unroll
  for (int t = 0; t < 4; ++t) emit_t(o2[t], dd, rc, lane, m, t, xnew);
}

// ---------------- feta (VALU) ----------------
__global__ __launch_bounds__(256) void k_feta(const float* __restrict__ x,
                                              const float* __restrict__ w1, const float* __restrict__ b1,
                                              const float* __restrict__ w2, const float* __restrict__ b2,
                                              const float* __restrict__ w3,
                                              float* __restrict__ out, int N) {
  int lane = threadIdx.x & 63;
  int wid = (blockIdx.x * blockDim.x + threadIdx.x) >> 6;
  int base = wid * GE;
  float xr[GE];
#pragma unroll
  for (int e = 0; e < GE; ++e) {
    int i = base + e; if (i >= N) i = N - 1;
    xr[e] = x[(size_t)i * 64 + lane];
  }
  float acc[GE];
  float bb = b1[lane];
#pragma unroll
  for (int e = 0; e < GE; ++e) acc[e] = bb;
#pragma unroll 4
  for (int k = 0; k < 64; ++k) {
    float w = w1[k * 64 + lane];
#pragma unroll
    for (int e = 0; e < GE; ++e) acc[e] = fmaf(bcast(xr[e], k), w, acc[e]);
  }
  float h1[GE];
#pragma unroll
  for (int e = 0; e < GE; ++e) h1[e] = fmaxf(acc[e], 0.f);
  float b2v = b2[lane];
#pragma unroll
  for (int e = 0; e < GE; ++e) acc[e] = b2v;
#pragma unroll 4
  for (int k = 0; k < 64; ++k) {
    float w = w2[k * 64 + lane];
#pragma unroll
    for (int e = 0; e < GE; ++e) acc[e] = fmaf(bcast(h1[e], k), w, acc[e]);
  }
  float w3l = w3[lane];
#pragma unroll
  for (int e = 0; e < GE; ++e) {
    float r = fmaxf(acc[e], 0.f) * w3l;
    for (int off = 32; off > 0; off >>= 1) r += __shfl_xor(r, off, 64);
    int i = base + e;
    if (lane == 0 && i < N) out[i] = r;
  }
}

__global__ __launch_bounds__(256) void k_copy(const float4* __restrict__ s,
                                              float4* __restrict__ d, int n4) {
  int i = blockIdx.x * 256 + threadIdx.x;
  if (i < n4) d[i] = s[i];
}

extern "C" void kernel_launch(void* const* d_in, const int* in_sizes, int n_in,
                              void* d_out, int out_size, void* d_ws, size_t ws_size,
                              hipStream_t stream) {
  const float* v      = (const float*)d_in[0];
  const float* labels = (const float*)d_in[1];
  const int*   ei     = (const int*)d_in[2];
  const float* hx_w1 = (const float*)d_in[4];
  const float* hx_b1 = (const float*)d_in[5];
  const float* hx_w2 = (const float*)d_in[6];
  const float* hx_b2 = (const float*)d_in[7];
  const float* hy_w1 = (const float*)d_in[8];
  const float* hy_b1 = (const float*)d_in[9];
  const float* hy_w2 = (const float*)d_in[10];
  const float* hy_b2 = (const float*)d_in[11];
  const float* fx_w1 = (const float*)d_in[12];
  const float* fx_b1 = (const float*)d_in[13];
  const float* fx_w2 = (const float*)d_in[14];
  const float* fx_b2 = (const float*)d_in[15];
  const float* fy_w1 = (const float*)d_in[16];
  const float* fy_b1 = (const float*)d_in[17];
  const float* fy_w2 = (const float*)d_in[18];
  const float* fy_b2 = (const float*)d_in[19];
  const float* feta_w1 = (const float*)d_in[20];
  const float* feta_b1 = (const float*)d_in[21];
  const float* feta_w2 = (const float*)d_in[22];
  const float* feta_b2 = (const float*)d_in[23];
  const float* feta_w3 = (const float*)d_in[24];

  int N = in_sizes[0] / 7;
  int E = in_sizes[2] / 2;
  const int* src = ei;
  const int* dst = ei + E;

  char* wsb = (char*)d_ws;
  float* goal = (float*)wsb;
  u64* goalkey = (u64*)(wsb + 16 * 4);
  float* xa = (float*)(wsb + 32 * 4);                            // N*64 f
  float* xb = xa + (size_t)N * 64;                               // N*64 f
  _Float16* y = (_Float16*)(xb + (size_t)N * 64);                // E*64 f16 (single)
  _Float16* wp = y + (size_t)E * 64;                             // 34816 f16
  float* vcp = (float*)(wp + 34816);                             // N*16 f
  int* deg = (int*)(vcp + (size_t)N * 16);                       // N
  int* cursor = deg + N;                                         // N
  int* srcp = cursor + N;                                        // E
  int* dstp = srcp + E;                                          // E
  int* bsum = dstp + E;                                          // 64
  int* boff = bsum + 64;                                         // 64

  _Float16* fxB1 = wp;          _Float16* fxB2 = wp + 12288;
  _Float16* fyB1 = wp + 16384;  _Float16* fyB2 = wp + 24576;
  _Float16* hyB1 = wp + 28672;  _Float16* hyB2 = wp + 30720;

  int SB = (N + 1023) / 1024;

  hipMemsetAsync(goalkey, 0, sizeof(u64), stream);
  hipMemsetAsync(deg, 0, (size_t)N * 4, stream);
  k_prep<<<17, 256, 0, stream>>>(fx_w1, fx_w2, fy_w1, fy_w2, hy_w1, hy_w2, wp);
  k_vch<<<(N * 16 + 255) / 256, 256, 0, stream>>>(v, labels, vcp, N, dst, E, deg);
  k_goal1<<<(N + 255) / 256, 256, 0, stream>>>(labels, N, goalkey);
  k_goal2<<<1, 64, 0, stream>>>(v, labels, goalkey, goal);
  k_scan1<<<SB, 256, 0, stream>>>(deg, N, bsum);
  k_scan2<<<1, 64, 0, stream>>>(bsum, SB, boff);
  k_scan3<<<SB, 256, 0, stream>>>(deg, boff, N, cursor);
  k_scatter<<<(E + 255) / 256, 256, 0, stream>>>(src, dst, E, cursor, srcp, dstp);

  // x1 -> xa and xb (xb is t=0 atomic seed)
  k_hx<<<(N + 31) / 32, 256, 0, stream>>>(v, labels, goal, hx_w1, hx_b1, hx_w2, hx_b2, xa, xb, N);

  int EB = (E + 63) / 64;
  // t=0: y0 = hy(vcp); x2 = max(x1, agg fx(x1,y0)) -> xb
  k_hyfx<<<EB, 256, 0, stream>>>(vcp, xa, srcp, dstp,
                                 hyB1, hy_b1, hyB2, hy_b2,
                                 fxB1, fx_b1, fxB2, fx_b2, y, xb, E);
  // t=1: y = max(y, fy(x2)); x3 = max(x2, agg fx(x2,y)) -> xa
  k_copy<<<(N * 16 + 255) / 256, 256, 0, stream>>>((const float4*)xb, (float4*)xa, N * 16);
  k_fyfx<<<EB, 256, 0, stream>>>(xb, y, srcp, dstp,
                                 fyB1, fy_b1, fyB2, fy_b2,
                                 fxB1, fx_b1, fxB2, fx_b2, xa, E);
  // t=2
  k_copy<<<(N * 16 + 255) / 256, 256, 0, stream>>>((const float4*)xa, (float4*)xb, N * 16);
  k_fyfx<<<EB, 256, 0, stream>>>(xa, y, srcp, dstp,
                                 fyB1, fy_b1, fyB2, fy_b2,
                                 fxB1, fx_b1, fxB2, fx_b2, xb, E);

  k_feta<<<(N + 31) / 32, 256, 0, stream>>>(xb, feta_w1, feta_b1, feta_w2, feta_b2, feta_w3,
                                            (float*)d_out, N);
}

// Round 10
// 385.486 us; speedup vs baseline: 6.3246x; 1.1219x over previous
//
#include <hip/hip_runtime.h>
#include <math.h>

typedef unsigned short u16;
typedef unsigned int u32;
typedef unsigned long long u64;
typedef __attribute__((ext_vector_type(8))) _Float16 f16x8;
typedef __attribute__((ext_vector_type(2))) _Float16 f16x2;
typedef __attribute__((ext_vector_type(4))) float f32x4;

union U8h { f16x8 v; f16x2 p[4]; u32 u[4]; _Float16 s[8]; };

__device__ __forceinline__ void atomicMaxF(float* addr, float val) {
  if (val >= 0.0f) {
    atomicMax((int*)addr, __float_as_int(val));
  } else {
    atomicMin((unsigned int*)addr, (unsigned int)__float_as_int(val));
  }
}

__device__ __forceinline__ f16x2 pk(float a, float b) {
  return __builtin_bit_cast(f16x2, __builtin_amdgcn_cvt_pkrtz(a, b));
}

// split 8 fp32 -> fp16 hi (RTZ) + lo (residual): hi+lo exact to ~2^-22
__device__ __forceinline__ void dec8h(const float* f, U8h& h, U8h& l) {
#pragma unroll
  for (int i = 0; i < 4; ++i) {
    float a = f[2 * i], b = f[2 * i + 1];
    f16x2 hp = pk(a, b);
    float ra = a - (float)hp[0];
    float rb = b - (float)hp[1];
    h.p[i] = hp;
    l.p[i] = pk(ra, rb);
  }
}

__device__ __forceinline__ void conv8_rne(const float* f, U8h& h) {
#pragma unroll
  for (int i = 0; i < 8; ++i) h.s[i] = (_Float16)f[i];
}

// lane's two 8-float chunks of a 64-float row (cols q*8.. and 32+q*8..)
__device__ __forceinline__ void load_row(const float* p, float* f) {
  *(float4*)(f + 0)  = *(const float4*)(p);
  *(float4*)(f + 4)  = *(const float4*)(p + 4);
  *(float4*)(f + 8)  = *(const float4*)(p + 32);
  *(float4*)(f + 12) = *(const float4*)(p + 36);
}

// ---- cross-q segmented-run merge for dst-sorted scatter-max ----
struct RunCtx { bool chain1, chain2, chain3, suppress; };

__device__ __forceinline__ RunCtx run_ctx(const int dd[4], int lane, int q) {
  bool allsame = (dd[0] == dd[1]) && (dd[1] == dd[2]) && (dd[2] == dd[3]);
  int nfd1 = __shfl(dd[0], lane + 16, 64);
  int nfd2 = __shfl(dd[0], lane + 32, 64);
  int nfd3 = __shfl(dd[0], lane + 48, 64);
  int as = allsame ? 1 : 0;
  int nas1 = __shfl(as, lane + 16, 64);
  int nas2 = __shfl(as, lane + 32, 64);
  int pld = __shfl(dd[3], lane - 16, 64);
  RunCtx c;
  c.chain1 = (q < 3) && (nfd1 == dd[3]);
  c.chain2 = c.chain1 && (nas1 != 0) && (q < 2) && (nfd2 == dd[3]);
  c.chain3 = c.chain2 && (nas2 != 0) && (q < 1) && (nfd3 == dd[3]);
  c.suppress = (q > 0) && (pld == dd[0]);
  return c;
}

__device__ __forceinline__ void emit_t(const f32x4 o, const int dd[4], const RunCtx c,
                                       int lane, int m, int t, float* __restrict__ xnew) {
  float fv = o[0];
  bool c01 = dd[1] == dd[0];
  fv = c01 ? fmaxf(fv, o[1]) : fv;
  bool c012 = c01 && (dd[2] == dd[1]);
  fv = c012 ? fmaxf(fv, o[2]) : fv;
  bool c0123 = c012 && (dd[3] == dd[2]);
  fv = c0123 ? fmaxf(fv, o[3]) : fv;
  float nfv1 = __shfl(fv, lane + 16, 64);
  float nfv2 = __shfl(fv, lane + 32, 64);
  float nfv3 = __shfl(fv, lane + 48, 64);
  float run = o[0];
  bool first = true;
#pragma unroll
  for (int r = 0; r < 4; ++r) {
    if (r > 0) run = (dd[r] == dd[r - 1]) ? fmaxf(run, o[r]) : o[r];
    bool end = (r == 3) || (dd[r + 1] != dd[r]);
    if (end) {
      float val = run;
      if (r == 3) {
        if (c.chain1) val = fmaxf(val, nfv1);
        if (c.chain2) val = fmaxf(val, nfv2);
        if (c.chain3) val = fmaxf(val, nfv3);
      }
      if (!(first && c.suppress) && dd[r] >= 0)
        atomicMaxF(&xnew[(size_t)dd[r] * 64 + t * 16 + m], val);
      first = false;
    }
  }
}

// XCD-aware block swizzle: contiguous edge ranges pin to one XCD's L2.
// gridDim.x must be a multiple of 8. Bijection on [0, gridDim.x).
__device__ __forceinline__ int swz_bid() {
  return (blockIdx.x & 7) * (gridDim.x >> 3) + (blockIdx.x >> 3);
}

// ---------------- goal ----------------
__global__ __launch_bounds__(256) void k_goal1(const float* __restrict__ labels, int N,
                                               u64* __restrict__ key) {
  int i = blockIdx.x * 256 + threadIdx.x;
  float val = (i < N) ? labels[2 * (size_t)i + 1] : 0.0f;
  u64 k = ((u64)__float_as_uint(fmaxf(val, 0.0f)) << 32) | (u32)(~(u32)i);
#pragma unroll
  for (int off = 32; off > 0; off >>= 1) {
    u64 o = __shfl_xor(k, off, 64);
    if (o > k) k = o;
  }
  if ((threadIdx.x & 63) == 0) atomicMax(key, k);
}

__global__ void k_goal2(const float* __restrict__ v, const float* __restrict__ labels,
                        const u64* __restrict__ key, float* __restrict__ goal) {
  int g = (int)(~(u32)(*key));
  int c = threadIdx.x;
  if (c < 9) goal[c] = (c < 7) ? v[7 * (size_t)g + c] : labels[2 * (size_t)g + (c - 7)];
}

// b1' = hx_b1 + goal . W1[goal rows]
__global__ void k_gbias(const float* __restrict__ goal, const float* __restrict__ hxw1,
                        const float* __restrict__ hxb1, float* __restrict__ b1p) {
  int n = threadIdx.x;
  if (n < 64) {
    float s = hxb1[n];
#pragma unroll
    for (int k = 0; k < 9; ++k) s += goal[k] * hxw1[(9 + k) * 64 + n];
    b1p[n] = s;
  }
}

// ---------------- vcp build + degree histogram ----------------
__global__ __launch_bounds__(256) void k_vch(const float* __restrict__ v,
                                             const float* __restrict__ labels,
                                             float* __restrict__ vcp, int N,
                                             const int* __restrict__ dst, int E,
                                             int* __restrict__ deg) {
  int tid = blockIdx.x * 256 + threadIdx.x;
  if (tid < N * 16) {
    int n = tid >> 4, c = tid & 15;
    float val = 0.f;
    if (c < 7) val = v[(size_t)n * 7 + c];
    else if (c == 7) val = labels[2 * (size_t)n];
    else if (c == 8) val = labels[2 * (size_t)n + 1];
    vcp[tid] = val;
  }
  if (tid < E) atomicAdd(&deg[dst[tid]], 1);
}

// ---------------- weight prep: frag-major fp16 for all MFMA MLPs ----------------
__global__ __launch_bounds__(256) void k_prep(const float* __restrict__ fxw1, const float* __restrict__ fxw2,
                                              const float* __restrict__ fyw1, const float* __restrict__ fyw2,
                                              const float* __restrict__ hyw1, const float* __restrict__ hyw2,
                                              const float* __restrict__ hxw1, const float* __restrict__ hxw2,
                                              const float* __restrict__ few1, const float* __restrict__ few2,
                                              _Float16* __restrict__ wp) {
  _Float16* fxB1 = wp;           // 12288
  _Float16* fxB2 = wp + 12288;   // 4096
  _Float16* fyB1 = wp + 16384;   // 8192
  _Float16* fyB2 = wp + 24576;   // 4096
  _Float16* hyB1 = wp + 28672;   // 2048
  _Float16* hyB2 = wp + 30720;   // 4096
  _Float16* hxB1 = wp + 34816;   // 2048
  _Float16* hxB2 = wp + 36864;   // 4096
  _Float16* feB1 = wp + 40960;   // 4096
  _Float16* feB2 = wp + 45056;   // 4096
  int tid = blockIdx.x * 256 + threadIdx.x;
  int which, id;
  _Float16* oh;
  if (tid < 1536)      { which = 0; id = tid;        oh = fxB1; }
  else if (tid < 2048) { which = 1; id = tid - 1536; oh = fxB2; }
  else if (tid < 3072) { which = 2; id = tid - 2048; oh = fyB1; }
  else if (tid < 3584) { which = 3; id = tid - 3072; oh = fyB2; }
  else if (tid < 3840) { which = 4; id = tid - 3584; oh = hyB1; }
  else if (tid < 4352) { which = 5; id = tid - 3840; oh = hyB2; }
  else if (tid < 4608) { which = 6; id = tid - 4352; oh = hxB1; }
  else if (tid < 5120) { which = 7; id = tid - 4608; oh = hxB2; }
  else if (tid < 5632) { which = 8; id = tid - 5120; oh = feB1; }
  else if (tid < 6144) { which = 9; id = tid - 5632; oh = feB2; }
  else return;
  int lane = id & 63;
  int q = lane >> 4, col = lane & 15;
  int c = id >> 8, t = (id >> 6) & 3;
#pragma unroll
  for (int j = 0; j < 8; ++j) {
    int k = c * 32 + q * 8 + j;
    int n = t * 16 + col;
    float w;
    if (which == 0) {
      w = (k < 64)  ? fxw1[k * 64 + n] + fxw1[(k + 64) * 64 + n]
        : (k < 128) ? fxw1[(k + 64) * 64 + n] - fxw1[(k - 64) * 64 + n]
                    : fxw1[(k + 64) * 64 + n];
    } else if (which == 1) {
      w = fxw2[k * 64 + n];
    } else if (which == 2) {
      w = (k < 64) ? fyw1[k * 64 + n] + fyw1[(k + 64) * 64 + n]
                   : fyw1[(k + 64) * 64 + n] - fyw1[(k - 64) * 64 + n];
    } else if (which == 3) {
      w = fyw2[k * 64 + n];
    } else if (which == 4) {
      if (k <= 8)                  w = hyw1[k * 64 + n] + hyw1[(k + 9) * 64 + n];
      else if (k >= 16 && k <= 24) w = hyw1[(k + 2) * 64 + n] - hyw1[(k - 16) * 64 + n];
      else                         w = 0.f;
    } else if (which == 5) {
      w = hyw2[k * 64 + n];
    } else if (which == 6) {
      // hx Wcat32: [vc(9); d(9); d^2(9); 0...]; goal rows folded into bias
      w = (k < 9) ? hxw1[k * 64 + n] : (k < 27) ? hxw1[(k + 9) * 64 + n] : 0.f;
    } else if (which == 7) {
      w = hxw2[k * 64 + n];
    } else if (which == 8) {
      w = few1[k * 64 + n];
    } else {
      w = few2[k * 64 + n];
    }
    oh[id * 8 + j] = (_Float16)w;
  }
}

// ---------------- CSR scan ----------------
__global__ __launch_bounds__(256) void k_scan1(const int* __restrict__ deg, int N,
                                               int* __restrict__ bsum) {
  __shared__ int red[256];
  int b = blockIdx.x;
  int s = 0;
  for (int i = threadIdx.x; i < 1024; i += 256) {
    int idx = b * 1024 + i;
    s += (idx < N) ? deg[idx] : 0;
  }
  red[threadIdx.x] = s; __syncthreads();
  for (int st = 128; st > 0; st >>= 1) {
    if (threadIdx.x < st) red[threadIdx.x] += red[threadIdx.x + st];
    __syncthreads();
  }
  if (threadIdx.x == 0) bsum[b] = red[0];
}

__global__ __launch_bounds__(256) void k_scan3(const int* __restrict__ deg,
                                               const int* __restrict__ bsum, int N,
                                               int* __restrict__ cursor) {
  __shared__ int lsum[256];
  __shared__ int bofs;
  int b = blockIdx.x;
  int tid = threadIdx.x;
  if (tid == 0) {
    int a = 0;
    for (int i = 0; i < b; ++i) a += bsum[i];
    bofs = a;
  }
  int base_i = b * 1024 + tid * 4;
  int loc[4]; int s = 0;
#pragma unroll
  for (int j = 0; j < 4; ++j) {
    int v = (base_i + j < N) ? deg[base_i + j] : 0;
    loc[j] = s; s += v;
  }
  lsum[tid] = s; __syncthreads();
  for (int st = 1; st < 256; st <<= 1) {
    int add = (tid >= st) ? lsum[tid - st] : 0;
    __syncthreads();
    lsum[tid] += add;
    __syncthreads();
  }
  int toff = bofs + lsum[tid] - s;
#pragma unroll
  for (int j = 0; j < 4; ++j) {
    if (base_i + j < N) cursor[base_i + j] = toff + loc[j];
  }
}

__global__ __launch_bounds__(256) void k_scatter(const int* __restrict__ src,
                                                 const int* __restrict__ dst, int E,
                                                 int* __restrict__ cursor,
                                                 int* __restrict__ srcp, int* __restrict__ dstp) {
  int e = blockIdx.x * 256 + threadIdx.x;
  if (e < E) {
    int d = dst[e];
    int pos = atomicAdd(&cursor[d], 1);
    srcp[pos] = src[e];
    dstp[pos] = d;
  }
}

// ---------------- hx (MFMA): x0 = MLP2([vc; d; d^2] K=32, goal-folded bias) ----------
__global__ __launch_bounds__(256) void k_hx2(
    const float* __restrict__ vcp, const float* __restrict__ goal,
    const _Float16* __restrict__ B1, const float* __restrict__ b1p,
    const _Float16* __restrict__ B2, const float* __restrict__ b2,
    float* __restrict__ xout, float* __restrict__ xout2, int N) {
  __shared__ float hbuf[4][16 * 68];
  const int lane = threadIdx.x & 63;
  const int wv = threadIdx.x >> 6;
  const int m = lane & 15, q = lane >> 4;
  const int base = blockIdx.x * 64 + wv * 16;
  int node = base + m; if (node >= N) node = N - 1;
  float vc[12];
  *(float4*)(vc + 0) = *(const float4*)(vcp + (size_t)node * 16);
  *(float4*)(vc + 4) = *(const float4*)(vcp + (size_t)node * 16 + 4);
  *(float4*)(vc + 8) = *(const float4*)(vcp + (size_t)node * 16 + 8);
  float gl[9];
#pragma unroll
  for (int i = 0; i < 9; ++i) gl[i] = goal[i];
  float f[8];
#pragma unroll
  for (int j = 0; j < 8; ++j) {
    int idx = q * 8 + j;
    float val = 0.f;
    if (idx < 9) val = vc[idx];
    else if (idx < 18) val = vc[idx - 9] - gl[idx - 9];
    else if (idx < 27) { float dv = vc[idx - 18] - gl[idx - 18]; val = dv * dv; }
    f[j] = val;
  }
  U8h Ah, Al;
  dec8h(f, Ah, Al);

  f32x4 acc[4];
#pragma unroll
  for (int t = 0; t < 4; ++t) { float bv = b1p[t * 16 + m]; acc[t] = (f32x4){bv, bv, bv, bv}; }
#pragma unroll
  for (int t = 0; t < 4; ++t) {
    f16x8 b = *(const f16x8*)(B1 + ((size_t)t * 64 + lane) * 8);
    acc[t] = __builtin_amdgcn_mfma_f32_16x16x32_f16(Ah.v, b, acc[t], 0, 0, 0);
    acc[t] = __builtin_amdgcn_mfma_f32_16x16x32_f16(Al.v, b, acc[t], 0, 0, 0);
  }

  float* hb = hbuf[wv];
#pragma unroll
  for (int t = 0; t < 4; ++t)
#pragma unroll
    for (int r = 0; r < 4; ++r)
      hb[(q * 4 + r) * 68 + t * 16 + m] = fmaxf(acc[t][r], 0.f);

  float fh[16];
  load_row(hb + m * 68 + q * 8, fh);
  U8h A2h[2], A2l[2];
  dec8h(fh + 0, A2h[0], A2l[0]);
  dec8h(fh + 8, A2h[1], A2l[1]);

  f32x4 acc2[4];
#pragma unroll
  for (int t = 0; t < 4; ++t) { float bv = b2[t * 16 + m]; acc2[t] = (f32x4){bv, bv, bv, bv}; }
#pragma unroll
  for (int c = 0; c < 2; ++c) {
#pragma unroll
    for (int t = 0; t < 4; ++t) {
      f16x8 b = *(const f16x8*)(B2 + ((size_t)(c * 4 + t) * 64 + lane) * 8);
      acc2[t] = __builtin_amdgcn_mfma_f32_16x16x32_f16(A2h[c].v, b, acc2[t], 0, 0, 0);
      acc2[t] = __builtin_amdgcn_mfma_f32_16x16x32_f16(A2l[c].v, b, acc2[t], 0, 0, 0);
    }
  }

#pragma unroll
  for (int t = 0; t < 4; ++t)
#pragma unroll
    for (int r = 0; r < 4; ++r)
      hb[(q * 4 + r) * 68 + t * 16 + m] = acc2[t][r];

  int row = base + m;
  if (row < N) {
    float ov[16];
    const float* orow = hb + m * 68 + q * 16;
    *(float4*)(ov + 0)  = *(const float4*)(orow);
    *(float4*)(ov + 4)  = *(const float4*)(orow + 4);
    *(float4*)(ov + 8)  = *(const float4*)(orow + 8);
    *(float4*)(ov + 12) = *(const float4*)(orow + 12);
    float* p1 = xout + (size_t)row * 64 + q * 16;
    float* p2 = xout2 + (size_t)row * 64 + q * 16;
#pragma unroll
    for (int i = 0; i < 4; ++i) {
      *(float4*)(p1 + i * 4) = *(const float4*)(ov + i * 4);
      *(float4*)(p2 + i * 4) = *(const float4*)(ov + i * 4);
    }
  }
}

// ---------------- fused hy + fx (t=0) ----------------
__global__ __launch_bounds__(256) void k_hyfx(
    const float* __restrict__ vcp, const float* __restrict__ x,
    const int* __restrict__ src, const int* __restrict__ dst,
    const _Float16* __restrict__ hB1, const float* __restrict__ hb1,
    const _Float16* __restrict__ hB2, const float* __restrict__ hb2,
    const _Float16* __restrict__ xB1, const float* __restrict__ xb1,
    const _Float16* __restrict__ xB2, const float* __restrict__ xb2,
    _Float16* __restrict__ y, float* __restrict__ xnew, int E) {
  __shared__ float hbuf[4][16 * 68];
  const int lane = threadIdx.x & 63;
  const int wv = threadIdx.x >> 6;
  const int m = lane & 15, q = lane >> 4;
  const int base = swz_bid() * 64 + wv * 16;
  int em = base + m; if (em >= E) em = E - 1;
  const int si = src[em], di = dst[em];
  const int row = base + m;
  const bool live = row < E;

  const int node = (q < 2) ? di : si;
  const float* p = vcp + (size_t)node * 16 + (q & 1) * 8;
  float f[8];
  *(float4*)(f + 0) = *(const float4*)(p);
  *(float4*)(f + 4) = *(const float4*)(p + 4);
  float fs[16], fd[16];
  load_row(x + (size_t)si * 64 + q * 8, fs);
  load_row(x + (size_t)di * 64 + q * 8, fd);

  U8h Ah, Al;
  dec8h(f, Ah, Al);

  f32x4 acc[4];
#pragma unroll
  for (int t = 0; t < 4; ++t) { float bv = hb1[t * 16 + m]; acc[t] = (f32x4){bv, bv, bv, bv}; }
#pragma unroll
  for (int t = 0; t < 4; ++t) {
    f16x8 b = *(const f16x8*)(hB1 + ((size_t)t * 64 + lane) * 8);
    acc[t] = __builtin_amdgcn_mfma_f32_16x16x32_f16(Ah.v, b, acc[t], 0, 0, 0);
    acc[t] = __builtin_amdgcn_mfma_f32_16x16x32_f16(Al.v, b, acc[t], 0, 0, 0);
  }

  float* hb = hbuf[wv];
#pragma unroll
  for (int t = 0; t < 4; ++t)
#pragma unroll
    for (int r = 0; r < 4; ++r)
      hb[(q * 4 + r) * 68 + t * 16 + m] = fmaxf(acc[t][r], 0.f);

  float fh[16];
  load_row(hb + m * 68 + q * 8, fh);
  U8h A2h[2], A2l[2];
  dec8h(fh + 0, A2h[0], A2l[0]);
  dec8h(fh + 8, A2h[1], A2l[1]);

  f32x4 o[4];
#pragma unroll
  for (int t = 0; t < 4; ++t) { float bv = hb2[t * 16 + m]; o[t] = (f32x4){bv, bv, bv, bv}; }
#pragma unroll
  for (int c = 0; c < 2; ++c) {
#pragma unroll
    for (int t = 0; t < 4; ++t) {
      f16x8 b = *(const f16x8*)(hB2 + ((size_t)(c * 4 + t) * 64 + lane) * 8);
      o[t] = __builtin_amdgcn_mfma_f32_16x16x32_f16(A2h[c].v, b, o[t], 0, 0, 0);
      o[t] = __builtin_amdgcn_mfma_f32_16x16x32_f16(A2l[c].v, b, o[t], 0, 0, 0);
    }
  }

#pragma unroll
  for (int t = 0; t < 4; ++t)
#pragma unroll
    for (int r = 0; r < 4; ++r)
      hb[(q * 4 + r) * 68 + t * 16 + m] = o[t][r];

  float nv[16];
  load_row(hb + m * 68 + q * 8, nv);
  U8h Yh0, Yh1;
  conv8_rne(nv + 0, Yh0);
  conv8_rne(nv + 8, Yh1);
  if (live) {
    size_t yo = (size_t)row * 64 + q * 8;
    *(f16x8*)(y + yo)      = Yh0.v;
    *(f16x8*)(y + yo + 32) = Yh1.v;
  }

  U8h Bh[4], Bl[4];
  dec8h(fs + 0, Bh[0], Bl[0]);
  dec8h(fs + 8, Bh[1], Bl[1]);
  dec8h(fd + 0, Bh[2], Bl[2]);
  dec8h(fd + 8, Bh[3], Bl[3]);

  f32x4 acc2[4];
#pragma unroll
  for (int t = 0; t < 4; ++t) { float bv = xb1[t * 16 + m]; acc2[t] = (f32x4){bv, bv, bv, bv}; }
#pragma unroll
  for (int c = 0; c < 4; ++c) {
#pragma unroll
    for (int t = 0; t < 4; ++t) {
      f16x8 b = *(const f16x8*)(xB1 + ((size_t)(c * 4 + t) * 64 + lane) * 8);
      acc2[t] = __builtin_amdgcn_mfma_f32_16x16x32_f16(Bh[c].v, b, acc2[t], 0, 0, 0);
      acc2[t] = __builtin_amdgcn_mfma_f32_16x16x32_f16(Bl[c].v, b, acc2[t], 0, 0, 0);
    }
  }
#pragma unroll
  for (int t = 0; t < 4; ++t) {
    f16x8 b4 = *(const f16x8*)(xB1 + ((size_t)(4 * 4 + t) * 64 + lane) * 8);
    f16x8 b5 = *(const f16x8*)(xB1 + ((size_t)(5 * 4 + t) * 64 + lane) * 8);
    acc2[t] = __builtin_amdgcn_mfma_f32_16x16x32_f16(Yh0.v, b4, acc2[t], 0, 0, 0);
    acc2[t] = __builtin_amdgcn_mfma_f32_16x16x32_f16(Yh1.v, b5, acc2[t], 0, 0, 0);
  }

#pragma unroll
  for (int t = 0; t < 4; ++t)
#pragma unroll
    for (int r = 0; r < 4; ++r)
      hb[(q * 4 + r) * 68 + t * 16 + m] = fmaxf(acc2[t][r], 0.f);

  float fh2[16];
  load_row(hb + m * 68 + q * 8, fh2);
  U8h C2h[2], C2l[2];
  dec8h(fh2 + 0, C2h[0], C2l[0]);
  dec8h(fh2 + 8, C2h[1], C2l[1]);

  f32x4 o2[4];
#pragma unroll
  for (int t = 0; t < 4; ++t) { float bv = xb2[t * 16 + m]; o2[t] = (f32x4){bv, bv, bv, bv}; }
#pragma unroll
  for (int c = 0; c < 2; ++c) {
#pragma unroll
    for (int t = 0; t < 4; ++t) {
      f16x8 b = *(const f16x8*)(xB2 + ((size_t)(c * 4 + t) * 64 + lane) * 8);
      o2[t] = __builtin_amdgcn_mfma_f32_16x16x32_f16(C2h[c].v, b, o2[t], 0, 0, 0);
      o2[t] = __builtin_amdgcn_mfma_f32_16x16x32_f16(C2l[c].v, b, o2[t], 0, 0, 0);
    }
  }

  int dd[4];
  int e0 = base + q * 4;
#pragma unroll
  for (int r = 0; r < 4; ++r) {
    int e2 = e0 + r;
    dd[r] = (e2 < E) ? dst[e2] : -1;
  }
  RunCtx rc = run_ctx(dd, lane, q);
#pragma unroll
  for (int t = 0; t < 4; ++t) emit_t(o2[t], dd, rc, lane, m, t, xnew);
}

// ---------------- fused fy + fx (t=1,2) ----------------
__global__ __launch_bounds__(256) void k_fyfx(
    const float* __restrict__ x, _Float16* __restrict__ y,
    const int* __restrict__ src, const int* __restrict__ dst,
    const _Float16* __restrict__ yB1, const float* __restrict__ yb1,
    const _Float16* __restrict__ yB2, const float* __restrict__ yb2,
    const _Float16* __restrict__ xB1, const float* __restrict__ xb1,
    const _Float16* __restrict__ xB2, const float* __restrict__ xb2,
    float* __restrict__ xnew, int E, int storeY) {
  __shared__ float hbuf[4][16 * 68];
  const int lane = threadIdx.x & 63;
  const int wv = threadIdx.x >> 6;
  const int m = lane & 15, q = lane >> 4;
  const int base = swz_bid() * 64 + wv * 16;
  int em = base + m; if (em >= E) em = E - 1;
  const int si = src[em], di = dst[em];
  const int row = base + m;
  const bool live = row < E;

  float fs[16], fd[16];
  load_row(x + (size_t)si * 64 + q * 8, fs);
  load_row(x + (size_t)di * 64 + q * 8, fd);
  U8h Ho[2];
  {
    size_t yo = (size_t)em * 64 + q * 8;
    Ho[0].v = *(const f16x8*)(y + yo);  Ho[1].v = *(const f16x8*)(y + yo + 32);
  }

  U8h Ah[4], Al[4];             // [0,1]=xd  [2,3]=xs
  dec8h(fd + 0, Ah[0], Al[0]);
  dec8h(fd + 8, Ah[1], Al[1]);
  dec8h(fs + 0, Ah[2], Al[2]);
  dec8h(fs + 8, Ah[3], Al[3]);

  f32x4 acc[4];
#pragma unroll
  for (int t = 0; t < 4; ++t) { float bv = yb1[t * 16 + m]; acc[t] = (f32x4){bv, bv, bv, bv}; }
#pragma unroll
  for (int c = 0; c < 4; ++c) {
#pragma unroll
    for (int t = 0; t < 4; ++t) {
      f16x8 b = *(const f16x8*)(yB1 + ((size_t)(c * 4 + t) * 64 + lane) * 8);
      acc[t] = __builtin_amdgcn_mfma_f32_16x16x32_f16(Ah[c].v, b, acc[t], 0, 0, 0);
      acc[t] = __builtin_amdgcn_mfma_f32_16x16x32_f16(Al[c].v, b, acc[t], 0, 0, 0);
    }
  }

  float* hb = hbuf[wv];
#pragma unroll
  for (int t = 0; t < 4; ++t)
#pragma unroll
    for (int r = 0; r < 4; ++r)
      hb[(q * 4 + r) * 68 + t * 16 + m] = fmaxf(acc[t][r], 0.f);

  float fh[16];
  load_row(hb + m * 68 + q * 8, fh);
  U8h A2h[2], A2l[2];
  dec8h(fh + 0, A2h[0], A2l[0]);
  dec8h(fh + 8, A2h[1], A2l[1]);

  f32x4 o[4];
#pragma unroll
  for (int t = 0; t < 4; ++t) { float bv = yb2[t * 16 + m]; o[t] = (f32x4){bv, bv, bv, bv}; }
#pragma unroll
  for (int c = 0; c < 2; ++c) {
#pragma unroll
    for (int t = 0; t < 4; ++t) {
      f16x8 b = *(const f16x8*)(yB2 + ((size_t)(c * 4 + t) * 64 + lane) * 8);
      o[t] = __builtin_amdgcn_mfma_f32_16x16x32_f16(A2h[c].v, b, o[t], 0, 0, 0);
      o[t] = __builtin_amdgcn_mfma_f32_16x16x32_f16(A2l[c].v, b, o[t], 0, 0, 0);
    }
  }

#pragma unroll
  for (int t = 0; t < 4; ++t)
#pragma unroll
    for (int r = 0; r < 4; ++r)
      hb[(q * 4 + r) * 68 + t * 16 + m] = o[t][r];

  float nv[16];
  load_row(hb + m * 68 + q * 8, nv);
#pragma unroll
  for (int i = 0; i < 8; ++i) {
    nv[i]     = fmaxf((float)Ho[0].s[i], nv[i]);
    nv[8 + i] = fmaxf((float)Ho[1].s[i], nv[8 + i]);
  }
  U8h Yh0, Yh1;
  conv8_rne(nv + 0, Yh0);
  conv8_rne(nv + 8, Yh1);
  if (live && storeY) {
    size_t yo = (size_t)row * 64 + q * 8;
    *(f16x8*)(y + yo)      = Yh0.v;
    *(f16x8*)(y + yo + 32) = Yh1.v;
  }

  f32x4 acc2[4];
#pragma unroll
  for (int t = 0; t < 4; ++t) { float bv = xb1[t * 16 + m]; acc2[t] = (f32x4){bv, bv, bv, bv}; }
  const int remap[4] = {2, 3, 0, 1};
#pragma unroll
  for (int c = 0; c < 4; ++c) {
    int a = remap[c];
#pragma unroll
    for (int t = 0; t < 4; ++t) {
      f16x8 b = *(const f16x8*)(xB1 + ((size_t)(c * 4 + t) * 64 + lane) * 8);
      acc2[t] = __builtin_amdgcn_mfma_f32_16x16x32_f16(Ah[a].v, b, acc2[t], 0, 0, 0);
      acc2[t] = __builtin_amdgcn_mfma_f32_16x16x32_f16(Al[a].v, b, acc2[t], 0, 0, 0);
    }
  }
#pragma unroll
  for (int t = 0; t < 4; ++t) {
    f16x8 b4 = *(const f16x8*)(xB1 + ((size_t)(4 * 4 + t) * 64 + lane) * 8);
    f16x8 b5 = *(const f16x8*)(xB1 + ((size_t)(5 * 4 + t) * 64 + lane) * 8);
    acc2[t] = __builtin_amdgcn_mfma_f32_16x16x32_f16(Yh0.v, b4, acc2[t], 0, 0, 0);
    acc2[t] = __builtin_amdgcn_mfma_f32_16x16x32_f16(Yh1.v, b5, acc2[t], 0, 0, 0);
  }

#pragma unroll
  for (int t = 0; t < 4; ++t)
#pragma unroll
    for (int r = 0; r < 4; ++r)
      hb[(q * 4 + r) * 68 + t * 16 + m] = fmaxf(acc2[t][r], 0.f);

  float fh2[16];
  load_row(hb + m * 68 + q * 8, fh2);
  U8h B2h[2], B2l[2];
  dec8h(fh2 + 0, B2h[0], B2l[0]);
  dec8h(fh2 + 8, B2h[1], B2l[1]);

  f32x4 o2[4];
#pragma unroll
  for (int t = 0; t < 4; ++t) { float bv = xb2[t * 16 + m]; o2[t] = (f32x4){bv, bv, bv, bv}; }
#pragma unroll
  for (int c = 0; c < 2; ++c) {
#pragma unroll
    for (int t = 0; t < 4; ++t) {
      f16x8 b = *(const f16x8*)(xB2 + ((size_t)(c * 4 + t) * 64 + lane) * 8);
      o2[t] = __builtin_amdgcn_mfma_f32_16x16x32_f16(B2h[c].v, b, o2[t], 0, 0, 0);
      o2[t] = __builtin_amdgcn_mfma_f32_16x16x32_f16(B2l[c].v, b, o2[t], 0, 0, 0);
    }
  }

  int dd[4];
  int e0 = base + q * 4;
#pragma unroll
  for (int r = 0; r < 4; ++r) {
    int e2 = e0 + r;
    dd[r] = (e2 < E) ? dst[e2] : -1;
  }
  RunCtx rc = run_ctx(dd, lane, q);
#pragma unroll
  for (int t = 0; t < 4; ++t) emit_t(o2[t], dd, rc, lane, m, t, xnew);
}

// ---------------- feta (MFMA): out = w3 . relu(MLP2(x)) ----------------
__global__ __launch_bounds__(256) void k_feta2(
    const float* __restrict__ x,
    const _Float16* __restrict__ B1, const float* __restrict__ b1,
    const _Float16* __restrict__ B2, const float* __restrict__ b2,
    const float* __restrict__ w3, float* __restrict__ out, int N) {
  __shared__ float hbuf[4][16 * 68];
  const int lane = threadIdx.x & 63;
  const int wv = threadIdx.x >> 6;
  const int m = lane & 15, q = lane >> 4;
  const int base = blockIdx.x * 64 + wv * 16;
  int node = base + m; if (node >= N) node = N - 1;
  float fs[16];
  load_row(x + (size_t)node * 64 + q * 8, fs);
  U8h Ah[2], Al[2];
  dec8h(fs + 0, Ah[0], Al[0]);
  dec8h(fs + 8, Ah[1], Al[1]);

  f32x4 acc[4];
#pragma unroll
  for (int t = 0; t < 4; ++t) { float bv = b1[t * 16 + m]; acc[t] = (f32x4){bv, bv, bv, bv}; }
#pragma unroll
  for (int c = 0; c < 2; ++c) {
#pragma unroll
    for (int t = 0; t < 4; ++t) {
      f16x8 b = *(const f16x8*)(B1 + ((size_t)(c * 4 + t) * 64 + lane) * 8);
      acc[t] = __builtin_amdgcn_mfma_f32_16x16x32_f16(Ah[c].v, b, acc[t], 0, 0, 0);
      acc[t] = __builtin_amdgcn_mfma_f32_16x16x32_f16(Al[c].v, b, acc[t], 0, 0, 0);
    }
  }

  float* hb = hbuf[wv];
#pragma unroll
  for (int t = 0; t < 4; ++t)
#pragma unroll
    for (int r = 0; r < 4; ++r)
      hb[(q * 4 + r) * 68 + t * 16 + m] = fmaxf(acc[t][r], 0.f);

  float fh[16];
  load_row(hb + m * 68 + q * 8, fh);
  U8h A2h[2], A2l[2];
  dec8h(fh + 0, A2h[0], A2l[0]);
  dec8h(fh + 8, A2h[1], A2l[1]);

  f32x4 acc2[4];
#pragma unroll
  for (int t = 0; t < 4; ++t) { float bv = b2[t * 16 + m]; acc2[t] = (f32x4){bv, bv, bv, bv}; }
#pragma unroll
  for (int c = 0; c < 2; ++c) {
#pragma unroll
    for (int t = 0; t < 4; ++t) {
      f16x8 b = *(const f16x8*)(B2 + ((size_t)(c * 4 + t) * 64 + lane) * 8);
      acc2[t] = __builtin_amdgcn_mfma_f32_16x16x32_f16(A2h[c].v, b, acc2[t], 0, 0, 0);
      acc2[t] = __builtin_amdgcn_mfma_f32_16x16x32_f16(A2l[c].v, b, acc2[t], 0, 0, 0);
    }
  }

  float w3v[4];
#pragma unroll
  for (int t = 0; t < 4; ++t) w3v[t] = w3[t * 16 + m];
#pragma unroll
  for (int r = 0; r < 4; ++r) {
    float s = 0.f;
#pragma unroll
    for (int t = 0; t < 4; ++t) s += fmaxf(acc2[t][r], 0.f) * w3v[t];
    s += __shfl_xor(s, 1, 64);
    s += __shfl_xor(s, 2, 64);
    s += __shfl_xor(s, 4, 64);
    s += __shfl_xor(s, 8, 64);
    int row = base + q * 4 + r;
    if (m == 0 && row < N) out[row] = s;
  }
}

__global__ __launch_bounds__(256) void k_copy(const float4* __restrict__ s,
                                              float4* __restrict__ d, int n4) {
  int i = blockIdx.x * 256 + threadIdx.x;
  if (i < n4) d[i] = s[i];
}

extern "C" void kernel_launch(void* const* d_in, const int* in_sizes, int n_in,
                              void* d_out, int out_size, void* d_ws, size_t ws_size,
                              hipStream_t stream) {
  const float* v      = (const float*)d_in[0];
  const float* labels = (const float*)d_in[1];
  const int*   ei     = (const int*)d_in[2];
  const float* hx_w1 = (const float*)d_in[4];
  const float* hx_b1 = (const float*)d_in[5];
  const float* hx_w2 = (const float*)d_in[6];
  const float* hx_b2 = (const float*)d_in[7];
  const float* hy_w1 = (const float*)d_in[8];
  const float* hy_b1 = (const float*)d_in[9];
  const float* hy_w2 = (const float*)d_in[10];
  const float* hy_b2 = (const float*)d_in[11];
  const float* fx_w1 = (const float*)d_in[12];
  const float* fx_b1 = (const float*)d_in[13];
  const float* fx_w2 = (const float*)d_in[14];
  const float* fx_b2 = (const float*)d_in[15];
  const float* fy_w1 = (const float*)d_in[16];
  const float* fy_b1 = (const float*)d_in[17];
  const float* fy_w2 = (const float*)d_in[18];
  const float* fy_b2 = (const float*)d_in[19];
  const float* feta_w1 = (const float*)d_in[20];
  const float* feta_b1 = (const float*)d_in[21];
  const float* feta_w2 = (const float*)d_in[22];
  const float* feta_b2 = (const float*)d_in[23];
  const float* feta_w3 = (const float*)d_in[24];

  int N = in_sizes[0] / 7;
  int E = in_sizes[2] / 2;
  const int* src = ei;
  const int* dst = ei + E;

  char* wsb = (char*)d_ws;
  float* goal = (float*)wsb;                                     // 16 f
  u64* goalkey = (u64*)(wsb + 64);
  float* b1p = (float*)(wsb + 96);                               // 64 f
  float* xa = (float*)(wsb + 512);                               // N*64 f
  float* xb = xa + (size_t)N * 64;                               // N*64 f
  _Float16* y = (_Float16*)(xb + (size_t)N * 64);                // E*64 f16
  _Float16* wp = y + (size_t)E * 64;                             // 49152 f16
  float* vcp = (float*)(wp + 49152);                             // N*16 f
  int* deg = (int*)(vcp + (size_t)N * 16);                       // N
  int* cursor = deg + N;                                         // N
  int* srcp = cursor + N;                                        // E
  int* dstp = srcp + E;                                          // E
  int* bsum = dstp + E;                                          // 64

  _Float16* fxB1 = wp;          _Float16* fxB2 = wp + 12288;
  _Float16* fyB1 = wp + 16384;  _Float16* fyB2 = wp + 24576;
  _Float16* hyB1 = wp + 28672;  _Float16* hyB2 = wp + 30720;
  _Float16* hxB1 = wp + 34816;  _Float16* hxB2 = wp + 36864;
  _Float16* feB1 = wp + 40960;  _Float16* feB2 = wp + 45056;

  int SB = (N + 1023) / 1024;

  hipMemsetAsync(goalkey, 0, sizeof(u64), stream);
  hipMemsetAsync(deg, 0, (size_t)N * 4, stream);
  k_prep<<<24, 256, 0, stream>>>(fx_w1, fx_w2, fy_w1, fy_w2, hy_w1, hy_w2,
                                 hx_w1, hx_w2, feta_w1, feta_w2, wp);
  k_vch<<<(N * 16 + 255) / 256, 256, 0, stream>>>(v, labels, vcp, N, dst, E, deg);
  k_goal1<<<(N + 255) / 256, 256, 0, stream>>>(labels, N, goalkey);
  k_goal2<<<1, 64, 0, stream>>>(v, labels, goalkey, goal);
  k_gbias<<<1, 64, 0, stream>>>(goal, hx_w1, hx_b1, b1p);
  k_scan1<<<SB, 256, 0, stream>>>(deg, N, bsum);
  k_scan3<<<SB, 256, 0, stream>>>(deg, bsum, N, cursor);
  k_scatter<<<(E + 255) / 256, 256, 0, stream>>>(src, dst, E, cursor, srcp, dstp);

  // x1 -> xa and xb (xb is t=0 atomic seed)
  k_hx2<<<(N + 63) / 64, 256, 0, stream>>>(vcp, goal, hxB1, b1p, hxB2, hx_b2, xa, xb, N);

  int EB = (((E + 63) / 64 + 7) / 8) * 8;  // multiple of 8 for XCD swizzle
  // t=0: y0 = hy(vcp); x2 = max(x1, agg fx(x1,y0)) -> xb
  k_hyfx<<<EB, 256, 0, stream>>>(vcp, xa, srcp, dstp,
                                 hyB1, hy_b1, hyB2, hy_b2,
                                 fxB1, fx_b1, fxB2, fx_b2, y, xb, E);
  // t=1
  k_copy<<<(N * 16 + 255) / 256, 256, 0, stream>>>((const float4*)xb, (float4*)xa, N * 16);
  k_fyfx<<<EB, 256, 0, stream>>>(xb, y, srcp, dstp,
                                 fyB1, fy_b1, fyB2, fy_b2,
                                 fxB1, fx_b1, fxB2, fx_b2, xa, E, 1);
  // t=2 (y is dead after: skip its store)
  k_copy<<<(N * 16 + 255) / 256, 256, 0, stream>>>((const float4*)xa, (float4*)xb, N * 16);
  k_fyfx<<<EB, 256, 0, stream>>>(xa, y, srcp, dstp,
                                 fyB1, fy_b1, fyB2, fy_b2,
                                 fxB1, fx_b1, fxB2, fx_b2, xb, E, 0);

  k_feta2<<<(N + 63) / 64, 256, 0, stream>>>(xb, feB1, feta_b1, feB2, feta_b2, feta_w3,
                                             (float*)d_out, N);
}

// Round 11
// 342.399 us; speedup vs baseline: 7.1204x; 1.1258x over previous
//
#include <hip/hip_runtime.h>
#include <math.h>

typedef unsigned short u16;
typedef unsigned int u32;
typedef unsigned long long u64;
typedef __attribute__((ext_vector_type(8))) _Float16 f16x8;
typedef __attribute__((ext_vector_type(2))) _Float16 f16x2;
typedef __attribute__((ext_vector_type(4))) float f32x4;

union U8h { f16x8 v; f16x2 p[4]; u32 u[4]; _Float16 s[8]; };
union U4h { _Float16 s[4]; u64 u; };

__device__ __forceinline__ void atomicMaxF(float* addr, float val) {
  if (val >= 0.0f) {
    atomicMax((int*)addr, __float_as_int(val));
  } else {
    atomicMin((unsigned int*)addr, (unsigned int)__float_as_int(val));
  }
}

__device__ __forceinline__ f16x2 pk(float a, float b) {
  return __builtin_bit_cast(f16x2, __builtin_amdgcn_cvt_pkrtz(a, b));
}

// split 8 fp32 -> fp16 hi (RTZ) + lo (residual): hi+lo exact to ~2^-22
__device__ __forceinline__ void dec8h(const float* f, U8h& h, U8h& l) {
#pragma unroll
  for (int i = 0; i < 4; ++i) {
    float a = f[2 * i], b = f[2 * i + 1];
    f16x2 hp = pk(a, b);
    float ra = a - (float)hp[0];
    float rb = b - (float)hp[1];
    h.p[i] = hp;
    l.p[i] = pk(ra, rb);
  }
}

__device__ __forceinline__ void conv8_rne(const float* f, U8h& h) {
#pragma unroll
  for (int i = 0; i < 8; ++i) h.s[i] = (_Float16)f[i];
}

// lane's two 8-float chunks of a 64-float row (cols q*8.. and 32+q*8..)
__device__ __forceinline__ void load_row(const float* p, float* f) {
  *(float4*)(f + 0)  = *(const float4*)(p);
  *(float4*)(f + 4)  = *(const float4*)(p + 4);
  *(float4*)(f + 8)  = *(const float4*)(p + 32);
  *(float4*)(f + 12) = *(const float4*)(p + 36);
}

// ---- cross-q segmented-run merge for dst-sorted scatter-max ----
struct RunCtx { bool chain1, chain2, chain3, suppress; };

__device__ __forceinline__ RunCtx run_ctx(const int dd[4], int lane, int q) {
  bool allsame = (dd[0] == dd[1]) && (dd[1] == dd[2]) && (dd[2] == dd[3]);
  int nfd1 = __shfl(dd[0], lane + 16, 64);
  int nfd2 = __shfl(dd[0], lane + 32, 64);
  int nfd3 = __shfl(dd[0], lane + 48, 64);
  int as = allsame ? 1 : 0;
  int nas1 = __shfl(as, lane + 16, 64);
  int nas2 = __shfl(as, lane + 32, 64);
  int pld = __shfl(dd[3], lane - 16, 64);
  RunCtx c;
  c.chain1 = (q < 3) && (nfd1 == dd[3]);
  c.chain2 = c.chain1 && (nas1 != 0) && (q < 2) && (nfd2 == dd[3]);
  c.chain3 = c.chain2 && (nas2 != 0) && (q < 1) && (nfd3 == dd[3]);
  c.suppress = (q > 0) && (pld == dd[0]);
  return c;
}

__device__ __forceinline__ void emit_t(const f32x4 o, const int dd[4], const RunCtx c,
                                       int lane, int m, int t, float* __restrict__ xnew) {
  float fv = o[0];
  bool c01 = dd[1] == dd[0];
  fv = c01 ? fmaxf(fv, o[1]) : fv;
  bool c012 = c01 && (dd[2] == dd[1]);
  fv = c012 ? fmaxf(fv, o[2]) : fv;
  bool c0123 = c012 && (dd[3] == dd[2]);
  fv = c0123 ? fmaxf(fv, o[3]) : fv;
  float nfv1 = __shfl(fv, lane + 16, 64);
  float nfv2 = __shfl(fv, lane + 32, 64);
  float nfv3 = __shfl(fv, lane + 48, 64);
  float run = o[0];
  bool first = true;
#pragma unroll
  for (int r = 0; r < 4; ++r) {
    if (r > 0) run = (dd[r] == dd[r - 1]) ? fmaxf(run, o[r]) : o[r];
    bool end = (r == 3) || (dd[r + 1] != dd[r]);
    if (end) {
      float val = run;
      if (r == 3) {
        if (c.chain1) val = fmaxf(val, nfv1);
        if (c.chain2) val = fmaxf(val, nfv2);
        if (c.chain3) val = fmaxf(val, nfv3);
      }
      if (!(first && c.suppress) && dd[r] >= 0)
        atomicMaxF(&xnew[(size_t)dd[r] * 64 + t * 16 + m], val);
      first = false;
    }
  }
}

// ---------------- vcp build + degree histogram + goal argmax (fused) ----------------
__global__ __launch_bounds__(256) void k_vch(const float* __restrict__ v,
                                             const float* __restrict__ labels,
                                             float* __restrict__ vcp, int N,
                                             const int* __restrict__ dst, int E,
                                             int* __restrict__ deg, u64* __restrict__ key) {
  int tid = blockIdx.x * 256 + threadIdx.x;
  if (tid < N * 16) {
    int n = tid >> 4, c = tid & 15;
    float val = 0.f;
    if (c < 7) val = v[(size_t)n * 7 + c];
    else if (c == 7) val = labels[2 * (size_t)n];
    else if (c == 8) val = labels[2 * (size_t)n + 1];
    vcp[tid] = val;
  }
  if (tid < E) atomicAdd(&deg[dst[tid]], 1);
  if ((tid & ~63) < N) {  // whole-wave goal argmax reduce
    float val = (tid < N) ? labels[2 * (size_t)tid + 1] : 0.0f;
    u64 k = ((u64)__float_as_uint(fmaxf(val, 0.0f)) << 32) | (u32)(~(u32)tid);
#pragma unroll
    for (int off = 32; off > 0; off >>= 1) {
      u64 o = __shfl_xor(k, off, 64);
      if (o > k) k = o;
    }
    if ((threadIdx.x & 63) == 0) atomicMax(key, k);
  }
}

// ---------------- goal extract + hx goal-folded bias ----------------
__global__ void k_goal2b(const float* __restrict__ v, const float* __restrict__ labels,
                         const u64* __restrict__ key,
                         const float* __restrict__ hxw1, const float* __restrict__ hxb1,
                         float* __restrict__ goal, float* __restrict__ b1p) {
  __shared__ float g[9];
  int gi = (int)(~(u32)(*key));
  int c = threadIdx.x;
  if (c < 9) {
    float gv = (c < 7) ? v[7 * (size_t)gi + c] : labels[2 * (size_t)gi + (c - 7)];
    g[c] = gv;
    goal[c] = gv;
  }
  __syncthreads();
  if (c < 64) {
    float s = hxb1[c];
#pragma unroll
    for (int k = 0; k < 9; ++k) s += g[k] * hxw1[(9 + k) * 64 + c];
    b1p[c] = s;
  }
}

// ---------------- weight prep: frag-major fp16 for all MFMA MLPs ----------------
__global__ __launch_bounds__(256) void k_prep(const float* __restrict__ fxw1, const float* __restrict__ fxw2,
                                              const float* __restrict__ fyw1, const float* __restrict__ fyw2,
                                              const float* __restrict__ hyw1, const float* __restrict__ hyw2,
                                              const float* __restrict__ hxw1, const float* __restrict__ hxw2,
                                              const float* __restrict__ few1, const float* __restrict__ few2,
                                              _Float16* __restrict__ wp, u64* __restrict__ goalkey) {
  if (blockIdx.x == 0 && threadIdx.x == 0) *goalkey = 0;  // runs before k_vch's atomics
  _Float16* fxB1 = wp;           // 12288
  _Float16* fxB2 = wp + 12288;   // 4096
  _Float16* fyB1 = wp + 16384;   // 8192
  _Float16* fyB2 = wp + 24576;   // 4096
  _Float16* hyB1 = wp + 28672;   // 2048
  _Float16* hyB2 = wp + 30720;   // 4096
  _Float16* hxB1 = wp + 34816;   // 2048
  _Float16* hxB2 = wp + 36864;   // 4096
  _Float16* feB1 = wp + 40960;   // 4096
  _Float16* feB2 = wp + 45056;   // 4096
  int tid = blockIdx.x * 256 + threadIdx.x;
  int which, id;
  _Float16* oh;
  if (tid < 1536)      { which = 0; id = tid;        oh = fxB1; }
  else if (tid < 2048) { which = 1; id = tid - 1536; oh = fxB2; }
  else if (tid < 3072) { which = 2; id = tid - 2048; oh = fyB1; }
  else if (tid < 3584) { which = 3; id = tid - 3072; oh = fyB2; }
  else if (tid < 3840) { which = 4; id = tid - 3584; oh = hyB1; }
  else if (tid < 4352) { which = 5; id = tid - 3840; oh = hyB2; }
  else if (tid < 4608) { which = 6; id = tid - 4352; oh = hxB1; }
  else if (tid < 5120) { which = 7; id = tid - 4608; oh = hxB2; }
  else if (tid < 5632) { which = 8; id = tid - 5120; oh = feB1; }
  else if (tid < 6144) { which = 9; id = tid - 5632; oh = feB2; }
  else return;
  int lane = id & 63;
  int q = lane >> 4, col = lane & 15;
  int c = id >> 8, t = (id >> 6) & 3;
#pragma unroll
  for (int j = 0; j < 8; ++j) {
    int k = c * 32 + q * 8 + j;
    int n = t * 16 + col;
    float w;
    if (which == 0) {
      w = (k < 64)  ? fxw1[k * 64 + n] + fxw1[(k + 64) * 64 + n]
        : (k < 128) ? fxw1[(k + 64) * 64 + n] - fxw1[(k - 64) * 64 + n]
                    : fxw1[(k + 64) * 64 + n];
    } else if (which == 1) {
      w = fxw2[k * 64 + n];
    } else if (which == 2) {
      w = (k < 64) ? fyw1[k * 64 + n] + fyw1[(k + 64) * 64 + n]
                   : fyw1[(k + 64) * 64 + n] - fyw1[(k - 64) * 64 + n];
    } else if (which == 3) {
      w = fyw2[k * 64 + n];
    } else if (which == 4) {
      if (k <= 8)                  w = hyw1[k * 64 + n] + hyw1[(k + 9) * 64 + n];
      else if (k >= 16 && k <= 24) w = hyw1[(k + 2) * 64 + n] - hyw1[(k - 16) * 64 + n];
      else                         w = 0.f;
    } else if (which == 5) {
      w = hyw2[k * 64 + n];
    } else if (which == 6) {
      w = (k < 9) ? hxw1[k * 64 + n] : (k < 27) ? hxw1[(k + 9) * 64 + n] : 0.f;
    } else if (which == 7) {
      w = hxw2[k * 64 + n];
    } else if (which == 8) {
      w = few1[k * 64 + n];
    } else {
      w = few2[k * 64 + n];
    }
    oh[id * 8 + j] = (_Float16)w;
  }
}

// ---------------- CSR scan ----------------
__global__ __launch_bounds__(256) void k_scan1(const int* __restrict__ deg, int N,
                                               int* __restrict__ bsum) {
  __shared__ int red[256];
  int b = blockIdx.x;
  int s = 0;
  for (int i = threadIdx.x; i < 1024; i += 256) {
    int idx = b * 1024 + i;
    s += (idx < N) ? deg[idx] : 0;
  }
  red[threadIdx.x] = s; __syncthreads();
  for (int st = 128; st > 0; st >>= 1) {
    if (threadIdx.x < st) red[threadIdx.x] += red[threadIdx.x + st];
    __syncthreads();
  }
  if (threadIdx.x == 0) bsum[b] = red[0];
}

__global__ __launch_bounds__(256) void k_scan3(const int* __restrict__ deg,
                                               const int* __restrict__ bsum, int N,
                                               int* __restrict__ cursor) {
  __shared__ int lsum[256];
  __shared__ int bofs;
  int b = blockIdx.x;
  int tid = threadIdx.x;
  if (tid == 0) {
    int a = 0;
    for (int i = 0; i < b; ++i) a += bsum[i];
    bofs = a;
  }
  int base_i = b * 1024 + tid * 4;
  int loc[4]; int s = 0;
#pragma unroll
  for (int j = 0; j < 4; ++j) {
    int v = (base_i + j < N) ? deg[base_i + j] : 0;
    loc[j] = s; s += v;
  }
  lsum[tid] = s; __syncthreads();
  for (int st = 1; st < 256; st <<= 1) {
    int add = (tid >= st) ? lsum[tid - st] : 0;
    __syncthreads();
    lsum[tid] += add;
    __syncthreads();
  }
  int toff = bofs + lsum[tid] - s;
#pragma unroll
  for (int j = 0; j < 4; ++j) {
    if (base_i + j < N) cursor[base_i + j] = toff + loc[j];
  }
}

__global__ __launch_bounds__(256) void k_scatter(const int* __restrict__ src,
                                                 const int* __restrict__ dst, int E,
                                                 int* __restrict__ cursor,
                                                 int* __restrict__ srcp, int* __restrict__ dstp) {
  int e = blockIdx.x * 256 + threadIdx.x;
  if (e < E) {
    int d = dst[e];
    int pos = atomicAdd(&cursor[d], 1);
    srcp[pos] = src[e];
    dstp[pos] = d;
  }
}

// ---------------- hx (MFMA): x0 = MLP2([vc; d; d^2] K=32, goal-folded bias) ----------
// writes fp32 x to two buffers + fp16 shadow for edge-kernel gathers
__global__ __launch_bounds__(256) void k_hx2(
    const float* __restrict__ vcp, const float* __restrict__ goal,
    const _Float16* __restrict__ B1, const float* __restrict__ b1p,
    const _Float16* __restrict__ B2, const float* __restrict__ b2,
    float* __restrict__ xout, float* __restrict__ xout2, _Float16* __restrict__ xh, int N) {
  __shared__ float hbuf[4][16 * 68];
  const int lane = threadIdx.x & 63;
  const int wv = threadIdx.x >> 6;
  const int m = lane & 15, q = lane >> 4;
  const int base = blockIdx.x * 64 + wv * 16;
  int node = base + m; if (node >= N) node = N - 1;
  float vc[12];
  *(float4*)(vc + 0) = *(const float4*)(vcp + (size_t)node * 16);
  *(float4*)(vc + 4) = *(const float4*)(vcp + (size_t)node * 16 + 4);
  *(float4*)(vc + 8) = *(const float4*)(vcp + (size_t)node * 16 + 8);
  float gl[9];
#pragma unroll
  for (int i = 0; i < 9; ++i) gl[i] = goal[i];
  float f[8];
#pragma unroll
  for (int j = 0; j < 8; ++j) {
    int idx = q * 8 + j;
    float val = 0.f;
    if (idx < 9) val = vc[idx];
    else if (idx < 18) val = vc[idx - 9] - gl[idx - 9];
    else if (idx < 27) { float dv = vc[idx - 18] - gl[idx - 18]; val = dv * dv; }
    f[j] = val;
  }
  U8h Ah, Al;
  dec8h(f, Ah, Al);

  f32x4 acc[4];
#pragma unroll
  for (int t = 0; t < 4; ++t) { float bv = b1p[t * 16 + m]; acc[t] = (f32x4){bv, bv, bv, bv}; }
#pragma unroll
  for (int t = 0; t < 4; ++t) {
    f16x8 b = *(const f16x8*)(B1 + ((size_t)t * 64 + lane) * 8);
    acc[t] = __builtin_amdgcn_mfma_f32_16x16x32_f16(Ah.v, b, acc[t], 0, 0, 0);
    acc[t] = __builtin_amdgcn_mfma_f32_16x16x32_f16(Al.v, b, acc[t], 0, 0, 0);
  }

  float* hb = hbuf[wv];
#pragma unroll
  for (int t = 0; t < 4; ++t)
#pragma unroll
    for (int r = 0; r < 4; ++r)
      hb[(q * 4 + r) * 68 + t * 16 + m] = fmaxf(acc[t][r], 0.f);

  float fh[16];
  load_row(hb + m * 68 + q * 8, fh);
  U8h A2h[2], A2l[2];
  dec8h(fh + 0, A2h[0], A2l[0]);
  dec8h(fh + 8, A2h[1], A2l[1]);

  f32x4 acc2[4];
#pragma unroll
  for (int t = 0; t < 4; ++t) { float bv = b2[t * 16 + m]; acc2[t] = (f32x4){bv, bv, bv, bv}; }
#pragma unroll
  for (int c = 0; c < 2; ++c) {
#pragma unroll
    for (int t = 0; t < 4; ++t) {
      f16x8 b = *(const f16x8*)(B2 + ((size_t)(c * 4 + t) * 64 + lane) * 8);
      acc2[t] = __builtin_amdgcn_mfma_f32_16x16x32_f16(A2h[c].v, b, acc2[t], 0, 0, 0);
      acc2[t] = __builtin_amdgcn_mfma_f32_16x16x32_f16(A2l[c].v, b, acc2[t], 0, 0, 0);
    }
  }

#pragma unroll
  for (int t = 0; t < 4; ++t)
#pragma unroll
    for (int r = 0; r < 4; ++r)
      hb[(q * 4 + r) * 68 + t * 16 + m] = acc2[t][r];

  int row = base + m;
  if (row < N) {
    float ov[16];
    const float* orow = hb + m * 68 + q * 16;
    *(float4*)(ov + 0)  = *(const float4*)(orow);
    *(float4*)(ov + 4)  = *(const float4*)(orow + 4);
    *(float4*)(ov + 8)  = *(const float4*)(orow + 8);
    *(float4*)(ov + 12) = *(const float4*)(orow + 12);
    float* p1 = xout + (size_t)row * 64 + q * 16;
    float* p2 = xout2 + (size_t)row * 64 + q * 16;
#pragma unroll
    for (int i = 0; i < 4; ++i) {
      *(float4*)(p1 + i * 4) = *(const float4*)(ov + i * 4);
      *(float4*)(p2 + i * 4) = *(const float4*)(ov + i * 4);
    }
    U8h X0, X1;
    conv8_rne(ov + 0, X0);
    conv8_rne(ov + 8, X1);
    *(f16x8*)(xh + (size_t)row * 64 + q * 16)     = X0.v;
    *(f16x8*)(xh + (size_t)row * 64 + q * 16 + 8) = X1.v;
  }
}

// ---------------- convert-copy: fp32 seed copy + fp16 gather shadow ----------------
__global__ __launch_bounds__(256) void k_cc(const float4* __restrict__ s,
                                            float4* __restrict__ d,
                                            _Float16* __restrict__ h16, int n4) {
  int i = blockIdx.x * 256 + threadIdx.x;
  if (i < n4) {
    float4 v = s[i];
    d[i] = v;
    U4h o;
    o.s[0] = (_Float16)v.x; o.s[1] = (_Float16)v.y;
    o.s[2] = (_Float16)v.z; o.s[3] = (_Float16)v.w;
    *(u64*)(h16 + (size_t)i * 4) = o.u;
  }
}

// ---------------- fused hy + fx (t=0): x gathered fp16 ----------------
__global__ __launch_bounds__(256) void k_hyfx(
    const float* __restrict__ vcp, const _Float16* __restrict__ xh,
    const int* __restrict__ src, const int* __restrict__ dst,
    const _Float16* __restrict__ hB1, const float* __restrict__ hb1,
    const _Float16* __restrict__ hB2, const float* __restrict__ hb2,
    const _Float16* __restrict__ xB1, const float* __restrict__ xb1,
    const _Float16* __restrict__ xB2, const float* __restrict__ xb2,
    _Float16* __restrict__ y, float* __restrict__ xnew, int E) {
  __shared__ float hbuf[4][16 * 68];
  const int lane = threadIdx.x & 63;
  const int wv = threadIdx.x >> 6;
  const int m = lane & 15, q = lane >> 4;
  const int base = blockIdx.x * 64 + wv * 16;
  int em = base + m; if (em >= E) em = E - 1;
  const int si = src[em], di = dst[em];
  const int row = base + m;
  const bool live = row < E;

  // gathers: vcp row (fp32, hy) + x rows (fp16, fx)
  const int node = (q < 2) ? di : si;
  const float* p = vcp + (size_t)node * 16 + (q & 1) * 8;
  float f[8];
  *(float4*)(f + 0) = *(const float4*)(p);
  *(float4*)(f + 4) = *(const float4*)(p + 4);
  const _Float16* ps = xh + (size_t)si * 64 + q * 8;
  const _Float16* pd = xh + (size_t)di * 64 + q * 8;
  U8h Xs0, Xs1, Xd0, Xd1;
  Xs0.v = *(const f16x8*)ps;         Xs1.v = *(const f16x8*)(ps + 32);
  Xd0.v = *(const f16x8*)pd;         Xd1.v = *(const f16x8*)(pd + 32);

  U8h Ah, Al;
  dec8h(f, Ah, Al);

  // hy L1 (K=32)
  f32x4 acc[4];
#pragma unroll
  for (int t = 0; t < 4; ++t) { float bv = hb1[t * 16 + m]; acc[t] = (f32x4){bv, bv, bv, bv}; }
#pragma unroll
  for (int t = 0; t < 4; ++t) {
    f16x8 b = *(const f16x8*)(hB1 + ((size_t)t * 64 + lane) * 8);
    acc[t] = __builtin_amdgcn_mfma_f32_16x16x32_f16(Ah.v, b, acc[t], 0, 0, 0);
    acc[t] = __builtin_amdgcn_mfma_f32_16x16x32_f16(Al.v, b, acc[t], 0, 0, 0);
  }

  float* hb = hbuf[wv];
#pragma unroll
  for (int t = 0; t < 4; ++t)
#pragma unroll
    for (int r = 0; r < 4; ++r)
      hb[(q * 4 + r) * 68 + t * 16 + m] = fmaxf(acc[t][r], 0.f);

  float fh[16];
  load_row(hb + m * 68 + q * 8, fh);
  U8h H0, H1;
  conv8_rne(fh + 0, H0);
  conv8_rne(fh + 8, H1);

  // hy L2 (single fp16 h)
  f32x4 o[4];
#pragma unroll
  for (int t = 0; t < 4; ++t) { float bv = hb2[t * 16 + m]; o[t] = (f32x4){bv, bv, bv, bv}; }
#pragma unroll
  for (int t = 0; t < 4; ++t) {
    f16x8 b0 = *(const f16x8*)(hB2 + ((size_t)(0 * 4 + t) * 64 + lane) * 8);
    f16x8 b1_ = *(const f16x8*)(hB2 + ((size_t)(1 * 4 + t) * 64 + lane) * 8);
    o[t] = __builtin_amdgcn_mfma_f32_16x16x32_f16(H0.v, b0, o[t], 0, 0, 0);
    o[t] = __builtin_amdgcn_mfma_f32_16x16x32_f16(H1.v, b1_, o[t], 0, 0, 0);
  }

  // transpose y0 -> row layout, quantize RNE, store + keep A-frags
#pragma unroll
  for (int t = 0; t < 4; ++t)
#pragma unroll
    for (int r = 0; r < 4; ++r)
      hb[(q * 4 + r) * 68 + t * 16 + m] = o[t][r];

  float nv[16];
  load_row(hb + m * 68 + q * 8, nv);
  U8h Yh0, Yh1;
  conv8_rne(nv + 0, Yh0);
  conv8_rne(nv + 8, Yh1);
  if (live) {
    size_t yo = (size_t)row * 64 + q * 8;
    *(f16x8*)(y + yo)      = Yh0.v;
    *(f16x8*)(y + yo + 32) = Yh1.v;
  }

  // fx L1: [xs0,xs1,xd0,xd1,y0,y1] all single fp16
  f32x4 acc2[4];
#pragma unroll
  for (int t = 0; t < 4; ++t) { float bv = xb1[t * 16 + m]; acc2[t] = (f32x4){bv, bv, bv, bv}; }
#pragma unroll
  for (int t = 0; t < 4; ++t) {
    f16x8 b0 = *(const f16x8*)(xB1 + ((size_t)(0 * 4 + t) * 64 + lane) * 8);
    f16x8 b1_ = *(const f16x8*)(xB1 + ((size_t)(1 * 4 + t) * 64 + lane) * 8);
    f16x8 b2_ = *(const f16x8*)(xB1 + ((size_t)(2 * 4 + t) * 64 + lane) * 8);
    f16x8 b3_ = *(const f16x8*)(xB1 + ((size_t)(3 * 4 + t) * 64 + lane) * 8);
    f16x8 b4_ = *(const f16x8*)(xB1 + ((size_t)(4 * 4 + t) * 64 + lane) * 8);
    f16x8 b5_ = *(const f16x8*)(xB1 + ((size_t)(5 * 4 + t) * 64 + lane) * 8);
    acc2[t] = __builtin_amdgcn_mfma_f32_16x16x32_f16(Xs0.v, b0, acc2[t], 0, 0, 0);
    acc2[t] = __builtin_amdgcn_mfma_f32_16x16x32_f16(Xs1.v, b1_, acc2[t], 0, 0, 0);
    acc2[t] = __builtin_amdgcn_mfma_f32_16x16x32_f16(Xd0.v, b2_, acc2[t], 0, 0, 0);
    acc2[t] = __builtin_amdgcn_mfma_f32_16x16x32_f16(Xd1.v, b3_, acc2[t], 0, 0, 0);
    acc2[t] = __builtin_amdgcn_mfma_f32_16x16x32_f16(Yh0.v, b4_, acc2[t], 0, 0, 0);
    acc2[t] = __builtin_amdgcn_mfma_f32_16x16x32_f16(Yh1.v, b5_, acc2[t], 0, 0, 0);
  }

#pragma unroll
  for (int t = 0; t < 4; ++t)
#pragma unroll
    for (int r = 0; r < 4; ++r)
      hb[(q * 4 + r) * 68 + t * 16 + m] = fmaxf(acc2[t][r], 0.f);

  float fh2[16];
  load_row(hb + m * 68 + q * 8, fh2);
  U8h G0, G1;
  conv8_rne(fh2 + 0, G0);
  conv8_rne(fh2 + 8, G1);

  f32x4 o2[4];
#pragma unroll
  for (int t = 0; t < 4; ++t) { float bv = xb2[t * 16 + m]; o2[t] = (f32x4){bv, bv, bv, bv}; }
#pragma unroll
  for (int t = 0; t < 4; ++t) {
    f16x8 b0 = *(const f16x8*)(xB2 + ((size_t)(0 * 4 + t) * 64 + lane) * 8);
    f16x8 b1_ = *(const f16x8*)(xB2 + ((size_t)(1 * 4 + t) * 64 + lane) * 8);
    o2[t] = __builtin_amdgcn_mfma_f32_16x16x32_f16(G0.v, b0, o2[t], 0, 0, 0);
    o2[t] = __builtin_amdgcn_mfma_f32_16x16x32_f16(G1.v, b1_, o2[t], 0, 0, 0);
  }

  int dd[4];
  int e0 = base + q * 4;
#pragma unroll
  for (int r = 0; r < 4; ++r) {
    int e2 = e0 + r;
    dd[r] = (e2 < E) ? dst[e2] : -1;
  }
  RunCtx rc = run_ctx(dd, lane, q);
#pragma unroll
  for (int t = 0; t < 4; ++t) emit_t(o2[t], dd, rc, lane, m, t, xnew);
}

// ---------------- fused fy + fx (t=1,2): x and y gathered fp16 ----------------
__global__ __launch_bounds__(256) void k_fyfx(
    const _Float16* __restrict__ xh, _Float16* __restrict__ y,
    const int* __restrict__ src, const int* __restrict__ dst,
    const _Float16* __restrict__ yB1, const float* __restrict__ yb1,
    const _Float16* __restrict__ yB2, const float* __restrict__ yb2,
    const _Float16* __restrict__ xB1, const float* __restrict__ xb1,
    const _Float16* __restrict__ xB2, const float* __restrict__ xb2,
    float* __restrict__ xnew, int E, int storeY) {
  __shared__ float hbuf[4][16 * 68];
  const int lane = threadIdx.x & 63;
  const int wv = threadIdx.x >> 6;
  const int m = lane & 15, q = lane >> 4;
  const int base = blockIdx.x * 64 + wv * 16;
  int em = base + m; if (em >= E) em = E - 1;
  const int si = src[em], di = dst[em];
  const int row = base + m;
  const bool live = row < E;

  const _Float16* ps = xh + (size_t)si * 64 + q * 8;
  const _Float16* pd = xh + (size_t)di * 64 + q * 8;
  U8h Xs0, Xs1, Xd0, Xd1;
  Xs0.v = *(const f16x8*)ps;         Xs1.v = *(const f16x8*)(ps + 32);
  Xd0.v = *(const f16x8*)pd;         Xd1.v = *(const f16x8*)(pd + 32);
  U8h Ho0, Ho1;
  {
    size_t yo = (size_t)em * 64 + q * 8;
    Ho0.v = *(const f16x8*)(y + yo);  Ho1.v = *(const f16x8*)(y + yo + 32);
  }

  // fy L1: chunks [xd0,xd1,xs0,xs1] single fp16
  f32x4 acc[4];
#pragma unroll
  for (int t = 0; t < 4; ++t) { float bv = yb1[t * 16 + m]; acc[t] = (f32x4){bv, bv, bv, bv}; }
#pragma unroll
  for (int t = 0; t < 4; ++t) {
    f16x8 b0 = *(const f16x8*)(yB1 + ((size_t)(0 * 4 + t) * 64 + lane) * 8);
    f16x8 b1_ = *(const f16x8*)(yB1 + ((size_t)(1 * 4 + t) * 64 + lane) * 8);
    f16x8 b2_ = *(const f16x8*)(yB1 + ((size_t)(2 * 4 + t) * 64 + lane) * 8);
    f16x8 b3_ = *(const f16x8*)(yB1 + ((size_t)(3 * 4 + t) * 64 + lane) * 8);
    acc[t] = __builtin_amdgcn_mfma_f32_16x16x32_f16(Xd0.v, b0, acc[t], 0, 0, 0);
    acc[t] = __builtin_amdgcn_mfma_f32_16x16x32_f16(Xd1.v, b1_, acc[t], 0, 0, 0);
    acc[t] = __builtin_amdgcn_mfma_f32_16x16x32_f16(Xs0.v, b2_, acc[t], 0, 0, 0);
    acc[t] = __builtin_amdgcn_mfma_f32_16x16x32_f16(Xs1.v, b3_, acc[t], 0, 0, 0);
  }

  float* hb = hbuf[wv];
#pragma unroll
  for (int t = 0; t < 4; ++t)
#pragma unroll
    for (int r = 0; r < 4; ++r)
      hb[(q * 4 + r) * 68 + t * 16 + m] = fmaxf(acc[t][r], 0.f);

  float fh[16];
  load_row(hb + m * 68 + q * 8, fh);
  U8h H0, H1;
  conv8_rne(fh + 0, H0);
  conv8_rne(fh + 8, H1);

  // fy L2
  f32x4 o[4];
#pragma unroll
  for (int t = 0; t < 4; ++t) { float bv = yb2[t * 16 + m]; o[t] = (f32x4){bv, bv, bv, bv}; }
#pragma unroll
  for (int t = 0; t < 4; ++t) {
    f16x8 b0 = *(const f16x8*)(yB2 + ((size_t)(0 * 4 + t) * 64 + lane) * 8);
    f16x8 b1_ = *(const f16x8*)(yB2 + ((size_t)(1 * 4 + t) * 64 + lane) * 8);
    o[t] = __builtin_amdgcn_mfma_f32_16x16x32_f16(H0.v, b0, o[t], 0, 0, 0);
    o[t] = __builtin_amdgcn_mfma_f32_16x16x32_f16(H1.v, b1_, o[t], 0, 0, 0);
  }

  // transpose fy out -> row layout; y = max(y_old, out); quantize; store
#pragma unroll
  for (int t = 0; t < 4; ++t)
#pragma unroll
    for (int r = 0; r < 4; ++r)
      hb[(q * 4 + r) * 68 + t * 16 + m] = o[t][r];

  float nv[16];
  load_row(hb + m * 68 + q * 8, nv);
#pragma unroll
  for (int i = 0; i < 8; ++i) {
    nv[i]     = fmaxf((float)Ho0.s[i], nv[i]);
    nv[8 + i] = fmaxf((float)Ho1.s[i], nv[8 + i]);
  }
  U8h Yh0, Yh1;
  conv8_rne(nv + 0, Yh0);
  conv8_rne(nv + 8, Yh1);
  if (live && storeY) {
    size_t yo = (size_t)row * 64 + q * 8;
    *(f16x8*)(y + yo)      = Yh0.v;
    *(f16x8*)(y + yo + 32) = Yh1.v;
  }

  // fx L1: [xs0,xs1,xd0,xd1,y0,y1] single fp16
  f32x4 acc2[4];
#pragma unroll
  for (int t = 0; t < 4; ++t) { float bv = xb1[t * 16 + m]; acc2[t] = (f32x4){bv, bv, bv, bv}; }
#pragma unroll
  for (int t = 0; t < 4; ++t) {
    f16x8 b0 = *(const f16x8*)(xB1 + ((size_t)(0 * 4 + t) * 64 + lane) * 8);
    f16x8 b1_ = *(const f16x8*)(xB1 + ((size_t)(1 * 4 + t) * 64 + lane) * 8);
    f16x8 b2_ = *(const f16x8*)(xB1 + ((size_t)(2 * 4 + t) * 64 + lane) * 8);
    f16x8 b3_ = *(const f16x8*)(xB1 + ((size_t)(3 * 4 + t) * 64 + lane) * 8);
    f16x8 b4_ = *(const f16x8*)(xB1 + ((size_t)(4 * 4 + t) * 64 + lane) * 8);
    f16x8 b5_ = *(const f16x8*)(xB1 + ((size_t)(5 * 4 + t) * 64 + lane) * 8);
    acc2[t] = __builtin_amdgcn_mfma_f32_16x16x32_f16(Xs0.v, b0, acc2[t], 0, 0, 0);
    acc2[t] = __builtin_amdgcn_mfma_f32_16x16x32_f16(Xs1.v, b1_, acc2[t], 0, 0, 0);
    acc2[t] = __builtin_amdgcn_mfma_f32_16x16x32_f16(Xd0.v, b2_, acc2[t], 0, 0, 0);
    acc2[t] = __builtin_amdgcn_mfma_f32_16x16x32_f16(Xd1.v, b3_, acc2[t], 0, 0, 0);
    acc2[t] = __builtin_amdgcn_mfma_f32_16x16x32_f16(Yh0.v, b4_, acc2[t], 0, 0, 0);
    acc2[t] = __builtin_amdgcn_mfma_f32_16x16x32_f16(Yh1.v, b5_, acc2[t], 0, 0, 0);
  }

#pragma unroll
  for (int t = 0; t < 4; ++t)
#pragma unroll
    for (int r = 0; r < 4; ++r)
      hb[(q * 4 + r) * 68 + t * 16 + m] = fmaxf(acc2[t][r], 0.f);

  float fh2[16];
  load_row(hb + m * 68 + q * 8, fh2);
  U8h G0, G1;
  conv8_rne(fh2 + 0, G0);
  conv8_rne(fh2 + 8, G1);

  f32x4 o2[4];
#pragma unroll
  for (int t = 0; t < 4; ++t) { float bv = xb2[t * 16 + m]; o2[t] = (f32x4){bv, bv, bv, bv}; }
#pragma unroll
  for (int t = 0; t < 4; ++t) {
    f16x8 b0 = *(const f16x8*)(xB2 + ((size_t)(0 * 4 + t) * 64 + lane) * 8);
    f16x8 b1_ = *(const f16x8*)(xB2 + ((size_t)(1 * 4 + t) * 64 + lane) * 8);
    o2[t] = __builtin_amdgcn_mfma_f32_16x16x32_f16(G0.v, b0, o2[t], 0, 0, 0);
    o2[t] = __builtin_amdgcn_mfma_f32_16x16x32_f16(G1.v, b1_, o2[t], 0, 0, 0);
  }

  int dd[4];
  int e0 = base + q * 4;
#pragma unroll
  for (int r = 0; r < 4; ++r) {
    int e2 = e0 + r;
    dd[r] = (e2 < E) ? dst[e2] : -1;
  }
  RunCtx rc = run_ctx(dd, lane, q);
#pragma unroll
  for (int t = 0; t < 4; ++t) emit_t(o2[t], dd, rc, lane, m, t, xnew);
}

// ---------------- feta (MFMA): out = w3 . relu(MLP2(x)) ----------------
__global__ __launch_bounds__(256) void k_feta2(
    const float* __restrict__ x,
    const _Float16* __restrict__ B1, const float* __restrict__ b1,
    const _Float16* __restrict__ B2, const float* __restrict__ b2,
    const float* __restrict__ w3, float* __restrict__ out, int N) {
  __shared__ float hbuf[4][16 * 68];
  const int lane = threadIdx.x & 63;
  const int wv = threadIdx.x >> 6;
  const int m = lane & 15, q = lane >> 4;
  const int base = blockIdx.x * 64 + wv * 16;
  int node = base + m; if (node >= N) node = N - 1;
  float fs[16];
  load_row(x + (size_t)node * 64 + q * 8, fs);
  U8h Ah[2], Al[2];
  dec8h(fs + 0, Ah[0], Al[0]);
  dec8h(fs + 8, Ah[1], Al[1]);

  f32x4 acc[4];
#pragma unroll
  for (int t = 0; t < 4; ++t) { float bv = b1[t * 16 + m]; acc[t] = (f32x4){bv, bv, bv, bv}; }
#pragma unroll
  for (int c = 0; c < 2; ++c) {
#pragma unroll
    for (int t = 0; t < 4; ++t) {
      f16x8 b = *(const f16x8*)(B1 + ((size_t)(c * 4 + t) * 64 + lane) * 8);
      acc[t] = __builtin_amdgcn_mfma_f32_16x16x32_f16(Ah[c].v, b, acc[t], 0, 0, 0);
      acc[t] = __builtin_amdgcn_mfma_f32_16x16x32_f16(Al[c].v, b, acc[t], 0, 0, 0);
    }
  }

  float* hb = hbuf[wv];
#pragma unroll
  for (int t = 0; t < 4; ++t)
#pragma unroll
    for (int r = 0; r < 4; ++r)
      hb[(q * 4 + r) * 68 + t * 16 + m] = fmaxf(acc[t][r], 0.f);

  float fh[16];
  load_row(hb + m * 68 + q * 8, fh);
  U8h A2h[2], A2l[2];
  dec8h(fh + 0, A2h[0], A2l[0]);
  dec8h(fh + 8, A2h[1], A2l[1]);

  f32x4 acc2[4];
#pragma unroll
  for (int t = 0; t < 4; ++t) { float bv = b2[t * 16 + m]; acc2[t] = (f32x4){bv, bv, bv, bv}; }
#pragma unroll
  for (int c = 0; c < 2; ++c) {
#pragma unroll
    for (int t = 0; t < 4; ++t) {
      f16x8 b = *(const f16x8*)(B2 + ((size_t)(c * 4 + t) * 64 + lane) * 8);
      acc2[t] = __builtin_amdgcn_mfma_f32_16x16x32_f16(A2h[c].v, b, acc2[t], 0, 0, 0);
      acc2[t] = __builtin_amdgcn_mfma_f32_16x16x32_f16(A2l[c].v, b, acc2[t], 0, 0, 0);
    }
  }

  float w3v[4];
#pragma unroll
  for (int t = 0; t < 4; ++t) w3v[t] = w3[t * 16 + m];
#pragma unroll
  for (int r = 0; r < 4; ++r) {
    float s = 0.f;
#pragma unroll
    for (int t = 0; t < 4; ++t) s += fmaxf(acc2[t][r], 0.f) * w3v[t];
    s += __shfl_xor(s, 1, 64);
    s += __shfl_xor(s, 2, 64);
    s += __shfl_xor(s, 4, 64);
    s += __shfl_xor(s, 8, 64);
    int row = base + q * 4 + r;
    if (m == 0 && row < N) out[row] = s;
  }
}

extern "C" void kernel_launch(void* const* d_in, const int* in_sizes, int n_in,
                              void* d_out, int out_size, void* d_ws, size_t ws_size,
                              hipStream_t stream) {
  const float* v      = (const float*)d_in[0];
  const float* labels = (const float*)d_in[1];
  const int*   ei     = (const int*)d_in[2];
  const float* hx_w1 = (const float*)d_in[4];
  const float* hx_b1 = (const float*)d_in[5];
  const float* hx_w2 = (const float*)d_in[6];
  const float* hx_b2 = (const float*)d_in[7];
  const float* hy_w1 = (const float*)d_in[8];
  const float* hy_b1 = (const float*)d_in[9];
  const float* hy_w2 = (const float*)d_in[10];
  const float* hy_b2 = (const float*)d_in[11];
  const float* fx_w1 = (const float*)d_in[12];
  const float* fx_b1 = (const float*)d_in[13];
  const float* fx_w2 = (const float*)d_in[14];
  const float* fx_b2 = (const float*)d_in[15];
  const float* fy_w1 = (const float*)d_in[16];
  const float* fy_b1 = (const float*)d_in[17];
  const float* fy_w2 = (const float*)d_in[18];
  const float* fy_b2 = (const float*)d_in[19];
  const float* feta_w1 = (const float*)d_in[20];
  const float* feta_b1 = (const float*)d_in[21];
  const float* feta_w2 = (const float*)d_in[22];
  const float* feta_b2 = (const float*)d_in[23];
  const float* feta_w3 = (const float*)d_in[24];

  int N = in_sizes[0] / 7;
  int E = in_sizes[2] / 2;
  const int* src = ei;
  const int* dst = ei + E;

  char* wsb = (char*)d_ws;
  float* goal = (float*)wsb;                                     // 16 f
  u64* goalkey = (u64*)(wsb + 64);
  float* b1p = (float*)(wsb + 96);                               // 64 f
  float* xa = (float*)(wsb + 512);                               // N*64 f
  float* xb = xa + (size_t)N * 64;                               // N*64 f
  _Float16* xh = (_Float16*)(xb + (size_t)N * 64);               // N*64 f16 gather shadow
  _Float16* y = xh + (size_t)N * 64;                             // E*64 f16
  _Float16* wp = y + (size_t)E * 64;                             // 49152 f16
  float* vcp = (float*)(wp + 49152);                             // N*16 f
  int* deg = (int*)(vcp + (size_t)N * 16);                       // N
  int* cursor = deg + N;                                         // N
  int* srcp = cursor + N;                                        // E
  int* dstp = srcp + E;                                          // E
  int* bsum = dstp + E;                                          // 64

  _Float16* fxB1 = wp;          _Float16* fxB2 = wp + 12288;
  _Float16* fyB1 = wp + 16384;  _Float16* fyB2 = wp + 24576;
  _Float16* hyB1 = wp + 28672;  _Float16* hyB2 = wp + 30720;
  _Float16* hxB1 = wp + 34816;  _Float16* hxB2 = wp + 36864;
  _Float16* feB1 = wp + 40960;  _Float16* feB2 = wp + 45056;

  int SB = (N + 1023) / 1024;

  hipMemsetAsync(deg, 0, (size_t)N * 4, stream);
  k_prep<<<24, 256, 0, stream>>>(fx_w1, fx_w2, fy_w1, fy_w2, hy_w1, hy_w2,
                                 hx_w1, hx_w2, feta_w1, feta_w2, wp, goalkey);
  k_vch<<<(N * 16 + 255) / 256, 256, 0, stream>>>(v, labels, vcp, N, dst, E, deg, goalkey);
  k_goal2b<<<1, 64, 0, stream>>>(v, labels, goalkey, hx_w1, hx_b1, goal, b1p);
  k_scan1<<<SB, 256, 0, stream>>>(deg, N, bsum);
  k_scan3<<<SB, 256, 0, stream>>>(deg, bsum, N, cursor);
  k_scatter<<<(E + 255) / 256, 256, 0, stream>>>(src, dst, E, cursor, srcp, dstp);

  // x1 -> xa (working) + xb (t=0 atomic seed) + xh (fp16 gather shadow)
  k_hx2<<<(N + 63) / 64, 256, 0, stream>>>(vcp, goal, hxB1, b1p, hxB2, hx_b2, xa, xb, xh, N);

  int EB = (E + 63) / 64;
  // t=0: y0 = hy(vcp); x2 = max(x1, agg fx(x1,y0)) -> xb
  k_hyfx<<<EB, 256, 0, stream>>>(vcp, xh, srcp, dstp,
                                 hyB1, hy_b1, hyB2, hy_b2,
                                 fxB1, fx_b1, fxB2, fx_b2, y, xb, E);
  // t=1
  k_cc<<<(N * 16 + 255) / 256, 256, 0, stream>>>((const float4*)xb, (float4*)xa, xh, N * 16);
  k_fyfx<<<EB, 256, 0, stream>>>(xh, y, srcp, dstp,
                                 fyB1, fy_b1, fyB2, fy_b2,
                                 fxB1, fx_b1, fxB2, fx_b2, xa, E, 1);
  // t=2 (y dead after: skip its store)
  k_cc<<<(N * 16 + 255) / 256, 256, 0, stream>>>((const float4*)xa, (float4*)xb, xh, N * 16);
  k_fyfx<<<EB, 256, 0, stream>>>(xh, y, srcp, dstp,
                                 fyB1, fy_b1, fyB2, fy_b2,
                                 fxB1, fx_b1, fxB2, fx_b2, xb, E, 0);

  k_feta2<<<(N + 63) / 64, 256, 0, stream>>>(xb, feB1, feta_b1, feB2, feta_b2, feta_w3,
                                             (float*)d_out, N);
}